// Round 17
// baseline (342.599 us; speedup 1.0000x reference)
//
#include <hip/hip_runtime.h>
#include <math.h>

// ---------------- problem constants ----------------
// B=4, N=600, S=168, D=40, Cc=32, Cs=16, Ce=128, Od=12
// Adjacency path: bit-exact Eigen/MLIR fast-tanh (clamp 7.99881172180175781f,
// FMA Horner, |x|<0.0004 passthrough) + Eigen seq-FMA dots. PROVEN R7-R16.
// R17: U intermediate eliminated via P[i,g,o2,p]=sum_c Wg[c,o2]*Weff[c,p];
// k_adj reverted to proven R15 form (LDS-staged, pipelined, 57us).

// ---------------- workspace layout ----------------
#define DW_WEFF 0          // [3][32][16] doubles
#define DW_CC   1536       // [3][32]
#define DW_P    1632       // [3][5][32][16] doubles = 7680
#define FB      18624      // float offset = 2*(1632+7680)
#define OW_CSV  (FB+0)
#define OW_CBIG (FB+48)
#define OW_VBIG (FB+304)
#define OW_T    (FB+760112)
#define OW_FEAT (FB+1374512)
#define OW_N1   (FB+1604912)
#define OW_N2   (FB+1892912)
#define OW_IRA  (FB+2180912)
#define OW_IRB  (FB+2188112)
#define OW_U1A  (FB+2195312)
#define OW_U2A  (FB+2310512)
#define OW_U1B  (FB+2425712)
#define OW_U2B  (FB+2540912)
#define OW_U3A  (FB+2656112)
#define OW_U3B  (FB+2771312)
#define OW_O    (FB+2886512)
#define OW_SE   (FB+3040112)

// ---------------- Eigen/MLIR fast tanh f32 (FMA build), bit-faithful ----------------
__device__ __forceinline__ float tanh_eigen(float x)
{
  const float CL = 7.99881172180175781f;
  float xc = fminf(fmaxf(x, -CL), CL);
  float x2 = __fmul_rn(xc, xc);
  float p = fmaf(x2, -2.76076847742355e-16f, 2.00018790482477e-13f);
  p = fmaf(x2, p, -8.60467152213735e-11f);
  p = fmaf(x2, p, 5.12229709037114e-08f);
  p = fmaf(x2, p, 1.48572235717979e-05f);
  p = fmaf(x2, p, 6.37261928875436e-04f);
  p = fmaf(x2, p, 4.89352455891786e-03f);
  p = __fmul_rn(xc, p);
  float q = fmaf(x2, 1.19825839466702e-06f, 1.18534705686654e-04f);
  q = fmaf(x2, q, 2.26843463243900e-03f);
  q = fmaf(x2, q, 4.89352518554385e-03f);
  float r = __fdiv_rn(p, q);
  return fabsf(x) < 0.0004f ? x : r;
}

// ---------------- mixprop weight-block values ----------------
__device__ __forceinline__ float wg_val(const float* gW, int i, int g, int c, int o2)
{
  const float* gW0 = gW + (i*2+0)*96*32;
  const float* gW1 = gW + (i*2+1)*96*32;
  if (g == 0) return gW0[c*32+o2] + gW1[c*32+o2]
                + 0.05f*(gW0[(32+c)*32+o2] + gW0[(64+c)*32+o2] + gW1[(32+c)*32+o2] + gW1[(64+c)*32+o2]);
  else if (g == 1) return gW0[(32+c)*32+o2];
  else if (g == 2) return gW0[(64+c)*32+o2];
  else if (g == 3) return gW1[(32+c)*32+o2];
  return gW1[(64+c)*32+o2];
}

// ---------------- fused: weff fold (block 48) + const_sv (blocks 0..47) ----------------
__global__ __launch_bounds__(256) void k_pre_wc(const float* Ws, const float* bs,
    const float* scW0, const float* scW1, const float* scW2, const float* scb,
    const float* svW0, const float* svW1, const float* svW2,
    const float* gb, const float* svb, double* wd, float* ws)
{
  if (blockIdx.x < 48) {
    int blk = blockIdx.x;
    int i = blk/16, o = blk%16;
    const float* svW = (i==0)?svW0:((i==1)?svW1:svW2);
    int L = (i==0)?162:((i==1)?79:39);
    int tid = threadIdx.x;
    __shared__ double red[256];
    double s = 0;
    for (int idx = tid; idx < 32*L; idx += 256) {
      int o2 = idx / L, l = idx - o2*L;
      s += (double)svW[(o*32+o2)*L + l] * ((double)gb[(i*2+0)*32+o2] + (double)gb[(i*2+1)*32+o2]);
    }
    red[tid] = s; __syncthreads();
    for (int st = 128; st; st >>= 1) { if (tid < st) red[tid] += red[tid+st]; __syncthreads(); }
    if (tid == 0) ws[OW_CSV + blk] = (float)(red[0] + (double)svb[i*16+o]);
    return;
  }
  __shared__ double w0[32][7], c0[32], w1[32][12], c1[32];
  int t = threadIdx.x;
  for (int e = t; e < 32*7; e += 256) {
    int c = e/7, p = e%7; double s = 0;
    for (int ci = 0; ci < 32; ci++) s += (double)scW0[(c*32+ci)*7+p] * (double)Ws[ci];
    w0[c][p] = s;
  }
  for (int e = t; e < 32; e += 256) {
    double s = 0;
    for (int ci = 0; ci < 32; ci++) { double a = 0; for (int p = 0; p < 7; p++) a += (double)scW0[(e*32+ci)*7+p]; s += a*(double)bs[ci]; }
    c0[e] = s + (double)scb[e];
  }
  __syncthreads();
  for (int e = t; e < 32*12; e += 256) {
    int c = e/12, m = e%12; double s = 0;
    for (int k1 = 0; k1 < 6; k1++) { int k0 = m - k1; if (k0 < 0 || k0 > 6) continue;
      for (int ci = 0; ci < 32; ci++) s += (double)scW1[(c*32+ci)*6+k1] * w0[ci][k0]; }
    w1[c][m] = s;
  }
  for (int e = t; e < 32; e += 256) {
    double s = 0;
    for (int ci = 0; ci < 32; ci++) { double a = 0; for (int k1 = 0; k1 < 6; k1++) a += (double)scW1[(e*32+ci)*6+k1]; s += a*c0[ci]; }
    c1[e] = s + (double)scb[32+e];
  }
  __syncthreads();
  for (int e = t; e < 32*16; e += 256) {
    int c = e/16, p = e%16; double s = 0;
    for (int k2 = 0; k2 < 3; k2++) { int m = p - 2*k2; if (m < 0 || m > 11) continue;
      for (int ci = 0; ci < 32; ci++) s += (double)scW2[(c*32+ci)*3+k2] * w1[ci][m]; }
    wd[DW_WEFF + (2*32+c)*16 + p] = s;
  }
  for (int e = t; e < 32; e += 256) {
    double s = 0;
    for (int ci = 0; ci < 32; ci++) { double a = 0; for (int k2 = 0; k2 < 3; k2++) a += (double)scW2[(e*32+ci)*3+k2]; s += a*c1[ci]; }
    wd[DW_CC + 64 + e] = s + (double)scb[64+e];
  }
  for (int e = t; e < 32*7;  e += 256) wd[DW_WEFF + (e/7)*16  + e%7 ] = w0[e/7][e%7];
  for (int e = t; e < 32*12; e += 256) wd[DW_WEFF + (32 + e/12)*16 + e%12] = w1[e/12][e%12];
  for (int e = t; e < 32; e += 256) { wd[DW_CC+e] = c0[e]; wd[DW_CC+32+e] = c1[e]; }
}

// ---------------- P[i][g][o2][p], Q, cbig (15 blocks) ----------------
__global__ __launch_bounds__(256) void k_pre_p(const float* svW0, const float* svW1, const float* svW2,
                                               const float* gW, double* wd, float* ws)
{
  int blk = blockIdx.x;      // i*5+g
  int i = blk/5, g = blk%5;
  const float* svW = (i==0)?svW0:((i==1)?svW1:svW2);
  int L = (i==0)?162:((i==1)?79:39);
  int tid = threadIdx.x;
  // P
  for (int e = tid; e < 512; e += 256) {
    int o2 = e >> 4, p = e & 15;
    double s = 0;
    for (int c = 0; c < 32; c++)
      s += (double)wg_val(gW,i,g,c,o2) * wd[DW_WEFF + (i*32+c)*16 + p];
    wd[DW_P + ((i*5+g)*32 + o2)*16 + p] = s;
  }
  // Q
  __shared__ double Qs[32];
  __shared__ double cbred[16][17];
  if (tid < 32) {
    double s = 0;
    for (int c = 0; c < 32; c++)
      s += (double)wg_val(gW,i,g,c,tid) * wd[DW_CC + i*32 + c];
    Qs[tid] = s;
  }
  __syncthreads();
  // cbig: o = tid>>4, part = tid&15 -> 2 o2 each
  {
    int o = tid >> 4, part = tid & 15;
    double s = 0;
    for (int o2 = part*2; o2 < part*2+2; o2++) {
      double sl = 0;
      const float* sv = svW + (o*32+o2)*L;
      for (int l = 0; l < L; l++) sl += (double)sv[l];
      s += sl * Qs[o2];
    }
    cbred[o][part] = s;
  }
  __syncthreads();
  if (tid < 16) {
    double s = 0;
    for (int p = 0; p < 16; p++) s += cbred[tid][p];
    ws[OW_CBIG + (i*80 + g*16 + tid)] = (float)s;
  }
}

// ---------------- t-path/out0 fused weight columns (svW x P) ----------------
__global__ __launch_bounds__(256) void k_pre_v(const float* svW0, const float* svW1, const float* svW2,
                                               const float* s0W, const float* s0b, double* wd, float* ws)
{
  int jj = blockIdx.x;             // 0..255
  int tid = threadIdx.x;
  if (jj >= 240) {
    int o = jj - 240;
    if (tid < 168) ws[OW_VBIG + jj*168 + tid] = s0W[o*168 + tid];
    if (tid == 0)  ws[OW_CBIG + jj] = s0b[o];
    return;
  }
  int i = jj/80, g = (jj%80)/16, o = jj%16;
  int st = (i==0)?1:((i==1)?2:4), tp = (i==0)?7:((i==1)?12:16), L = (i==0)?162:((i==1)?79:39);
  const float* svW = (i==0)?svW0:((i==1)?svW1:svW2);
  const float* svo = svW + o*32*L;
  __shared__ float svlds[32*162];
  __shared__ double Pl[32][16];
  int NL = 32*L;
  for (int e = tid; e < NL; e += 256) svlds[e] = svo[e];
  for (int e = tid; e < 512; e += 256) {
    int o2 = e >> 4, p = e & 15;
    Pl[o2][p] = wd[DW_P + ((i*5+g)*32 + o2)*16 + p];
  }
  __syncthreads();
  if (tid < 168) {
    int u = tid;
    int lo_ = u - tp + 1;
    int lmin = lo_ > 0 ? (lo_ + st - 1)/st : 0;
    int lmax = u/st; if (lmax > L-1) lmax = L-1;
    double v = 0.0;
    for (int o2 = 0; o2 < 32; o2++) {
      const float* sv = svlds + o2*L;
      const double* Pp = Pl[o2];
      for (int l = lmin; l <= lmax; l++)
        v += (double)sv[l] * Pp[u - st*l];
    }
    ws[OW_VBIG + jj*168 + u] = (float)v;
  }
}

// ---------------- fused: feat (blocks 0..299) + t-path GEMM (300..449) ----------------
__global__ __launch_bounds__(256) void k_fg(const float* x, double* wd, float* ws)
{
  int t = threadIdx.x;
  if (blockIdx.x >= 300) {
    __shared__ float xs[16][168];
    int r0 = (blockIdx.x - 300)*16;
    for (int e = t; e < 16*168; e += 256) { int r = e/168, u = e%168; xs[r][u] = x[(r0+r)*168 + u]; }
    __syncthreads();
    int jj = t;
    const float* V = ws + OW_VBIG + jj*168;
    double a[16];
    #pragma unroll
    for (int r = 0; r < 16; r++) a[r] = 0;
    for (int u = 0; u < 168; u++) {
      float wv = V[u];
      #pragma unroll
      for (int r = 0; r < 16; r++) a[r] += (double)wv * (double)xs[r][u];
    }
    double cb = (double)ws[OW_CBIG + jj];
    for (int r = 0; r < 16; r++)
      ws[OW_T + (r0+r)*256 + jj] = (float)(a[r] + cb);
    return;
  }
  int blk = blockIdx.x;      // 4*75
  int b = blk / 75, n0 = (blk % 75) * 8;
  __shared__ float xsf[8][168];
  __shared__ double xbar[8][35];
  for (int e = t; e < 8*168; e += 256) xsf[e/168][e%168] = x[(b*600 + n0 + e/168)*168 + e%168];
  __syncthreads();
  for (int e = t; e < 8*35; e += 256) {
    int nn = e/35, slot = e%35;
    int i = slot < 7 ? 0 : (slot < 19 ? 1 : 2);
    int p = slot - (i==0?0:(i==1?7:19));
    int st = (i==0)?1:((i==1)?2:4), L = (i==0)?162:((i==1)?79:39);
    double s = 0;
    for (int l = 0; l < L; l++) s += (double)xsf[nn][st*l+p];
    xbar[nn][slot] = s / (double)L;
  }
  __syncthreads();
  int nn = t >> 5, c = t & 31;
  for (int i = 0; i < 3; i++) {
    int off = (i==0)?0:((i==1)?7:19), tp = (i==0)?7:((i==1)?12:16);
    double f = wd[DW_CC + i*32 + c];
    for (int p = 0; p < tp; p++) f += wd[DW_WEFF + (i*32+c)*16 + p] * xbar[nn][off+p];
    ws[OW_FEAT + ((i*4+b)*600 + n0+nn)*32 + c] = (float)f;
  }
}

// ---------------- n1/n2: LDS-staged weights, 16 nodes per block ----------------
__global__ __launch_bounds__(256) void k_nodes(const float* lin1W, const float* lin1b,
                                               const float* lin2W, const float* lin2b,
                                               const float* emb1, const float* emb2, float* ws)
{
  int blk = blockIdx.x;  // i*152 + b*38 + nt
  int nt = blk % 38, b = (blk/38) % 4, i = blk/152;
  int n0 = nt*16;
  __shared__ float W1[1280], W2[1280], b1[40], b2[40], sf[16][33];
  int t = threadIdx.x;
  for (int e = t; e < 1280; e += 256) { W1[e] = lin1W[i*1280 + e]; W2[e] = lin2W[i*1280 + e]; }
  if (t < 40) { b1[t] = lin1b[i*40 + t]; b2[t] = lin2b[i*40 + t]; }
  for (int e = t; e < 16*32; e += 256) {
    int nn = e >> 5, c = e & 31; int n = n0 + nn;
    sf[nn][c] = (n < 600) ? ws[OW_FEAT + ((i*4+b)*600 + n)*32 + c] : 0.f;
  }
  __syncthreads();
  const float TSF[3] = {3.0f, 2.4f, 1.8f};
  for (int item = t; item < 16*80; item += 256) {
    int nn = item / 80, rr = item % 80;
    int n = n0 + nn; if (n >= 600) continue;
    int which = rr/40, d = rr%40;
    const float* W  = which ? W2 : W1;
    const float* bv = which ? b2 : b1;
    const float* em = which ? emb2 : emb1;
    float pre = 0.f;
    #pragma unroll
    for (int c = 0; c < 32; c++) pre = fmaf(sf[nn][c], W[c*40+d], pre);
    float p2 = __fadd_rn(pre, bv[d]);
    float p3 = __fadd_rn(p2, em[n*40+d]);
    float arg = __fmul_rn(TSF[i], p3);
    ws[(which ? OW_N2 : OW_N1) + ((i*4+b)*600 + n)*40 + d] = tanh_eigen(arg);
  }
}

// ---------------- adjacency staging helpers ----------------
__device__ __forceinline__ float4 adj_ld(const float* n1, const float* n2, int e, int w0)
{
  int mat = e >= 320; int idx = e - 320*mat;
  int jj = idx/10, q = idx - 10*jj;
  int w = w0 + jj;
  if (w < 600) return *(const float4*)((mat ? n2 : n1) + w*40 + 4*q);
  float4 z; z.x = z.y = z.z = z.w = 0.f; return z;
}

// ---------------- adjacency: R15 proven (8-way broadcast + staged + svals) ----------------
__global__ __launch_bounds__(256) void k_adj(float* adj_out, float* ws)
{
  int blk = blockIdx.x;                 // 3*4*75
  int tile = blk % 75, b = (blk/75) % 4, i = blk/300;
  int row0 = tile*8;
  const float* n1 = ws + OW_N1 + (i*4+b)*24000;
  const float* n2 = ws + OW_N2 + (i*4+b)*24000;
  __shared__ float c1s[32][44], c2s[32][44];
  __shared__ float svals[8][604];       // 604%32==28: conflict-free
  int t = threadIdx.x;
  int rc = t & 7, jc = t >> 3;          // 8 lanes share each column address
  float am1[40], am2[40];
  {
    const float4* m1p = (const float4*)(n1 + (row0 + rc)*40);
    const float4* m2p = (const float4*)(n2 + (row0 + rc)*40);
    #pragma unroll
    for (int q = 0; q < 10; q++) {
      float4 v1 = m1p[q], v2 = m2p[q];
      am1[4*q]=v1.x; am1[4*q+1]=v1.y; am1[4*q+2]=v1.z; am1[4*q+3]=v1.w;
      am2[4*q]=v2.x; am2[4*q+1]=v2.y; am2[4*q+2]=v2.z; am2[4*q+3]=v2.w;
    }
  }
  float4 s0 = adj_ld(n1, n2, t, 0);
  float4 s1 = adj_ld(n1, n2, t + 256, 0);
  float4 s2; if (t < 128) s2 = adj_ld(n1, n2, t + 512, 0);
  for (int k = 0; k < 19; k++) {
    int w0 = 32*k;
    __syncthreads();
    {
      int e = t;       { int mat=e>=320, idx=e-320*mat, jj=idx/10, q=idx-10*jj, w=w0+jj;
                         if (w<600) *(float4*)(&(mat?c2s:c1s)[jj][4*q]) = s0; }
      e = t + 256;     { int mat=e>=320, idx=e-320*mat, jj=idx/10, q=idx-10*jj, w=w0+jj;
                         if (w<600) *(float4*)(&(mat?c2s:c1s)[jj][4*q]) = s1; }
      if (t < 128) { e = t + 512; int mat=e>=320, idx=e-320*mat, jj=idx/10, q=idx-10*jj, w=w0+jj;
                         if (w<600) *(float4*)(&(mat?c2s:c1s)[jj][4*q]) = s2; }
    }
    __syncthreads();
    if (k < 18) {
      int w0n = w0 + 32;
      s0 = adj_ld(n1, n2, t, w0n);
      s1 = adj_ld(n1, n2, t + 256, w0n);
      if (t < 128) s2 = adj_ld(n1, n2, t + 512, w0n);
    }
    int jcl = jc & 31;
    if (jc < 32) {
      int w = w0 + jcl;
      if (w < 600) {
        const float4* c2p = (const float4*)c2s[jcl];
        const float4* c1p = (const float4*)c1s[jcl];
        float d1 = 0.f, d2 = 0.f;
        #pragma unroll
        for (int q = 0; q < 10; q++) {
          float4 v = c2p[q];
          d1 = fmaf(am1[4*q], v.x, d1); d1 = fmaf(am1[4*q+1], v.y, d1);
          d1 = fmaf(am1[4*q+2], v.z, d1); d1 = fmaf(am1[4*q+3], v.w, d1);
        }
        #pragma unroll
        for (int q = 0; q < 10; q++) {
          float4 v = c1p[q];
          d2 = fmaf(am2[4*q], v.x, d2); d2 = fmaf(am2[4*q+1], v.y, d2);
          d2 = fmaf(am2[4*q+2], v.z, d2); d2 = fmaf(am2[4*q+3], v.w, d2);
        }
        float af = __fsub_rn(d1, d2);
        float tv = __fmul_rn(3.0f, af);
        float v = tanh_eigen(tv);
        svals[rc][w] = v > 0.f ? v : 0.f;       // relu
      }
    }
  }
  __syncthreads();
  // ---- top-k phase: proven logic, vv from svals ----
  int r = t >> 5, j = t & 31;
  float vv[19];
  #pragma unroll
  for (int k = 0; k < 19; k++) {
    int w = j + 32*k;
    vv[k] = (w < 600) ? svals[r][w] : 0.f;
  }
  float rm = 0.f;
  #pragma unroll
  for (int k = 0; k < 19; k++) rm = fmaxf(rm, vv[k]);
  #pragma unroll
  for (int s = 16; s; s >>= 1) rm = fmaxf(rm, __shfl_xor(rm, s, 32));
  const float VP = tanh_eigen(8.0f);
  unsigned int vpb = __float_as_uint(VP);
  int cntp = 0;
  #pragma unroll
  for (int k = 0; k < 19; k++) { int w = j + 32*k; if (w < 600 && __float_as_uint(vv[k]) >= vpb) cntp++; }
  #pragma unroll
  for (int s = 16; s; s >>= 1) cntp += __shfl_xor(cntp, s, 32);
  unsigned int lo, hi;
  unsigned int mb1 = __float_as_uint(rm) + 1u;
  if (cntp >= 20) { lo = vpb; hi = mb1; }
  else            { lo = 0u;  hi = vpb < mb1 ? vpb : mb1; }
  while (hi - lo > 1u) {
    unsigned int mid = lo + ((hi - lo) >> 1);
    int cnt = 0;
    #pragma unroll
    for (int k = 0; k < 19; k++) {
      int w = j + 32*k;
      if (w < 600 && __float_as_uint(vv[k]) >= mid) cnt++;
    }
    #pragma unroll
    for (int s = 16; s; s >>= 1) cnt += __shfl_xor(cnt, s, 32);
    if (cnt >= 20) lo = mid; else hi = mid;
  }
  unsigned int kb = lo;
  float* arow = adj_out + (i*4+b)*360000 + (row0+r)*600;
  float rsum = 0.f;
  #pragma unroll
  for (int k = 0; k < 19; k++) {
    int w = j + 32*k;
    if (w < 600) {
      float v = (__float_as_uint(vv[k]) >= kb) ? vv[k] : 0.f;
      arow[w] = v;
      rsum += v;
    }
  }
  #pragma unroll
  for (int s = 16; s; s >>= 1) rsum += __shfl_xor(rsum, s, 32);
  if (j == 0) ws[OW_IRA + (i*4+b)*600 + row0 + r] = 1.f/(1.f + rsum);
}

// ---------------- column sums (parallel: 120 blocks) ----------------
__global__ __launch_bounds__(256) void k_invrb(const float* adj, float* ws)
{
  int blk = blockIdx.x;            // ib*10 + wt
  int ib = blk / 10, wt = blk % 10;
  int tid = threadIdx.x;
  int wl = tid & 63, vg = tid >> 6;
  int w = wt*64 + wl;
  const float* A = adj + ib*360000;
  float s = 0.f;
  if (w < 600) {
    for (int v = vg*150; v < vg*150 + 150; v++) s += A[v*600 + w];
  }
  __shared__ float red[4][64];
  red[vg][wl] = s;
  __syncthreads();
  if (vg == 0 && w < 600) {
    float tot = ((red[0][wl] + red[1][wl]) + red[2][wl]) + red[3][wl];
    ws[OW_IRB + ib*600 + w] = 1.f/(1.f + tot);
  }
}

// ---------------- prop1: 4w x 4oz per thread, per-wave K-split, b128 LDS ----------------
__global__ __launch_bounds__(256) void k_prop1(const float* adj, float* ws)
{
  int blk = blockIdx.x;            // ib*38 + d*19 + wt
  int wt = blk % 19;
  int d  = (blk / 19) & 1;
  int ib = blk / 38;
  int i = ib >> 2, b = ib & 3;
  int w0 = wt * 32;
  const float* A   = adj + ib*360000;
  const float* irx = ws + (d ? OW_IRB : OW_IRA) + ib*600;
  const float* Tb  = ws + OW_T + (b*600)*256 + i*80 + 16 + d*32;
  __shared__ float As[4][32][36];
  __shared__ float Zs[4][32][36];
  __shared__ float red[3][64][17];
  int tid = threadIdx.x;
  int wv = tid >> 6, ln = tid & 63;
  int wq = ln >> 3, oq = ln & 7;
  float acc[4][4];
  #pragma unroll
  for (int a1 = 0; a1 < 4; a1++)
    #pragma unroll
    for (int a2 = 0; a2 < 4; a2++) acc[a1][a2] = 0.f;
  int vbeg = wv*160, vend = vbeg + 160 < 600 ? vbeg + 160 : 600;
  for (int v0 = vbeg; v0 < vend; v0 += 32) {
    if (d == 0) {
      #pragma unroll
      for (int q = 0; q < 4; q++) {
        int m = q*64 + ln, rr = m >> 3, c4 = (m & 7)*4;
        int v = v0 + rr;
        float4 av; av.x = av.y = av.z = av.w = 0.f;
        if (v < 600) {
          int wb = w0 + c4;
          if (wb + 3 < 600) av = *(const float4*)(A + v*600 + wb);
          else {
            if (wb+0 < 600) av.x = A[v*600 + wb+0];
            if (wb+1 < 600) av.y = A[v*600 + wb+1];
            if (wb+2 < 600) av.z = A[v*600 + wb+2];
            if (wb+3 < 600) av.w = A[v*600 + wb+3];
          }
        }
        *(float4*)(&As[wv][rr][c4]) = av;
      }
    } else {
      #pragma unroll
      for (int q = 0; q < 4; q++) {
        int m = q*64 + ln, rr = m >> 3, c4 = (m & 7)*4;
        int w = w0 + rr;
        float4 av; av.x = av.y = av.z = av.w = 0.f;
        if (w < 600) {
          if (v0 + c4 + 3 < 600) av = *(const float4*)(A + w*600 + v0 + c4);
          else {
            if (v0+c4+0 < 600) av.x = A[w*600 + v0+c4+0];
            if (v0+c4+1 < 600) av.y = A[w*600 + v0+c4+1];
            if (v0+c4+2 < 600) av.z = A[w*600 + v0+c4+2];
            if (v0+c4+3 < 600) av.w = A[w*600 + v0+c4+3];
          }
        }
        As[wv][c4+0][rr] = av.x; As[wv][c4+1][rr] = av.y;
        As[wv][c4+2][rr] = av.z; As[wv][c4+3][rr] = av.w;
      }
    }
    #pragma unroll
    for (int q = 0; q < 4; q++) {
      int m = q*64 + ln, rr = m >> 3, c4 = (m & 7)*4;
      int v = v0 + rr;
      float4 zv; zv.x = zv.y = zv.z = zv.w = 0.f;
      if (v < 600) {
        float ir = irx[v];
        float4 tv = *(const float4*)(Tb + v*256 + c4);
        zv.x = ir*tv.x; zv.y = ir*tv.y; zv.z = ir*tv.z; zv.w = ir*tv.w;
      }
      *(float4*)(&Zs[wv][rr][c4]) = zv;
    }
    __builtin_amdgcn_s_waitcnt(0);
    for (int vl = 0; vl < 32; vl++) {
      float4 a4 = *(const float4*)(&As[wv][vl][wq*4]);
      float4 z4 = *(const float4*)(&Zs[wv][vl][oq*4]);
      acc[0][0] = fmaf(a4.x, z4.x, acc[0][0]); acc[0][1] = fmaf(a4.x, z4.y, acc[0][1]);
      acc[0][2] = fmaf(a4.x, z4.z, acc[0][2]); acc[0][3] = fmaf(a4.x, z4.w, acc[0][3]);
      acc[1][0] = fmaf(a4.y, z4.x, acc[1][0]); acc[1][1] = fmaf(a4.y, z4.y, acc[1][1]);
      acc[1][2] = fmaf(a4.y, z4.z, acc[1][2]); acc[1][3] = fmaf(a4.y, z4.w, acc[1][3]);
      acc[2][0] = fmaf(a4.z, z4.x, acc[2][0]); acc[2][1] = fmaf(a4.z, z4.y, acc[2][1]);
      acc[2][2] = fmaf(a4.z, z4.z, acc[2][2]); acc[2][3] = fmaf(a4.z, z4.w, acc[2][3]);
      acc[3][0] = fmaf(a4.w, z4.x, acc[3][0]); acc[3][1] = fmaf(a4.w, z4.y, acc[3][1]);
      acc[3][2] = fmaf(a4.w, z4.z, acc[3][2]); acc[3][3] = fmaf(a4.w, z4.w, acc[3][3]);
    }
  }
  if (wv > 0) {
    #pragma unroll
    for (int kw = 0; kw < 4; kw++)
      #pragma unroll
      for (int ko = 0; ko < 4; ko++) red[wv-1][ln][kw*4+ko] = acc[kw][ko];
  }
  __syncthreads();
  if (wv == 0) {
    #pragma unroll
    for (int kw = 0; kw < 4; kw++) {
      int w = w0 + wq*4 + kw;
      if (w >= 600) continue;
      float irw = irx[w];
      #pragma unroll
      for (int ko = 0; ko < 4; ko++) {
        int oz = oq*4 + ko;
        float sum = acc[kw][ko] + red[0][ln][kw*4+ko] + red[1][ln][kw*4+ko] + red[2][ln][kw*4+ko];
        sum += irw * Tb[w*256 + oz];
        float* dst = ws + (d==0 ? (oz < 16 ? OW_U1A : OW_U2A) : (oz < 16 ? OW_U1B : OW_U2B));
        dst[(ib*600 + w)*16 + (oz & 15)] = sum;
      }
    }
  }
}

// ---------------- prop2: 4w x 2oz per thread, per-wave K-split ----------------
__global__ __launch_bounds__(256) void k_prop2(const float* adj, float* ws)
{
  int blk = blockIdx.x;            // ib*38 + d*19 + wt
  int wt = blk % 19;
  int d  = (blk / 19) & 1;
  int ib = blk / 38;
  int w0 = wt * 32;
  const float* A   = adj + ib*360000;
  const float* irx = ws + (d ? OW_IRB : OW_IRA) + ib*600;
  const float* u2x = ws + (d ? OW_U2B : OW_U2A) + ib*9600;
  __shared__ float As[4][32][36];
  __shared__ float Zs[4][32][20];
  __shared__ float red[3][64][9];
  int tid = threadIdx.x;
  int wv = tid >> 6, ln = tid & 63;
  int wq = ln >> 3, oq = ln & 7;
  float acc[4][2];
  #pragma unroll
  for (int a1 = 0; a1 < 4; a1++) { acc[a1][0] = 0.f; acc[a1][1] = 0.f; }
  int vbeg = wv*160, vend = vbeg + 160 < 600 ? vbeg + 160 : 600;
  for (int v0 = vbeg; v0 < vend; v0 += 32) {
    if (d == 0) {
      #pragma unroll
      for (int q = 0; q < 4; q++) {
        int m = q*64 + ln, rr = m >> 3, c4 = (m & 7)*4;
        int v = v0 + rr;
        float4 av; av.x = av.y = av.z = av.w = 0.f;
        if (v < 600) {
          int wb = w0 + c4;
          if (wb + 3 < 600) av = *(const float4*)(A + v*600 + wb);
          else {
            if (wb+0 < 600) av.x = A[v*600 + wb+0];
            if (wb+1 < 600) av.y = A[v*600 + wb+1];
            if (wb+2 < 600) av.z = A[v*600 + wb+2];
            if (wb+3 < 600) av.w = A[v*600 + wb+3];
          }
        }
        *(float4*)(&As[wv][rr][c4]) = av;
      }
    } else {
      #pragma unroll
      for (int q = 0; q < 4; q++) {
        int m = q*64 + ln, rr = m >> 3, c4 = (m & 7)*4;
        int w = w0 + rr;
        float4 av; av.x = av.y = av.z = av.w = 0.f;
        if (w < 600) {
          if (v0 + c4 + 3 < 600) av = *(const float4*)(A + w*600 + v0 + c4);
          else {
            if (v0+c4+0 < 600) av.x = A[w*600 + v0+c4+0];
            if (v0+c4+1 < 600) av.y = A[w*600 + v0+c4+1];
            if (v0+c4+2 < 600) av.z = A[w*600 + v0+c4+2];
            if (v0+c4+3 < 600) av.w = A[w*600 + v0+c4+3];
          }
        }
        As[wv][c4+0][rr] = av.x; As[wv][c4+1][rr] = av.y;
        As[wv][c4+2][rr] = av.z; As[wv][c4+3][rr] = av.w;
      }
    }
    #pragma unroll
    for (int q = 0; q < 2; q++) {
      int m = q*64 + ln, rr = m >> 2, c4 = (m & 3)*4;
      int v = v0 + rr;
      float4 zv; zv.x = zv.y = zv.z = zv.w = 0.f;
      if (v < 600) {
        float ir = irx[v];
        float4 uv = *(const float4*)(u2x + v*16 + c4);
        zv.x = ir*uv.x; zv.y = ir*uv.y; zv.z = ir*uv.z; zv.w = ir*uv.w;
      }
      *(float4*)(&Zs[wv][rr][c4]) = zv;
    }
    __builtin_amdgcn_s_waitcnt(0);
    for (int vl = 0; vl < 32; vl++) {
      float4 a4 = *(const float4*)(&As[wv][vl][wq*4]);
      float2 z2 = *(const float2*)(&Zs[wv][vl][oq*2]);
      acc[0][0] = fmaf(a4.x, z2.x, acc[0][0]); acc[0][1] = fmaf(a4.x, z2.y, acc[0][1]);
      acc[1][0] = fmaf(a4.y, z2.x, acc[1][0]); acc[1][1] = fmaf(a4.y, z2.y, acc[1][1]);
      acc[2][0] = fmaf(a4.z, z2.x, acc[2][0]); acc[2][1] = fmaf(a4.z, z2.y, acc[2][1]);
      acc[3][0] = fmaf(a4.w, z2.x, acc[3][0]); acc[3][1] = fmaf(a4.w, z2.y, acc[3][1]);
    }
  }
  if (wv > 0) {
    #pragma unroll
    for (int kw = 0; kw < 4; kw++) {
      red[wv-1][ln][kw*2+0] = acc[kw][0];
      red[wv-1][ln][kw*2+1] = acc[kw][1];
    }
  }
  __syncthreads();
  if (wv == 0) {
    float* dst = ws + (d==0 ? OW_U3A : OW_U3B);
    #pragma unroll
    for (int kw = 0; kw < 4; kw++) {
      int w = w0 + wq*4 + kw;
      if (w >= 600) continue;
      float irw = irx[w];
      #pragma unroll
      for (int ko = 0; ko < 2; ko++) {
        int oz = oq*2 + ko;
        float sum = acc[kw][ko] + red[0][ln][kw*2+ko] + red[1][ln][kw*2+ko] + red[2][ln][kw*2+ko];
        sum += irw * u2x[w*16 + oz];
        dst[(ib*600 + w)*16 + oz] = sum;
      }
    }
  }
}

// ---------------- assemble head outputs ----------------
__global__ void k_outs(float* ws)
{
  int e = blockIdx.x*256 + threadIdx.x;
  if (e >= 153600) return;
  int n = e % 600, o = (e/600) % 16, b = (e/9600) % 4, s = e/38400;
  float val;
  if (s == 0) {
    val = ws[OW_T + (b*600+n)*256 + 240 + o];
  } else {
    int i = s - 1;
    int idx = ((i*4+b)*600 + n)*16 + o;
    float t0 = ws[OW_T + (b*600+n)*256 + i*80 + o];
    val = t0 + 0.95f  * (ws[OW_U1A+idx] + ws[OW_U1B+idx])
             + 0.0475f* (ws[OW_U2A+idx] + ws[OW_U2B+idx])
             + 0.9025f* (ws[OW_U3A+idx] + ws[OW_U3B+idx])
             + ws[OW_CSV + i*16 + o];
  }
  ws[OW_O + ((s*4+b)*16 + o)*600 + n] = val;
}

// ---------------- SE gate ----------------
__global__ void k_se(const float* gfW1, const float* gfW2, float* ws)
{
  __shared__ float sv[4][64], hb[4][4];
  int t = threadIdx.x, b = t >> 6, k = t & 63;
  const float* Op = ws + OW_O + (((k>>4)*4 + b)*16 + (k & 15))*600;
  float s = 0.f;
  for (int n = 0; n < 600; n++) s += Op[n];
  sv[b][k] = s * (1.f/600.f);
  __syncthreads();
  if (t < 16) {
    int bb = t >> 2, j = t & 3;
    float h = 0.f;
    for (int kk = 0; kk < 64; kk++) h += sv[bb][kk]*gfW1[kk*4+j];
    hb[bb][j] = h > 0.f ? h : 0.f;
  }
  __syncthreads();
  if (t < 16) {
    int bb = t >> 2, ii = t & 3;
    float g = 0.f;
    for (int j = 0; j < 4; j++) g += hb[bb][j]*gfW2[j*4+ii];
    ws[OW_SE + bb*4 + ii] = 1.f/(1.f + expf(-g));
  }
}

// ---------------- gate + end MLP (parallel final stage) ----------------
__global__ __launch_bounds__(128) void k_head(const float* e1W, const float* e1b,
                                              const float* e2W, const float* e2b,
                                              float* ws, float* dout)
{
  int blk = blockIdx.x, b = blk/600, n = blk%600;
  __shared__ float y0[16], y1[128];
  int t = threadIdx.x;
  if (t < 16) {
    float f = 0.f;
    for (int s = 0; s < 4; s++) f += ws[OW_SE + b*4 + s] * ws[OW_O + ((s*4+b)*16 + t)*600 + n];
    f *= 0.25f;
    y0[t] = f > 0.f ? f : 0.f;
  }
  __syncthreads();
  {
    float h = e1b[t];
    for (int o = 0; o < 16; o++) h += e1W[t*16+o]*y0[o];
    y1[t] = h > 0.f ? h : 0.f;
  }
  __syncthreads();
  if (t < 96) {
    int o = t >> 3, part = t & 7;   // 12 outputs x 8 partials
    float v = 0.f;
    #pragma unroll
    for (int e = 0; e < 16; e++) v = fmaf(e2W[o*128 + part*16 + e], y1[part*16 + e], v);
    #pragma unroll
    for (int s = 4; s; s >>= 1) v += __shfl_down(v, s, 8);
    if (part == 0) dout[b*7200 + o*600 + n] = e2b[o] + v;
  }
}

extern "C" void kernel_launch(void* const* d_in, const int* in_sizes, int n_in,
                              void* d_out, int out_size, void* d_ws, size_t ws_size,
                              hipStream_t stream)
{
  const float* x    = (const float*)d_in[0];
  const float* Ws   = (const float*)d_in[1];
  const float* bs   = (const float*)d_in[2];
  const float* scW0 = (const float*)d_in[3];
  const float* scW1 = (const float*)d_in[4];
  const float* scW2 = (const float*)d_in[5];
  const float* scb  = (const float*)d_in[6];
  const float* emb1 = (const float*)d_in[7];
  const float* emb2 = (const float*)d_in[8];
  const float* lin1W= (const float*)d_in[9];
  const float* lin1b= (const float*)d_in[10];
  const float* lin2W= (const float*)d_in[11];
  const float* lin2b= (const float*)d_in[12];
  const float* gW   = (const float*)d_in[13];
  const float* gb   = (const float*)d_in[14];
  const float* svW0 = (const float*)d_in[15];
  const float* svW1 = (const float*)d_in[16];
  const float* svW2 = (const float*)d_in[17];
  const float* svb  = (const float*)d_in[18];
  const float* s0W  = (const float*)d_in[19];
  const float* s0b  = (const float*)d_in[20];
  const float* gfW1 = (const float*)d_in[21];
  const float* gfW2 = (const float*)d_in[22];
  const float* e1W  = (const float*)d_in[23];
  const float* e1b  = (const float*)d_in[24];
  const float* e2W  = (const float*)d_in[25];
  const float* e2b  = (const float*)d_in[26];
  float* out = (float*)d_out;
  float* ws  = (float*)d_ws;
  double* wd = (double*)d_ws;
  float* adj_out = out + 28800;

  k_pre_wc<<<49, 256, 0, stream>>>(Ws, bs, scW0, scW1, scW2, scb,
                                   svW0, svW1, svW2, gb, svb, wd, ws);
  k_pre_p<<<15, 256, 0, stream>>>(svW0, svW1, svW2, gW, wd, ws);
  k_pre_v<<<256, 256, 0, stream>>>(svW0, svW1, svW2, s0W, s0b, wd, ws);
  k_fg<<<450, 256, 0, stream>>>(x, wd, ws);
  k_nodes<<<456, 256, 0, stream>>>(lin1W, lin1b, lin2W, lin2b, emb1, emb2, ws);
  k_adj<<<900, 256, 0, stream>>>(adj_out, ws);
  k_invrb<<<120, 256, 0, stream>>>(adj_out, ws);
  k_prop1<<<456, 256, 0, stream>>>(adj_out, ws);
  k_prop2<<<456, 256, 0, stream>>>(adj_out, ws);
  k_outs<<<600, 256, 0, stream>>>(ws);
  k_se<<<1, 256, 0, stream>>>(gfW1, gfW2, ws);
  k_head<<<2400, 128, 0, stream>>>(e1W, e1b, e2W, e2b, ws, out);
}

// Round 18
// 252.455 us; speedup vs baseline: 1.3571x; 1.3571x over previous
//
#include <hip/hip_runtime.h>
#include <math.h>

// ---------------- problem constants ----------------
// B=4, N=600, S=168, D=40, Cc=32, Cs=16, Ce=128, Od=12
// Adjacency path: bit-exact Eigen/MLIR fast-tanh (clamp 7.99881172180175781f,
// FMA Horner, |x|<0.0004 passthrough) + Eigen seq-FMA dots. PROVEN R7-R17.
// R18: k_pre_p fixed (gW+Weff staged in LDS, coalesced); cbig moved into
// k_pre_v via Q reduction. k_adj = proven R15; prop = proven R14.

// ---------------- workspace layout ----------------
#define DW_WEFF 0          // [3][32][16] doubles
#define DW_CC   1536       // [3][32]
#define DW_P    1632       // [3][5][32][16] doubles = 7680
#define DW_Q    9312       // [3][5][32] doubles = 480
#define FB      19584      // float offset = 2*9792
#define OW_CSV  (FB+0)
#define OW_CBIG (FB+48)
#define OW_VBIG (FB+304)
#define OW_T    (FB+760112)
#define OW_FEAT (FB+1374512)
#define OW_N1   (FB+1604912)
#define OW_N2   (FB+1892912)
#define OW_IRA  (FB+2180912)
#define OW_IRB  (FB+2188112)
#define OW_U1A  (FB+2195312)
#define OW_U2A  (FB+2310512)
#define OW_U1B  (FB+2425712)
#define OW_U2B  (FB+2540912)
#define OW_U3A  (FB+2656112)
#define OW_U3B  (FB+2771312)
#define OW_O    (FB+2886512)
#define OW_SE   (FB+3040112)

// ---------------- Eigen/MLIR fast tanh f32 (FMA build), bit-faithful ----------------
__device__ __forceinline__ float tanh_eigen(float x)
{
  const float CL = 7.99881172180175781f;
  float xc = fminf(fmaxf(x, -CL), CL);
  float x2 = __fmul_rn(xc, xc);
  float p = fmaf(x2, -2.76076847742355e-16f, 2.00018790482477e-13f);
  p = fmaf(x2, p, -8.60467152213735e-11f);
  p = fmaf(x2, p, 5.12229709037114e-08f);
  p = fmaf(x2, p, 1.48572235717979e-05f);
  p = fmaf(x2, p, 6.37261928875436e-04f);
  p = fmaf(x2, p, 4.89352455891786e-03f);
  p = __fmul_rn(xc, p);
  float q = fmaf(x2, 1.19825839466702e-06f, 1.18534705686654e-04f);
  q = fmaf(x2, q, 2.26843463243900e-03f);
  q = fmaf(x2, q, 4.89352518554385e-03f);
  float r = __fdiv_rn(p, q);
  return fabsf(x) < 0.0004f ? x : r;
}

// ---------------- fused: weff fold (block 48) + const_sv (blocks 0..47) ----------------
__global__ __launch_bounds__(256) void k_pre_wc(const float* Ws, const float* bs,
    const float* scW0, const float* scW1, const float* scW2, const float* scb,
    const float* svW0, const float* svW1, const float* svW2,
    const float* gb, const float* svb, double* wd, float* ws)
{
  if (blockIdx.x < 48) {
    int blk = blockIdx.x;
    int i = blk/16, o = blk%16;
    const float* svW = (i==0)?svW0:((i==1)?svW1:svW2);
    int L = (i==0)?162:((i==1)?79:39);
    int tid = threadIdx.x;
    __shared__ double red[256];
    double s = 0;
    for (int idx = tid; idx < 32*L; idx += 256) {
      int o2 = idx / L, l = idx - o2*L;
      s += (double)svW[(o*32+o2)*L + l] * ((double)gb[(i*2+0)*32+o2] + (double)gb[(i*2+1)*32+o2]);
    }
    red[tid] = s; __syncthreads();
    for (int st = 128; st; st >>= 1) { if (tid < st) red[tid] += red[tid+st]; __syncthreads(); }
    if (tid == 0) ws[OW_CSV + blk] = (float)(red[0] + (double)svb[i*16+o]);
    return;
  }
  __shared__ double w0[32][7], c0[32], w1[32][12], c1[32];
  int t = threadIdx.x;
  for (int e = t; e < 32*7; e += 256) {
    int c = e/7, p = e%7; double s = 0;
    for (int ci = 0; ci < 32; ci++) s += (double)scW0[(c*32+ci)*7+p] * (double)Ws[ci];
    w0[c][p] = s;
  }
  for (int e = t; e < 32; e += 256) {
    double s = 0;
    for (int ci = 0; ci < 32; ci++) { double a = 0; for (int p = 0; p < 7; p++) a += (double)scW0[(e*32+ci)*7+p]; s += a*(double)bs[ci]; }
    c0[e] = s + (double)scb[e];
  }
  __syncthreads();
  for (int e = t; e < 32*12; e += 256) {
    int c = e/12, m = e%12; double s = 0;
    for (int k1 = 0; k1 < 6; k1++) { int k0 = m - k1; if (k0 < 0 || k0 > 6) continue;
      for (int ci = 0; ci < 32; ci++) s += (double)scW1[(c*32+ci)*6+k1] * w0[ci][k0]; }
    w1[c][m] = s;
  }
  for (int e = t; e < 32; e += 256) {
    double s = 0;
    for (int ci = 0; ci < 32; ci++) { double a = 0; for (int k1 = 0; k1 < 6; k1++) a += (double)scW1[(e*32+ci)*6+k1]; s += a*c0[ci]; }
    c1[e] = s + (double)scb[32+e];
  }
  __syncthreads();
  for (int e = t; e < 32*16; e += 256) {
    int c = e/16, p = e%16; double s = 0;
    for (int k2 = 0; k2 < 3; k2++) { int m = p - 2*k2; if (m < 0 || m > 11) continue;
      for (int ci = 0; ci < 32; ci++) s += (double)scW2[(c*32+ci)*3+k2] * w1[ci][m]; }
    wd[DW_WEFF + (2*32+c)*16 + p] = s;
  }
  for (int e = t; e < 32; e += 256) {
    double s = 0;
    for (int ci = 0; ci < 32; ci++) { double a = 0; for (int k2 = 0; k2 < 3; k2++) a += (double)scW2[(e*32+ci)*3+k2]; s += a*c1[ci]; }
    wd[DW_CC + 64 + e] = s + (double)scb[64+e];
  }
  for (int e = t; e < 32*7;  e += 256) wd[DW_WEFF + (e/7)*16  + e%7 ] = w0[e/7][e%7];
  for (int e = t; e < 32*12; e += 256) wd[DW_WEFF + (32 + e/12)*16 + e%12] = w1[e/12][e%12];
  for (int e = t; e < 32; e += 256) { wd[DW_CC+e] = c0[e]; wd[DW_CC+32+e] = c1[e]; }
}

// ---------------- P[i][g][o2][p] + Q[i][g][o2]  (15 blocks, LDS-staged gW) ----------------
__global__ __launch_bounds__(256) void k_pre_p(const float* gW, double* wd)
{
  int blk = blockIdx.x;      // i*5+g
  int i = blk/5, g = blk%5;
  int tid = threadIdx.x;
  __shared__ float gls[2][3072];     // gW[i*2+0], gW[i*2+1] (96x32 each)
  __shared__ double weffs[512];      // Weff[i] (32x16)
  __shared__ double ccs[32];
  for (int e = tid; e < 6144; e += 256) gls[e >> 11 >= 1 ? (e/3072) : 0][e % 3072] = gW[i*6144 + e];
  for (int e = tid; e < 512; e += 256) weffs[e] = wd[DW_WEFF + i*512 + e];
  if (tid < 32) ccs[tid] = wd[DW_CC + i*32 + tid];
  __syncthreads();
  const float* g0 = gls[0];
  const float* g1 = gls[1];
  // P
  for (int e = tid; e < 512; e += 256) {
    int o2 = e >> 4, p = e & 15;
    double s = 0;
    for (int c = 0; c < 32; c++) {
      float w;
      if (g == 0) w = g0[c*32+o2] + g1[c*32+o2]
                    + 0.05f*(g0[(32+c)*32+o2] + g0[(64+c)*32+o2] + g1[(32+c)*32+o2] + g1[(64+c)*32+o2]);
      else if (g == 1) w = g0[(32+c)*32+o2];
      else if (g == 2) w = g0[(64+c)*32+o2];
      else if (g == 3) w = g1[(32+c)*32+o2];
      else             w = g1[(64+c)*32+o2];
      s += (double)w * weffs[c*16 + p];
    }
    wd[DW_P + ((i*5+g)*32 + o2)*16 + p] = s;
  }
  // Q
  if (tid < 32) {
    int o2 = tid;
    double s = 0;
    for (int c = 0; c < 32; c++) {
      float w;
      if (g == 0) w = g0[c*32+o2] + g1[c*32+o2]
                    + 0.05f*(g0[(32+c)*32+o2] + g0[(64+c)*32+o2] + g1[(32+c)*32+o2] + g1[(64+c)*32+o2]);
      else if (g == 1) w = g0[(32+c)*32+o2];
      else if (g == 2) w = g0[(64+c)*32+o2];
      else if (g == 3) w = g1[(32+c)*32+o2];
      else             w = g1[(64+c)*32+o2];
      s += (double)w * ccs[c];
    }
    wd[DW_Q + (i*5+g)*32 + o2] = s;
  }
}

// ---------------- t-path/out0 fused weight columns (svW x P) + cbig (svW x Q) ----------------
__global__ __launch_bounds__(256) void k_pre_v(const float* svW0, const float* svW1, const float* svW2,
                                               const float* s0W, const float* s0b, double* wd, float* ws)
{
  int jj = blockIdx.x;             // 0..255
  int tid = threadIdx.x;
  if (jj >= 240) {
    int o = jj - 240;
    if (tid < 168) ws[OW_VBIG + jj*168 + tid] = s0W[o*168 + tid];
    if (tid == 0)  ws[OW_CBIG + jj] = s0b[o];
    return;
  }
  int i = jj/80, g = (jj%80)/16, o = jj%16;
  int st = (i==0)?1:((i==1)?2:4), tp = (i==0)?7:((i==1)?12:16), L = (i==0)?162:((i==1)?79:39);
  const float* svW = (i==0)?svW0:((i==1)?svW1:svW2);
  const float* svo = svW + o*32*L;
  __shared__ float svlds[32*162];
  __shared__ double Pl[32][16];
  __shared__ double Qs[32];
  __shared__ double red[256];
  int NL = 32*L;
  for (int e = tid; e < NL; e += 256) svlds[e] = svo[e];
  for (int e = tid; e < 512; e += 256) {
    int o2 = e >> 4, p = e & 15;
    Pl[o2][p] = wd[DW_P + ((i*5+g)*32 + o2)*16 + p];
  }
  if (tid < 32) Qs[tid] = wd[DW_Q + (i*5+g)*32 + tid];
  __syncthreads();
  // cbig = sum svW * Q
  double s = 0;
  for (int e = tid; e < NL; e += 256) s += (double)svlds[e] * Qs[e / L];
  red[tid] = s; __syncthreads();
  for (int stp = 128; stp; stp >>= 1) { if (tid < stp) red[tid] += red[tid+stp]; __syncthreads(); }
  if (tid == 0) ws[OW_CBIG + jj] = (float)red[0];
  // column weights
  if (tid < 168) {
    int u = tid;
    int lo_ = u - tp + 1;
    int lmin = lo_ > 0 ? (lo_ + st - 1)/st : 0;
    int lmax = u/st; if (lmax > L-1) lmax = L-1;
    double v = 0.0;
    for (int o2 = 0; o2 < 32; o2++) {
      const float* sv = svlds + o2*L;
      const double* Pp = Pl[o2];
      for (int l = lmin; l <= lmax; l++)
        v += (double)sv[l] * Pp[u - st*l];
    }
    ws[OW_VBIG + jj*168 + u] = (float)v;
  }
}

// ---------------- fused: feat (blocks 0..299) + t-path GEMM (300..449) ----------------
__global__ __launch_bounds__(256) void k_fg(const float* x, double* wd, float* ws)
{
  int t = threadIdx.x;
  if (blockIdx.x >= 300) {
    __shared__ float xs[16][168];
    int r0 = (blockIdx.x - 300)*16;
    for (int e = t; e < 16*168; e += 256) { int r = e/168, u = e%168; xs[r][u] = x[(r0+r)*168 + u]; }
    __syncthreads();
    int jj = t;
    const float* V = ws + OW_VBIG + jj*168;
    double a[16];
    #pragma unroll
    for (int r = 0; r < 16; r++) a[r] = 0;
    for (int u = 0; u < 168; u++) {
      float wv = V[u];
      #pragma unroll
      for (int r = 0; r < 16; r++) a[r] += (double)wv * (double)xs[r][u];
    }
    double cb = (double)ws[OW_CBIG + jj];
    for (int r = 0; r < 16; r++)
      ws[OW_T + (r0+r)*256 + jj] = (float)(a[r] + cb);
    return;
  }
  int blk = blockIdx.x;      // 4*75
  int b = blk / 75, n0 = (blk % 75) * 8;
  __shared__ float xsf[8][168];
  __shared__ double xbar[8][35];
  for (int e = t; e < 8*168; e += 256) xsf[e/168][e%168] = x[(b*600 + n0 + e/168)*168 + e%168];
  __syncthreads();
  for (int e = t; e < 8*35; e += 256) {
    int nn = e/35, slot = e%35;
    int i = slot < 7 ? 0 : (slot < 19 ? 1 : 2);
    int p = slot - (i==0?0:(i==1?7:19));
    int st = (i==0)?1:((i==1)?2:4), L = (i==0)?162:((i==1)?79:39);
    double s = 0;
    for (int l = 0; l < L; l++) s += (double)xsf[nn][st*l+p];
    xbar[nn][slot] = s / (double)L;
  }
  __syncthreads();
  int nn = t >> 5, c = t & 31;
  for (int i = 0; i < 3; i++) {
    int off = (i==0)?0:((i==1)?7:19), tp = (i==0)?7:((i==1)?12:16);
    double f = wd[DW_CC + i*32 + c];
    for (int p = 0; p < tp; p++) f += wd[DW_WEFF + (i*32+c)*16 + p] * xbar[nn][off+p];
    ws[OW_FEAT + ((i*4+b)*600 + n0+nn)*32 + c] = (float)f;
  }
}

// ---------------- n1/n2: LDS-staged weights, 16 nodes per block ----------------
__global__ __launch_bounds__(256) void k_nodes(const float* lin1W, const float* lin1b,
                                               const float* lin2W, const float* lin2b,
                                               const float* emb1, const float* emb2, float* ws)
{
  int blk = blockIdx.x;  // i*152 + b*38 + nt
  int nt = blk % 38, b = (blk/38) % 4, i = blk/152;
  int n0 = nt*16;
  __shared__ float W1[1280], W2[1280], b1[40], b2[40], sf[16][33];
  int t = threadIdx.x;
  for (int e = t; e < 1280; e += 256) { W1[e] = lin1W[i*1280 + e]; W2[e] = lin2W[i*1280 + e]; }
  if (t < 40) { b1[t] = lin1b[i*40 + t]; b2[t] = lin2b[i*40 + t]; }
  for (int e = t; e < 16*32; e += 256) {
    int nn = e >> 5, c = e & 31; int n = n0 + nn;
    sf[nn][c] = (n < 600) ? ws[OW_FEAT + ((i*4+b)*600 + n)*32 + c] : 0.f;
  }
  __syncthreads();
  const float TSF[3] = {3.0f, 2.4f, 1.8f};
  for (int item = t; item < 16*80; item += 256) {
    int nn = item / 80, rr = item % 80;
    int n = n0 + nn; if (n >= 600) continue;
    int which = rr/40, d = rr%40;
    const float* W  = which ? W2 : W1;
    const float* bv = which ? b2 : b1;
    const float* em = which ? emb2 : emb1;
    float pre = 0.f;
    #pragma unroll
    for (int c = 0; c < 32; c++) pre = fmaf(sf[nn][c], W[c*40+d], pre);
    float p2 = __fadd_rn(pre, bv[d]);
    float p3 = __fadd_rn(p2, em[n*40+d]);
    float arg = __fmul_rn(TSF[i], p3);
    ws[(which ? OW_N2 : OW_N1) + ((i*4+b)*600 + n)*40 + d] = tanh_eigen(arg);
  }
}

// ---------------- adjacency staging helpers ----------------
__device__ __forceinline__ float4 adj_ld(const float* n1, const float* n2, int e, int w0)
{
  int mat = e >= 320; int idx = e - 320*mat;
  int jj = idx/10, q = idx - 10*jj;
  int w = w0 + jj;
  if (w < 600) return *(const float4*)((mat ? n2 : n1) + w*40 + 4*q);
  float4 z; z.x = z.y = z.z = z.w = 0.f; return z;
}

// ---------------- adjacency: R15 proven (8-way broadcast + staged + svals) ----------------
__global__ __launch_bounds__(256) void k_adj(float* adj_out, float* ws)
{
  int blk = blockIdx.x;                 // 3*4*75
  int tile = blk % 75, b = (blk/75) % 4, i = blk/300;
  int row0 = tile*8;
  const float* n1 = ws + OW_N1 + (i*4+b)*24000;
  const float* n2 = ws + OW_N2 + (i*4+b)*24000;
  __shared__ float c1s[32][44], c2s[32][44];
  __shared__ float svals[8][604];       // 604%32==28: conflict-free
  int t = threadIdx.x;
  int rc = t & 7, jc = t >> 3;          // 8 lanes share each column address
  float am1[40], am2[40];
  {
    const float4* m1p = (const float4*)(n1 + (row0 + rc)*40);
    const float4* m2p = (const float4*)(n2 + (row0 + rc)*40);
    #pragma unroll
    for (int q = 0; q < 10; q++) {
      float4 v1 = m1p[q], v2 = m2p[q];
      am1[4*q]=v1.x; am1[4*q+1]=v1.y; am1[4*q+2]=v1.z; am1[4*q+3]=v1.w;
      am2[4*q]=v2.x; am2[4*q+1]=v2.y; am2[4*q+2]=v2.z; am2[4*q+3]=v2.w;
    }
  }
  float4 s0 = adj_ld(n1, n2, t, 0);
  float4 s1 = adj_ld(n1, n2, t + 256, 0);
  float4 s2; if (t < 128) s2 = adj_ld(n1, n2, t + 512, 0);
  for (int k = 0; k < 19; k++) {
    int w0 = 32*k;
    __syncthreads();
    {
      int e = t;       { int mat=e>=320, idx=e-320*mat, jj=idx/10, q=idx-10*jj, w=w0+jj;
                         if (w<600) *(float4*)(&(mat?c2s:c1s)[jj][4*q]) = s0; }
      e = t + 256;     { int mat=e>=320, idx=e-320*mat, jj=idx/10, q=idx-10*jj, w=w0+jj;
                         if (w<600) *(float4*)(&(mat?c2s:c1s)[jj][4*q]) = s1; }
      if (t < 128) { e = t + 512; int mat=e>=320, idx=e-320*mat, jj=idx/10, q=idx-10*jj, w=w0+jj;
                         if (w<600) *(float4*)(&(mat?c2s:c1s)[jj][4*q]) = s2; }
    }
    __syncthreads();
    if (k < 18) {
      int w0n = w0 + 32;
      s0 = adj_ld(n1, n2, t, w0n);
      s1 = adj_ld(n1, n2, t + 256, w0n);
      if (t < 128) s2 = adj_ld(n1, n2, t + 512, w0n);
    }
    if (jc < 32) {
      int w = w0 + jc;
      if (w < 600) {
        const float4* c2p = (const float4*)c2s[jc];
        const float4* c1p = (const float4*)c1s[jc];
        float d1 = 0.f, d2 = 0.f;
        #pragma unroll
        for (int q = 0; q < 10; q++) {
          float4 v = c2p[q];
          d1 = fmaf(am1[4*q], v.x, d1); d1 = fmaf(am1[4*q+1], v.y, d1);
          d1 = fmaf(am1[4*q+2], v.z, d1); d1 = fmaf(am1[4*q+3], v.w, d1);
        }
        #pragma unroll
        for (int q = 0; q < 10; q++) {
          float4 v = c1p[q];
          d2 = fmaf(am2[4*q], v.x, d2); d2 = fmaf(am2[4*q+1], v.y, d2);
          d2 = fmaf(am2[4*q+2], v.z, d2); d2 = fmaf(am2[4*q+3], v.w, d2);
        }
        float af = __fsub_rn(d1, d2);
        float tv = __fmul_rn(3.0f, af);
        float v = tanh_eigen(tv);
        svals[rc][w] = v > 0.f ? v : 0.f;       // relu
      }
    }
  }
  __syncthreads();
  // ---- top-k phase: proven logic, vv from svals ----
  int r = t >> 5, j = t & 31;
  float vv[19];
  #pragma unroll
  for (int k = 0; k < 19; k++) {
    int w = j + 32*k;
    vv[k] = (w < 600) ? svals[r][w] : 0.f;
  }
  float rm = 0.f;
  #pragma unroll
  for (int k = 0; k < 19; k++) rm = fmaxf(rm, vv[k]);
  #pragma unroll
  for (int s = 16; s; s >>= 1) rm = fmaxf(rm, __shfl_xor(rm, s, 32));
  const float VP = tanh_eigen(8.0f);
  unsigned int vpb = __float_as_uint(VP);
  int cntp = 0;
  #pragma unroll
  for (int k = 0; k < 19; k++) { int w = j + 32*k; if (w < 600 && __float_as_uint(vv[k]) >= vpb) cntp++; }
  #pragma unroll
  for (int s = 16; s; s >>= 1) cntp += __shfl_xor(cntp, s, 32);
  unsigned int lo, hi;
  unsigned int mb1 = __float_as_uint(rm) + 1u;
  if (cntp >= 20) { lo = vpb; hi = mb1; }
  else            { lo = 0u;  hi = vpb < mb1 ? vpb : mb1; }
  while (hi - lo > 1u) {
    unsigned int mid = lo + ((hi - lo) >> 1);
    int cnt = 0;
    #pragma unroll
    for (int k = 0; k < 19; k++) {
      int w = j + 32*k;
      if (w < 600 && __float_as_uint(vv[k]) >= mid) cnt++;
    }
    #pragma unroll
    for (int s = 16; s; s >>= 1) cnt += __shfl_xor(cnt, s, 32);
    if (cnt >= 20) lo = mid; else hi = mid;
  }
  unsigned int kb = lo;
  float* arow = adj_out + (i*4+b)*360000 + (row0+r)*600;
  float rsum = 0.f;
  #pragma unroll
  for (int k = 0; k < 19; k++) {
    int w = j + 32*k;
    if (w < 600) {
      float v = (__float_as_uint(vv[k]) >= kb) ? vv[k] : 0.f;
      arow[w] = v;
      rsum += v;
    }
  }
  #pragma unroll
  for (int s = 16; s; s >>= 1) rsum += __shfl_xor(rsum, s, 32);
  if (j == 0) ws[OW_IRA + (i*4+b)*600 + row0 + r] = 1.f/(1.f + rsum);
}

// ---------------- column sums (parallel: 120 blocks) ----------------
__global__ __launch_bounds__(256) void k_invrb(const float* adj, float* ws)
{
  int blk = blockIdx.x;            // ib*10 + wt
  int ib = blk / 10, wt = blk % 10;
  int tid = threadIdx.x;
  int wl = tid & 63, vg = tid >> 6;
  int w = wt*64 + wl;
  const float* A = adj + ib*360000;
  float s = 0.f;
  if (w < 600) {
    for (int v = vg*150; v < vg*150 + 150; v++) s += A[v*600 + w];
  }
  __shared__ float red[4][64];
  red[vg][wl] = s;
  __syncthreads();
  if (vg == 0 && w < 600) {
    float tot = ((red[0][wl] + red[1][wl]) + red[2][wl]) + red[3][wl];
    ws[OW_IRB + ib*600 + w] = 1.f/(1.f + tot);
  }
}

// ---------------- prop1: 4w x 4oz per thread, per-wave K-split, b128 LDS ----------------
__global__ __launch_bounds__(256) void k_prop1(const float* adj, float* ws)
{
  int blk = blockIdx.x;            // ib*38 + d*19 + wt
  int wt = blk % 19;
  int d  = (blk / 19) & 1;
  int ib = blk / 38;
  int i = ib >> 2, b = ib & 3;
  int w0 = wt * 32;
  const float* A   = adj + ib*360000;
  const float* irx = ws + (d ? OW_IRB : OW_IRA) + ib*600;
  const float* Tb  = ws + OW_T + (b*600)*256 + i*80 + 16 + d*32;
  __shared__ float As[4][32][36];
  __shared__ float Zs[4][32][36];
  __shared__ float red[3][64][17];
  int tid = threadIdx.x;
  int wv = tid >> 6, ln = tid & 63;
  int wq = ln >> 3, oq = ln & 7;
  float acc[4][4];
  #pragma unroll
  for (int a1 = 0; a1 < 4; a1++)
    #pragma unroll
    for (int a2 = 0; a2 < 4; a2++) acc[a1][a2] = 0.f;
  int vbeg = wv*160, vend = vbeg + 160 < 600 ? vbeg + 160 : 600;
  for (int v0 = vbeg; v0 < vend; v0 += 32) {
    if (d == 0) {
      #pragma unroll
      for (int q = 0; q < 4; q++) {
        int m = q*64 + ln, rr = m >> 3, c4 = (m & 7)*4;
        int v = v0 + rr;
        float4 av; av.x = av.y = av.z = av.w = 0.f;
        if (v < 600) {
          int wb = w0 + c4;
          if (wb + 3 < 600) av = *(const float4*)(A + v*600 + wb);
          else {
            if (wb+0 < 600) av.x = A[v*600 + wb+0];
            if (wb+1 < 600) av.y = A[v*600 + wb+1];
            if (wb+2 < 600) av.z = A[v*600 + wb+2];
            if (wb+3 < 600) av.w = A[v*600 + wb+3];
          }
        }
        *(float4*)(&As[wv][rr][c4]) = av;
      }
    } else {
      #pragma unroll
      for (int q = 0; q < 4; q++) {
        int m = q*64 + ln, rr = m >> 3, c4 = (m & 7)*4;
        int w = w0 + rr;
        float4 av; av.x = av.y = av.z = av.w = 0.f;
        if (w < 600) {
          if (v0 + c4 + 3 < 600) av = *(const float4*)(A + w*600 + v0 + c4);
          else {
            if (v0+c4+0 < 600) av.x = A[w*600 + v0+c4+0];
            if (v0+c4+1 < 600) av.y = A[w*600 + v0+c4+1];
            if (v0+c4+2 < 600) av.z = A[w*600 + v0+c4+2];
            if (v0+c4+3 < 600) av.w = A[w*600 + v0+c4+3];
          }
        }
        As[wv][c4+0][rr] = av.x; As[wv][c4+1][rr] = av.y;
        As[wv][c4+2][rr] = av.z; As[wv][c4+3][rr] = av.w;
      }
    }
    #pragma unroll
    for (int q = 0; q < 4; q++) {
      int m = q*64 + ln, rr = m >> 3, c4 = (m & 7)*4;
      int v = v0 + rr;
      float4 zv; zv.x = zv.y = zv.z = zv.w = 0.f;
      if (v < 600) {
        float ir = irx[v];
        float4 tv = *(const float4*)(Tb + v*256 + c4);
        zv.x = ir*tv.x; zv.y = ir*tv.y; zv.z = ir*tv.z; zv.w = ir*tv.w;
      }
      *(float4*)(&Zs[wv][rr][c4]) = zv;
    }
    __builtin_amdgcn_s_waitcnt(0);
    for (int vl = 0; vl < 32; vl++) {
      float4 a4 = *(const float4*)(&As[wv][vl][wq*4]);
      float4 z4 = *(const float4*)(&Zs[wv][vl][oq*4]);
      acc[0][0] = fmaf(a4.x, z4.x, acc[0][0]); acc[0][1] = fmaf(a4.x, z4.y, acc[0][1]);
      acc[0][2] = fmaf(a4.x, z4.z, acc[0][2]); acc[0][3] = fmaf(a4.x, z4.w, acc[0][3]);
      acc[1][0] = fmaf(a4.y, z4.x, acc[1][0]); acc[1][1] = fmaf(a4.y, z4.y, acc[1][1]);
      acc[1][2] = fmaf(a4.y, z4.z, acc[1][2]); acc[1][3] = fmaf(a4.y, z4.w, acc[1][3]);
      acc[2][0] = fmaf(a4.z, z4.x, acc[2][0]); acc[2][1] = fmaf(a4.z, z4.y, acc[2][1]);
      acc[2][2] = fmaf(a4.z, z4.z, acc[2][2]); acc[2][3] = fmaf(a4.z, z4.w, acc[2][3]);
      acc[3][0] = fmaf(a4.w, z4.x, acc[3][0]); acc[3][1] = fmaf(a4.w, z4.y, acc[3][1]);
      acc[3][2] = fmaf(a4.w, z4.z, acc[3][2]); acc[3][3] = fmaf(a4.w, z4.w, acc[3][3]);
    }
  }
  if (wv > 0) {
    #pragma unroll
    for (int kw = 0; kw < 4; kw++)
      #pragma unroll
      for (int ko = 0; ko < 4; ko++) red[wv-1][ln][kw*4+ko] = acc[kw][ko];
  }
  __syncthreads();
  if (wv == 0) {
    #pragma unroll
    for (int kw = 0; kw < 4; kw++) {
      int w = w0 + wq*4 + kw;
      if (w >= 600) continue;
      float irw = irx[w];
      #pragma unroll
      for (int ko = 0; ko < 4; ko++) {
        int oz = oq*4 + ko;
        float sum = acc[kw][ko] + red[0][ln][kw*4+ko] + red[1][ln][kw*4+ko] + red[2][ln][kw*4+ko];
        sum += irw * Tb[w*256 + oz];
        float* dst = ws + (d==0 ? (oz < 16 ? OW_U1A : OW_U2A) : (oz < 16 ? OW_U1B : OW_U2B));
        dst[(ib*600 + w)*16 + (oz & 15)] = sum;
      }
    }
  }
}

// ---------------- prop2: 4w x 2oz per thread, per-wave K-split ----------------
__global__ __launch_bounds__(256) void k_prop2(const float* adj, float* ws)
{
  int blk = blockIdx.x;            // ib*38 + d*19 + wt
  int wt = blk % 19;
  int d  = (blk / 19) & 1;
  int ib = blk / 38;
  int w0 = wt * 32;
  const float* A   = adj + ib*360000;
  const float* irx = ws + (d ? OW_IRB : OW_IRA) + ib*600;
  const float* u2x = ws + (d ? OW_U2B : OW_U2A) + ib*9600;
  __shared__ float As[4][32][36];
  __shared__ float Zs[4][32][20];
  __shared__ float red[3][64][9];
  int tid = threadIdx.x;
  int wv = tid >> 6, ln = tid & 63;
  int wq = ln >> 3, oq = ln & 7;
  float acc[4][2];
  #pragma unroll
  for (int a1 = 0; a1 < 4; a1++) { acc[a1][0] = 0.f; acc[a1][1] = 0.f; }
  int vbeg = wv*160, vend = vbeg + 160 < 600 ? vbeg + 160 : 600;
  for (int v0 = vbeg; v0 < vend; v0 += 32) {
    if (d == 0) {
      #pragma unroll
      for (int q = 0; q < 4; q++) {
        int m = q*64 + ln, rr = m >> 3, c4 = (m & 7)*4;
        int v = v0 + rr;
        float4 av; av.x = av.y = av.z = av.w = 0.f;
        if (v < 600) {
          int wb = w0 + c4;
          if (wb + 3 < 600) av = *(const float4*)(A + v*600 + wb);
          else {
            if (wb+0 < 600) av.x = A[v*600 + wb+0];
            if (wb+1 < 600) av.y = A[v*600 + wb+1];
            if (wb+2 < 600) av.z = A[v*600 + wb+2];
            if (wb+3 < 600) av.w = A[v*600 + wb+3];
          }
        }
        *(float4*)(&As[wv][rr][c4]) = av;
      }
    } else {
      #pragma unroll
      for (int q = 0; q < 4; q++) {
        int m = q*64 + ln, rr = m >> 3, c4 = (m & 7)*4;
        int w = w0 + rr;
        float4 av; av.x = av.y = av.z = av.w = 0.f;
        if (w < 600) {
          if (v0 + c4 + 3 < 600) av = *(const float4*)(A + w*600 + v0 + c4);
          else {
            if (v0+c4+0 < 600) av.x = A[w*600 + v0+c4+0];
            if (v0+c4+1 < 600) av.y = A[w*600 + v0+c4+1];
            if (v0+c4+2 < 600) av.z = A[w*600 + v0+c4+2];
            if (v0+c4+3 < 600) av.w = A[w*600 + v0+c4+3];
          }
        }
        As[wv][c4+0][rr] = av.x; As[wv][c4+1][rr] = av.y;
        As[wv][c4+2][rr] = av.z; As[wv][c4+3][rr] = av.w;
      }
    }
    #pragma unroll
    for (int q = 0; q < 2; q++) {
      int m = q*64 + ln, rr = m >> 2, c4 = (m & 3)*4;
      int v = v0 + rr;
      float4 zv; zv.x = zv.y = zv.z = zv.w = 0.f;
      if (v < 600) {
        float ir = irx[v];
        float4 uv = *(const float4*)(u2x + v*16 + c4);
        zv.x = ir*uv.x; zv.y = ir*uv.y; zv.z = ir*uv.z; zv.w = ir*uv.w;
      }
      *(float4*)(&Zs[wv][rr][c4]) = zv;
    }
    __builtin_amdgcn_s_waitcnt(0);
    for (int vl = 0; vl < 32; vl++) {
      float4 a4 = *(const float4*)(&As[wv][vl][wq*4]);
      float2 z2 = *(const float2*)(&Zs[wv][vl][oq*2]);
      acc[0][0] = fmaf(a4.x, z2.x, acc[0][0]); acc[0][1] = fmaf(a4.x, z2.y, acc[0][1]);
      acc[1][0] = fmaf(a4.y, z2.x, acc[1][0]); acc[1][1] = fmaf(a4.y, z2.y, acc[1][1]);
      acc[2][0] = fmaf(a4.z, z2.x, acc[2][0]); acc[2][1] = fmaf(a4.z, z2.y, acc[2][1]);
      acc[3][0] = fmaf(a4.w, z2.x, acc[3][0]); acc[3][1] = fmaf(a4.w, z2.y, acc[3][1]);
    }
  }
  if (wv > 0) {
    #pragma unroll
    for (int kw = 0; kw < 4; kw++) {
      red[wv-1][ln][kw*2+0] = acc[kw][0];
      red[wv-1][ln][kw*2+1] = acc[kw][1];
    }
  }
  __syncthreads();
  if (wv == 0) {
    float* dst = ws + (d==0 ? OW_U3A : OW_U3B);
    #pragma unroll
    for (int kw = 0; kw < 4; kw++) {
      int w = w0 + wq*4 + kw;
      if (w >= 600) continue;
      float irw = irx[w];
      #pragma unroll
      for (int ko = 0; ko < 2; ko++) {
        int oz = oq*2 + ko;
        float sum = acc[kw][ko] + red[0][ln][kw*2+ko] + red[1][ln][kw*2+ko] + red[2][ln][kw*2+ko];
        sum += irw * u2x[w*16 + oz];
        dst[(ib*600 + w)*16 + oz] = sum;
      }
    }
  }
}

// ---------------- assemble head outputs ----------------
__global__ void k_outs(float* ws)
{
  int e = blockIdx.x*256 + threadIdx.x;
  if (e >= 153600) return;
  int n = e % 600, o = (e/600) % 16, b = (e/9600) % 4, s = e/38400;
  float val;
  if (s == 0) {
    val = ws[OW_T + (b*600+n)*256 + 240 + o];
  } else {
    int i = s - 1;
    int idx = ((i*4+b)*600 + n)*16 + o;
    float t0 = ws[OW_T + (b*600+n)*256 + i*80 + o];
    val = t0 + 0.95f  * (ws[OW_U1A+idx] + ws[OW_U1B+idx])
             + 0.0475f* (ws[OW_U2A+idx] + ws[OW_U2B+idx])
             + 0.9025f* (ws[OW_U3A+idx] + ws[OW_U3B+idx])
             + ws[OW_CSV + i*16 + o];
  }
  ws[OW_O + ((s*4+b)*16 + o)*600 + n] = val;
}

// ---------------- SE gate ----------------
__global__ void k_se(const float* gfW1, const float* gfW2, float* ws)
{
  __shared__ float sv[4][64], hb[4][4];
  int t = threadIdx.x, b = t >> 6, k = t & 63;
  const float* Op = ws + OW_O + (((k>>4)*4 + b)*16 + (k & 15))*600;
  float s = 0.f;
  for (int n = 0; n < 600; n++) s += Op[n];
  sv[b][k] = s * (1.f/600.f);
  __syncthreads();
  if (t < 16) {
    int bb = t >> 2, j = t & 3;
    float h = 0.f;
    for (int kk = 0; kk < 64; kk++) h += sv[bb][kk]*gfW1[kk*4+j];
    hb[bb][j] = h > 0.f ? h : 0.f;
  }
  __syncthreads();
  if (t < 16) {
    int bb = t >> 2, ii = t & 3;
    float g = 0.f;
    for (int j = 0; j < 4; j++) g += hb[bb][j]*gfW2[j*4+ii];
    ws[OW_SE + bb*4 + ii] = 1.f/(1.f + expf(-g));
  }
}

// ---------------- gate + end MLP (parallel final stage) ----------------
__global__ __launch_bounds__(128) void k_head(const float* e1W, const float* e1b,
                                              const float* e2W, const float* e2b,
                                              float* ws, float* dout)
{
  int blk = blockIdx.x, b = blk/600, n = blk%600;
  __shared__ float y0[16], y1[128];
  int t = threadIdx.x;
  if (t < 16) {
    float f = 0.f;
    for (int s = 0; s < 4; s++) f += ws[OW_SE + b*4 + s] * ws[OW_O + ((s*4+b)*16 + t)*600 + n];
    f *= 0.25f;
    y0[t] = f > 0.f ? f : 0.f;
  }
  __syncthreads();
  {
    float h = e1b[t];
    for (int o = 0; o < 16; o++) h += e1W[t*16+o]*y0[o];
    y1[t] = h > 0.f ? h : 0.f;
  }
  __syncthreads();
  if (t < 96) {
    int o = t >> 3, part = t & 7;   // 12 outputs x 8 partials
    float v = 0.f;
    #pragma unroll
    for (int e = 0; e < 16; e++) v = fmaf(e2W[o*128 + part*16 + e], y1[part*16 + e], v);
    #pragma unroll
    for (int s = 4; s; s >>= 1) v += __shfl_down(v, s, 8);
    if (part == 0) dout[b*7200 + o*600 + n] = e2b[o] + v;
  }
}

extern "C" void kernel_launch(void* const* d_in, const int* in_sizes, int n_in,
                              void* d_out, int out_size, void* d_ws, size_t ws_size,
                              hipStream_t stream)
{
  const float* x    = (const float*)d_in[0];
  const float* Ws   = (const float*)d_in[1];
  const float* bs   = (const float*)d_in[2];
  const float* scW0 = (const float*)d_in[3];
  const float* scW1 = (const float*)d_in[4];
  const float* scW2 = (const float*)d_in[5];
  const float* scb  = (const float*)d_in[6];
  const float* emb1 = (const float*)d_in[7];
  const float* emb2 = (const float*)d_in[8];
  const float* lin1W= (const float*)d_in[9];
  const float* lin1b= (const float*)d_in[10];
  const float* lin2W= (const float*)d_in[11];
  const float* lin2b= (const float*)d_in[12];
  const float* gW   = (const float*)d_in[13];
  const float* gb   = (const float*)d_in[14];
  const float* svW0 = (const float*)d_in[15];
  const float* svW1 = (const float*)d_in[16];
  const float* svW2 = (const float*)d_in[17];
  const float* svb  = (const float*)d_in[18];
  const float* s0W  = (const float*)d_in[19];
  const float* s0b  = (const float*)d_in[20];
  const float* gfW1 = (const float*)d_in[21];
  const float* gfW2 = (const float*)d_in[22];
  const float* e1W  = (const float*)d_in[23];
  const float* e1b  = (const float*)d_in[24];
  const float* e2W  = (const float*)d_in[25];
  const float* e2b  = (const float*)d_in[26];
  float* out = (float*)d_out;
  float* ws  = (float*)d_ws;
  double* wd = (double*)d_ws;
  float* adj_out = out + 28800;

  k_pre_wc<<<49, 256, 0, stream>>>(Ws, bs, scW0, scW1, scW2, scb,
                                   svW0, svW1, svW2, gb, svb, wd, ws);
  k_pre_p<<<15, 256, 0, stream>>>(gW, wd);
  k_pre_v<<<256, 256, 0, stream>>>(svW0, svW1, svW2, s0W, s0b, wd, ws);
  k_fg<<<450, 256, 0, stream>>>(x, wd, ws);
  k_nodes<<<456, 256, 0, stream>>>(lin1W, lin1b, lin2W, lin2b, emb1, emb2, ws);
  k_adj<<<900, 256, 0, stream>>>(adj_out, ws);
  k_invrb<<<120, 256, 0, stream>>>(adj_out, ws);
  k_prop1<<<456, 256, 0, stream>>>(adj_out, ws);
  k_prop2<<<456, 256, 0, stream>>>(adj_out, ws);
  k_outs<<<600, 256, 0, stream>>>(ws);
  k_se<<<1, 256, 0, stream>>>(gfW1, gfW2, ws);
  k_head<<<2400, 128, 0, stream>>>(e1W, e1b, e2W, e2b, ws, out);
}

// Round 19
// 236.426 us; speedup vs baseline: 1.4491x; 1.0678x over previous
//
#include <hip/hip_runtime.h>
#include <math.h>

// ---------------- problem constants ----------------
// B=4, N=600, S=168, D=40, Cc=32, Cs=16, Ce=128, Od=12
// Adjacency path: bit-exact Eigen/MLIR fast-tanh (clamp 7.99881172180175781f,
// FMA Horner, |x|<0.0004 passthrough) + Eigen seq-FMA dots. PROVEN R7-R18.
// R19: k_adj double-buffered column tiles (19 barriers vs 38, writes overlap
// compute); SE row sums fused into k_outs (k_se single-block load loop gone).

// ---------------- workspace layout ----------------
#define DW_WEFF 0          // [3][32][16] doubles
#define DW_CC   1536       // [3][32]
#define DW_P    1632       // [3][5][32][16] doubles = 7680
#define DW_Q    9312       // [3][5][32] doubles = 480
#define FB      19584      // float offset = 2*9792
#define OW_CSV  (FB+0)
#define OW_CBIG (FB+48)
#define OW_VBIG (FB+304)
#define OW_T    (FB+760112)
#define OW_FEAT (FB+1374512)
#define OW_N1   (FB+1604912)
#define OW_N2   (FB+1892912)
#define OW_IRA  (FB+2180912)
#define OW_IRB  (FB+2188112)
#define OW_U1A  (FB+2195312)
#define OW_U2A  (FB+2310512)
#define OW_U1B  (FB+2425712)
#define OW_U2B  (FB+2540912)
#define OW_U3A  (FB+2656112)
#define OW_U3B  (FB+2771312)
#define OW_O    (FB+2886512)
#define OW_SE   (FB+3040112)   // [16]
#define OW_SVS  (FB+3040128)   // [256] per-(s,b,o) row sums (atomic)

// ---------------- Eigen/MLIR fast tanh f32 (FMA build), bit-faithful ----------------
__device__ __forceinline__ float tanh_eigen(float x)
{
  const float CL = 7.99881172180175781f;
  float xc = fminf(fmaxf(x, -CL), CL);
  float x2 = __fmul_rn(xc, xc);
  float p = fmaf(x2, -2.76076847742355e-16f, 2.00018790482477e-13f);
  p = fmaf(x2, p, -8.60467152213735e-11f);
  p = fmaf(x2, p, 5.12229709037114e-08f);
  p = fmaf(x2, p, 1.48572235717979e-05f);
  p = fmaf(x2, p, 6.37261928875436e-04f);
  p = fmaf(x2, p, 4.89352455891786e-03f);
  p = __fmul_rn(xc, p);
  float q = fmaf(x2, 1.19825839466702e-06f, 1.18534705686654e-04f);
  q = fmaf(x2, q, 2.26843463243900e-03f);
  q = fmaf(x2, q, 4.89352518554385e-03f);
  float r = __fdiv_rn(p, q);
  return fabsf(x) < 0.0004f ? x : r;
}

// ---------------- fused: weff fold (block 48) + const_sv (blocks 0..47) ----------------
__global__ __launch_bounds__(256) void k_pre_wc(const float* Ws, const float* bs,
    const float* scW0, const float* scW1, const float* scW2, const float* scb,
    const float* svW0, const float* svW1, const float* svW2,
    const float* gb, const float* svb, double* wd, float* ws)
{
  if (blockIdx.x < 48) {
    int blk = blockIdx.x;
    int i = blk/16, o = blk%16;
    const float* svW = (i==0)?svW0:((i==1)?svW1:svW2);
    int L = (i==0)?162:((i==1)?79:39);
    int tid = threadIdx.x;
    __shared__ double red[256];
    double s = 0;
    for (int idx = tid; idx < 32*L; idx += 256) {
      int o2 = idx / L, l = idx - o2*L;
      s += (double)svW[(o*32+o2)*L + l] * ((double)gb[(i*2+0)*32+o2] + (double)gb[(i*2+1)*32+o2]);
    }
    red[tid] = s; __syncthreads();
    for (int st = 128; st; st >>= 1) { if (tid < st) red[tid] += red[tid+st]; __syncthreads(); }
    if (tid == 0) ws[OW_CSV + blk] = (float)(red[0] + (double)svb[i*16+o]);
    return;
  }
  __shared__ double w0[32][7], c0[32], w1[32][12], c1[32];
  int t = threadIdx.x;
  for (int e = t; e < 32*7; e += 256) {
    int c = e/7, p = e%7; double s = 0;
    for (int ci = 0; ci < 32; ci++) s += (double)scW0[(c*32+ci)*7+p] * (double)Ws[ci];
    w0[c][p] = s;
  }
  for (int e = t; e < 32; e += 256) {
    double s = 0;
    for (int ci = 0; ci < 32; ci++) { double a = 0; for (int p = 0; p < 7; p++) a += (double)scW0[(e*32+ci)*7+p]; s += a*(double)bs[ci]; }
    c0[e] = s + (double)scb[e];
  }
  __syncthreads();
  for (int e = t; e < 32*12; e += 256) {
    int c = e/12, m = e%12; double s = 0;
    for (int k1 = 0; k1 < 6; k1++) { int k0 = m - k1; if (k0 < 0 || k0 > 6) continue;
      for (int ci = 0; ci < 32; ci++) s += (double)scW1[(c*32+ci)*6+k1] * w0[ci][k0]; }
    w1[c][m] = s;
  }
  for (int e = t; e < 32; e += 256) {
    double s = 0;
    for (int ci = 0; ci < 32; ci++) { double a = 0; for (int k1 = 0; k1 < 6; k1++) a += (double)scW1[(e*32+ci)*6+k1]; s += a*c0[ci]; }
    c1[e] = s + (double)scb[32+e];
  }
  __syncthreads();
  for (int e = t; e < 32*16; e += 256) {
    int c = e/16, p = e%16; double s = 0;
    for (int k2 = 0; k2 < 3; k2++) { int m = p - 2*k2; if (m < 0 || m > 11) continue;
      for (int ci = 0; ci < 32; ci++) s += (double)scW2[(c*32+ci)*3+k2] * w1[ci][m]; }
    wd[DW_WEFF + (2*32+c)*16 + p] = s;
  }
  for (int e = t; e < 32; e += 256) {
    double s = 0;
    for (int ci = 0; ci < 32; ci++) { double a = 0; for (int k2 = 0; k2 < 3; k2++) a += (double)scW2[(e*32+ci)*3+k2]; s += a*c1[ci]; }
    wd[DW_CC + 64 + e] = s + (double)scb[64+e];
  }
  for (int e = t; e < 32*7;  e += 256) wd[DW_WEFF + (e/7)*16  + e%7 ] = w0[e/7][e%7];
  for (int e = t; e < 32*12; e += 256) wd[DW_WEFF + (32 + e/12)*16 + e%12] = w1[e/12][e%12];
  for (int e = t; e < 32; e += 256) { wd[DW_CC+e] = c0[e]; wd[DW_CC+32+e] = c1[e]; }
}

// ---------------- P[i][g][o2][p] + Q[i][g][o2]  (15 blocks, LDS-staged gW) ----------------
__global__ __launch_bounds__(256) void k_pre_p(const float* gW, double* wd)
{
  int blk = blockIdx.x;      // i*5+g
  int i = blk/5, g = blk%5;
  int tid = threadIdx.x;
  __shared__ float gls[2][3072];
  __shared__ double weffs[512];
  __shared__ double ccs[32];
  for (int e = tid; e < 6144; e += 256) gls[e/3072][e % 3072] = gW[i*6144 + e];
  for (int e = tid; e < 512; e += 256) weffs[e] = wd[DW_WEFF + i*512 + e];
  if (tid < 32) ccs[tid] = wd[DW_CC + i*32 + tid];
  __syncthreads();
  const float* g0 = gls[0];
  const float* g1 = gls[1];
  for (int e = tid; e < 512; e += 256) {
    int o2 = e >> 4, p = e & 15;
    double s = 0;
    for (int c = 0; c < 32; c++) {
      float w;
      if (g == 0) w = g0[c*32+o2] + g1[c*32+o2]
                    + 0.05f*(g0[(32+c)*32+o2] + g0[(64+c)*32+o2] + g1[(32+c)*32+o2] + g1[(64+c)*32+o2]);
      else if (g == 1) w = g0[(32+c)*32+o2];
      else if (g == 2) w = g0[(64+c)*32+o2];
      else if (g == 3) w = g1[(32+c)*32+o2];
      else             w = g1[(64+c)*32+o2];
      s += (double)w * weffs[c*16 + p];
    }
    wd[DW_P + ((i*5+g)*32 + o2)*16 + p] = s;
  }
  if (tid < 32) {
    int o2 = tid;
    double s = 0;
    for (int c = 0; c < 32; c++) {
      float w;
      if (g == 0) w = g0[c*32+o2] + g1[c*32+o2]
                    + 0.05f*(g0[(32+c)*32+o2] + g0[(64+c)*32+o2] + g1[(32+c)*32+o2] + g1[(64+c)*32+o2]);
      else if (g == 1) w = g0[(32+c)*32+o2];
      else if (g == 2) w = g0[(64+c)*32+o2];
      else if (g == 3) w = g1[(32+c)*32+o2];
      else             w = g1[(64+c)*32+o2];
      s += (double)w * ccs[c];
    }
    wd[DW_Q + (i*5+g)*32 + o2] = s;
  }
}

// ---------------- t-path/out0 fused weight columns (svW x P) + cbig (svW x Q) ----------------
__global__ __launch_bounds__(256) void k_pre_v(const float* svW0, const float* svW1, const float* svW2,
                                               const float* s0W, const float* s0b, double* wd, float* ws)
{
  int jj = blockIdx.x;             // 0..255
  int tid = threadIdx.x;
  if (jj >= 240) {
    int o = jj - 240;
    if (tid < 168) ws[OW_VBIG + jj*168 + tid] = s0W[o*168 + tid];
    if (tid == 0)  ws[OW_CBIG + jj] = s0b[o];
    return;
  }
  int i = jj/80, g = (jj%80)/16, o = jj%16;
  int st = (i==0)?1:((i==1)?2:4), tp = (i==0)?7:((i==1)?12:16), L = (i==0)?162:((i==1)?79:39);
  const float* svW = (i==0)?svW0:((i==1)?svW1:svW2);
  const float* svo = svW + o*32*L;
  __shared__ float svlds[32*162];
  __shared__ double Pl[32][16];
  __shared__ double Qs[32];
  __shared__ double red[256];
  int NL = 32*L;
  for (int e = tid; e < NL; e += 256) svlds[e] = svo[e];
  for (int e = tid; e < 512; e += 256) {
    int o2 = e >> 4, p = e & 15;
    Pl[o2][p] = wd[DW_P + ((i*5+g)*32 + o2)*16 + p];
  }
  if (tid < 32) Qs[tid] = wd[DW_Q + (i*5+g)*32 + tid];
  __syncthreads();
  double s = 0;
  for (int e = tid; e < NL; e += 256) s += (double)svlds[e] * Qs[e / L];
  red[tid] = s; __syncthreads();
  for (int stp = 128; stp; stp >>= 1) { if (tid < stp) red[tid] += red[tid+stp]; __syncthreads(); }
  if (tid == 0) ws[OW_CBIG + jj] = (float)red[0];
  if (tid < 168) {
    int u = tid;
    int lo_ = u - tp + 1;
    int lmin = lo_ > 0 ? (lo_ + st - 1)/st : 0;
    int lmax = u/st; if (lmax > L-1) lmax = L-1;
    double v = 0.0;
    for (int o2 = 0; o2 < 32; o2++) {
      const float* sv = svlds + o2*L;
      const double* Pp = Pl[o2];
      for (int l = lmin; l <= lmax; l++)
        v += (double)sv[l] * Pp[u - st*l];
    }
    ws[OW_VBIG + jj*168 + u] = (float)v;
  }
}

// ---------------- fused: feat (blocks 0..299) + t-path GEMM (300..449) ----------------
__global__ __launch_bounds__(256) void k_fg(const float* x, double* wd, float* ws)
{
  int t = threadIdx.x;
  if (blockIdx.x >= 300) {
    __shared__ float xs[16][168];
    int r0 = (blockIdx.x - 300)*16;
    for (int e = t; e < 16*168; e += 256) { int r = e/168, u = e%168; xs[r][u] = x[(r0+r)*168 + u]; }
    __syncthreads();
    int jj = t;
    const float* V = ws + OW_VBIG + jj*168;
    double a[16];
    #pragma unroll
    for (int r = 0; r < 16; r++) a[r] = 0;
    for (int u = 0; u < 168; u++) {
      float wv = V[u];
      #pragma unroll
      for (int r = 0; r < 16; r++) a[r] += (double)wv * (double)xs[r][u];
    }
    double cb = (double)ws[OW_CBIG + jj];
    for (int r = 0; r < 16; r++)
      ws[OW_T + (r0+r)*256 + jj] = (float)(a[r] + cb);
    return;
  }
  int blk = blockIdx.x;      // 4*75
  int b = blk / 75, n0 = (blk % 75) * 8;
  __shared__ float xsf[8][168];
  __shared__ double xbar[8][35];
  for (int e = t; e < 8*168; e += 256) xsf[e/168][e%168] = x[(b*600 + n0 + e/168)*168 + e%168];
  __syncthreads();
  for (int e = t; e < 8*35; e += 256) {
    int nn = e/35, slot = e%35;
    int i = slot < 7 ? 0 : (slot < 19 ? 1 : 2);
    int p = slot - (i==0?0:(i==1?7:19));
    int st = (i==0)?1:((i==1)?2:4), L = (i==0)?162:((i==1)?79:39);
    double s = 0;
    for (int l = 0; l < L; l++) s += (double)xsf[nn][st*l+p];
    xbar[nn][slot] = s / (double)L;
  }
  __syncthreads();
  int nn = t >> 5, c = t & 31;
  for (int i = 0; i < 3; i++) {
    int off = (i==0)?0:((i==1)?7:19), tp = (i==0)?7:((i==1)?12:16);
    double f = wd[DW_CC + i*32 + c];
    for (int p = 0; p < tp; p++) f += wd[DW_WEFF + (i*32+c)*16 + p] * xbar[nn][off+p];
    ws[OW_FEAT + ((i*4+b)*600 + n0+nn)*32 + c] = (float)f;
  }
}

// ---------------- n1/n2: LDS-staged weights, 16 nodes per block ----------------
__global__ __launch_bounds__(256) void k_nodes(const float* lin1W, const float* lin1b,
                                               const float* lin2W, const float* lin2b,
                                               const float* emb1, const float* emb2, float* ws)
{
  int blk = blockIdx.x;  // i*152 + b*38 + nt
  int nt = blk % 38, b = (blk/38) % 4, i = blk/152;
  int n0 = nt*16;
  __shared__ float W1[1280], W2[1280], b1[40], b2[40], sf[16][33];
  int t = threadIdx.x;
  for (int e = t; e < 1280; e += 256) { W1[e] = lin1W[i*1280 + e]; W2[e] = lin2W[i*1280 + e]; }
  if (t < 40) { b1[t] = lin1b[i*40 + t]; b2[t] = lin2b[i*40 + t]; }
  for (int e = t; e < 16*32; e += 256) {
    int nn = e >> 5, c = e & 31; int n = n0 + nn;
    sf[nn][c] = (n < 600) ? ws[OW_FEAT + ((i*4+b)*600 + n)*32 + c] : 0.f;
  }
  __syncthreads();
  const float TSF[3] = {3.0f, 2.4f, 1.8f};
  for (int item = t; item < 16*80; item += 256) {
    int nn = item / 80, rr = item % 80;
    int n = n0 + nn; if (n >= 600) continue;
    int which = rr/40, d = rr%40;
    const float* W  = which ? W2 : W1;
    const float* bv = which ? b2 : b1;
    const float* em = which ? emb2 : emb1;
    float pre = 0.f;
    #pragma unroll
    for (int c = 0; c < 32; c++) pre = fmaf(sf[nn][c], W[c*40+d], pre);
    float p2 = __fadd_rn(pre, bv[d]);
    float p3 = __fadd_rn(p2, em[n*40+d]);
    float arg = __fmul_rn(TSF[i], p3);
    ws[(which ? OW_N2 : OW_N1) + ((i*4+b)*600 + n)*40 + d] = tanh_eigen(arg);
  }
}

// ---------------- adjacency staging helper ----------------
__device__ __forceinline__ float4 adj_ld(const float* n1, const float* n2, int e, int w0)
{
  int mat = e >= 320; int idx = e - 320*mat;
  int jj = idx/10, q = idx - 10*jj;
  int w = w0 + jj;
  if (w < 600) return *(const float4*)((mat ? n2 : n1) + w*40 + 4*q);
  float4 z; z.x = z.y = z.z = z.w = 0.f; return z;
}

// ---------------- adjacency: double-buffered tiles (1 barrier/tile) + svals + top-k ----------------
__global__ __launch_bounds__(256) void k_adj(float* adj_out, float* ws)
{
  int blk = blockIdx.x;                 // 3*4*75
  int tile = blk % 75, b = (blk/75) % 4, i = blk/300;
  int row0 = tile*8;
  const float* n1 = ws + OW_N1 + (i*4+b)*24000;
  const float* n2 = ws + OW_N2 + (i*4+b)*24000;
  __shared__ float c1s[2][32][44], c2s[2][32][44];
  __shared__ float svals[8][604];       // 604%32==28: conflict-free
  int t = threadIdx.x;
  int rc = t & 7, jc = t >> 3;          // 8 lanes share each column address
  float am1[40], am2[40];
  {
    const float4* m1p = (const float4*)(n1 + (row0 + rc)*40);
    const float4* m2p = (const float4*)(n2 + (row0 + rc)*40);
    #pragma unroll
    for (int q = 0; q < 10; q++) {
      float4 v1 = m1p[q], v2 = m2p[q];
      am1[4*q]=v1.x; am1[4*q+1]=v1.y; am1[4*q+2]=v1.z; am1[4*q+3]=v1.w;
      am2[4*q]=v2.x; am2[4*q+1]=v2.y; am2[4*q+2]=v2.z; am2[4*q+3]=v2.w;
    }
  }
  // decompose thread -> staging slots (same mapping as R15/R18)
  int e0 = t,       m0 = e0 >= 320, i0 = e0 - 320*m0, j0 = i0/10, q0 = i0 - 10*j0;
  int e1 = t + 256, m1_ = e1 >= 320, i1 = e1 - 320*m1_, j1 = i1/10, q1 = i1 - 10*j1;
  int e2 = t + 512, m2_ = 1,        i2 = e2 - 320,     j2 = i2/10, q2 = i2 - 10*j2;
  float4 s0, s1, s2;
  // prologue: tile0 -> buf0, issue tile1
  s0 = adj_ld(n1, n2, t, 0); s1 = adj_ld(n1, n2, t + 256, 0); if (t < 128) s2 = adj_ld(n1, n2, t + 512, 0);
  { int w;
    w = 0 + j0; if (w < 600) *(float4*)(&(m0 ? c2s : c1s)[0][j0][4*q0]) = s0;
    w = 0 + j1; if (w < 600) *(float4*)(&(m1_ ? c2s : c1s)[0][j1][4*q1]) = s1;
    if (t < 128) { w = 0 + j2; if (w < 600) *(float4*)(&c2s[0][j2][4*q2]) = s2; }
  }
  s0 = adj_ld(n1, n2, t, 32); s1 = adj_ld(n1, n2, t + 256, 32); if (t < 128) s2 = adj_ld(n1, n2, t + 512, 32);
  __syncthreads();
  for (int k = 0; k < 19; k++) {
    int cur = k & 1;
    int w0 = 32*k;
    if (k < 18) {                       // write tile k+1 into buf[cur^1] (free since barrier k-1)
      int w0n = w0 + 32; int w;
      w = w0n + j0; if (w < 600) *(float4*)(&(m0 ? c2s : c1s)[cur^1][j0][4*q0]) = s0;
      w = w0n + j1; if (w < 600) *(float4*)(&(m1_ ? c2s : c1s)[cur^1][j1][4*q1]) = s1;
      if (t < 128) { w = w0n + j2; if (w < 600) *(float4*)(&c2s[cur^1][j2][4*q2]) = s2; }
      if (k < 17) {                     // issue loads for tile k+2
        int w0nn = w0 + 64;
        s0 = adj_ld(n1, n2, t, w0nn);
        s1 = adj_ld(n1, n2, t + 256, w0nn);
        if (t < 128) s2 = adj_ld(n1, n2, t + 512, w0nn);
      }
    }
    // compute tile k from buf[cur]
    {
      int w = w0 + jc;
      if (w < 600) {
        const float4* c2p = (const float4*)c2s[cur][jc];
        const float4* c1p = (const float4*)c1s[cur][jc];
        float d1 = 0.f, d2 = 0.f;
        #pragma unroll
        for (int q = 0; q < 10; q++) {          // ascending d, single accumulator: bit-exact
          float4 v = c2p[q];
          d1 = fmaf(am1[4*q], v.x, d1); d1 = fmaf(am1[4*q+1], v.y, d1);
          d1 = fmaf(am1[4*q+2], v.z, d1); d1 = fmaf(am1[4*q+3], v.w, d1);
        }
        #pragma unroll
        for (int q = 0; q < 10; q++) {
          float4 v = c1p[q];
          d2 = fmaf(am2[4*q], v.x, d2); d2 = fmaf(am2[4*q+1], v.y, d2);
          d2 = fmaf(am2[4*q+2], v.z, d2); d2 = fmaf(am2[4*q+3], v.w, d2);
        }
        float af = __fsub_rn(d1, d2);
        float tv = __fmul_rn(3.0f, af);
        float v = tanh_eigen(tv);
        svals[rc][w] = v > 0.f ? v : 0.f;       // relu
      }
    }
    __syncthreads();
  }
  // ---- top-k phase: proven logic, vv from svals ----
  int r = t >> 5, j = t & 31;
  float vv[19];
  #pragma unroll
  for (int k = 0; k < 19; k++) {
    int w = j + 32*k;
    vv[k] = (w < 600) ? svals[r][w] : 0.f;
  }
  float rm = 0.f;
  #pragma unroll
  for (int k = 0; k < 19; k++) rm = fmaxf(rm, vv[k]);
  #pragma unroll
  for (int s = 16; s; s >>= 1) rm = fmaxf(rm, __shfl_xor(rm, s, 32));
  const float VP = tanh_eigen(8.0f);
  unsigned int vpb = __float_as_uint(VP);
  int cntp = 0;
  #pragma unroll
  for (int k = 0; k < 19; k++) { int w = j + 32*k; if (w < 600 && __float_as_uint(vv[k]) >= vpb) cntp++; }
  #pragma unroll
  for (int s = 16; s; s >>= 1) cntp += __shfl_xor(cntp, s, 32);
  unsigned int lo, hi;
  unsigned int mb1 = __float_as_uint(rm) + 1u;
  if (cntp >= 20) { lo = vpb; hi = mb1; }
  else            { lo = 0u;  hi = vpb < mb1 ? vpb : mb1; }
  while (hi - lo > 1u) {
    unsigned int mid = lo + ((hi - lo) >> 1);
    int cnt = 0;
    #pragma unroll
    for (int k = 0; k < 19; k++) {
      int w = j + 32*k;
      if (w < 600 && __float_as_uint(vv[k]) >= mid) cnt++;
    }
    #pragma unroll
    for (int s = 16; s; s >>= 1) cnt += __shfl_xor(cnt, s, 32);
    if (cnt >= 20) lo = mid; else hi = mid;
  }
  unsigned int kb = lo;
  float* arow = adj_out + (i*4+b)*360000 + (row0+r)*600;
  float rsum = 0.f;
  #pragma unroll
  for (int k = 0; k < 19; k++) {
    int w = j + 32*k;
    if (w < 600) {
      float v = (__float_as_uint(vv[k]) >= kb) ? vv[k] : 0.f;
      arow[w] = v;
      rsum += v;
    }
  }
  #pragma unroll
  for (int s = 16; s; s >>= 1) rsum += __shfl_xor(rsum, s, 32);
  if (j == 0) ws[OW_IRA + (i*4+b)*600 + row0 + r] = 1.f/(1.f + rsum);
}

// ---------------- column sums (parallel: 120 blocks) ----------------
__global__ __launch_bounds__(256) void k_invrb(const float* adj, float* ws)
{
  int blk = blockIdx.x;            // ib*10 + wt
  int ib = blk / 10, wt = blk % 10;
  int tid = threadIdx.x;
  int wl = tid & 63, vg = tid >> 6;
  int w = wt*64 + wl;
  const float* A = adj + ib*360000;
  float s = 0.f;
  if (w < 600) {
    for (int v = vg*150; v < vg*150 + 150; v++) s += A[v*600 + w];
  }
  __shared__ float red[4][64];
  red[vg][wl] = s;
  __syncthreads();
  if (vg == 0 && w < 600) {
    float tot = ((red[0][wl] + red[1][wl]) + red[2][wl]) + red[3][wl];
    ws[OW_IRB + ib*600 + w] = 1.f/(1.f + tot);
  }
}

// ---------------- prop1: 4w x 4oz per thread, per-wave K-split, b128 LDS ----------------
__global__ __launch_bounds__(256) void k_prop1(const float* adj, float* ws)
{
  int blk = blockIdx.x;            // ib*38 + d*19 + wt
  int wt = blk % 19;
  int d  = (blk / 19) & 1;
  int ib = blk / 38;
  int i = ib >> 2, b = ib & 3;
  int w0 = wt * 32;
  const float* A   = adj + ib*360000;
  const float* irx = ws + (d ? OW_IRB : OW_IRA) + ib*600;
  const float* Tb  = ws + OW_T + (b*600)*256 + i*80 + 16 + d*32;
  __shared__ float As[4][32][36];
  __shared__ float Zs[4][32][36];
  __shared__ float red[3][64][17];
  int tid = threadIdx.x;
  int wv = tid >> 6, ln = tid & 63;
  int wq = ln >> 3, oq = ln & 7;
  float acc[4][4];
  #pragma unroll
  for (int a1 = 0; a1 < 4; a1++)
    #pragma unroll
    for (int a2 = 0; a2 < 4; a2++) acc[a1][a2] = 0.f;
  int vbeg = wv*160, vend = vbeg + 160 < 600 ? vbeg + 160 : 600;
  for (int v0 = vbeg; v0 < vend; v0 += 32) {
    if (d == 0) {
      #pragma unroll
      for (int q = 0; q < 4; q++) {
        int m = q*64 + ln, rr = m >> 3, c4 = (m & 7)*4;
        int v = v0 + rr;
        float4 av; av.x = av.y = av.z = av.w = 0.f;
        if (v < 600) {
          int wb = w0 + c4;
          if (wb + 3 < 600) av = *(const float4*)(A + v*600 + wb);
          else {
            if (wb+0 < 600) av.x = A[v*600 + wb+0];
            if (wb+1 < 600) av.y = A[v*600 + wb+1];
            if (wb+2 < 600) av.z = A[v*600 + wb+2];
            if (wb+3 < 600) av.w = A[v*600 + wb+3];
          }
        }
        *(float4*)(&As[wv][rr][c4]) = av;
      }
    } else {
      #pragma unroll
      for (int q = 0; q < 4; q++) {
        int m = q*64 + ln, rr = m >> 3, c4 = (m & 7)*4;
        int w = w0 + rr;
        float4 av; av.x = av.y = av.z = av.w = 0.f;
        if (w < 600) {
          if (v0 + c4 + 3 < 600) av = *(const float4*)(A + w*600 + v0 + c4);
          else {
            if (v0+c4+0 < 600) av.x = A[w*600 + v0+c4+0];
            if (v0+c4+1 < 600) av.y = A[w*600 + v0+c4+1];
            if (v0+c4+2 < 600) av.z = A[w*600 + v0+c4+2];
            if (v0+c4+3 < 600) av.w = A[w*600 + v0+c4+3];
          }
        }
        As[wv][c4+0][rr] = av.x; As[wv][c4+1][rr] = av.y;
        As[wv][c4+2][rr] = av.z; As[wv][c4+3][rr] = av.w;
      }
    }
    #pragma unroll
    for (int q = 0; q < 4; q++) {
      int m = q*64 + ln, rr = m >> 3, c4 = (m & 7)*4;
      int v = v0 + rr;
      float4 zv; zv.x = zv.y = zv.z = zv.w = 0.f;
      if (v < 600) {
        float ir = irx[v];
        float4 tv = *(const float4*)(Tb + v*256 + c4);
        zv.x = ir*tv.x; zv.y = ir*tv.y; zv.z = ir*tv.z; zv.w = ir*tv.w;
      }
      *(float4*)(&Zs[wv][rr][c4]) = zv;
    }
    __builtin_amdgcn_s_waitcnt(0);
    for (int vl = 0; vl < 32; vl++) {
      float4 a4 = *(const float4*)(&As[wv][vl][wq*4]);
      float4 z4 = *(const float4*)(&Zs[wv][vl][oq*4]);
      acc[0][0] = fmaf(a4.x, z4.x, acc[0][0]); acc[0][1] = fmaf(a4.x, z4.y, acc[0][1]);
      acc[0][2] = fmaf(a4.x, z4.z, acc[0][2]); acc[0][3] = fmaf(a4.x, z4.w, acc[0][3]);
      acc[1][0] = fmaf(a4.y, z4.x, acc[1][0]); acc[1][1] = fmaf(a4.y, z4.y, acc[1][1]);
      acc[1][2] = fmaf(a4.y, z4.z, acc[1][2]); acc[1][3] = fmaf(a4.y, z4.w, acc[1][3]);
      acc[2][0] = fmaf(a4.z, z4.x, acc[2][0]); acc[2][1] = fmaf(a4.z, z4.y, acc[2][1]);
      acc[2][2] = fmaf(a4.z, z4.z, acc[2][2]); acc[2][3] = fmaf(a4.z, z4.w, acc[2][3]);
      acc[3][0] = fmaf(a4.w, z4.x, acc[3][0]); acc[3][1] = fmaf(a4.w, z4.y, acc[3][1]);
      acc[3][2] = fmaf(a4.w, z4.z, acc[3][2]); acc[3][3] = fmaf(a4.w, z4.w, acc[3][3]);
    }
  }
  if (wv > 0) {
    #pragma unroll
    for (int kw = 0; kw < 4; kw++)
      #pragma unroll
      for (int ko = 0; ko < 4; ko++) red[wv-1][ln][kw*4+ko] = acc[kw][ko];
  }
  __syncthreads();
  if (wv == 0) {
    #pragma unroll
    for (int kw = 0; kw < 4; kw++) {
      int w = w0 + wq*4 + kw;
      if (w >= 600) continue;
      float irw = irx[w];
      #pragma unroll
      for (int ko = 0; ko < 4; ko++) {
        int oz = oq*4 + ko;
        float sum = acc[kw][ko] + red[0][ln][kw*4+ko] + red[1][ln][kw*4+ko] + red[2][ln][kw*4+ko];
        sum += irw * Tb[w*256 + oz];
        float* dst = ws + (d==0 ? (oz < 16 ? OW_U1A : OW_U2A) : (oz < 16 ? OW_U1B : OW_U2B));
        dst[(ib*600 + w)*16 + (oz & 15)] = sum;
      }
    }
  }
}

// ---------------- prop2: 4w x 2oz per thread, per-wave K-split ----------------
__global__ __launch_bounds__(256) void k_prop2(const float* adj, float* ws)
{
  int blk = blockIdx.x;            // ib*38 + d*19 + wt
  int wt = blk % 19;
  int d  = (blk / 19) & 1;
  int ib = blk / 38;
  int w0 = wt * 32;
  const float* A   = adj + ib*360000;
  const float* irx = ws + (d ? OW_IRB : OW_IRA) + ib*600;
  const float* u2x = ws + (d ? OW_U2B : OW_U2A) + ib*9600;
  __shared__ float As[4][32][36];
  __shared__ float Zs[4][32][20];
  __shared__ float red[3][64][9];
  int tid = threadIdx.x;
  int wv = tid >> 6, ln = tid & 63;
  int wq = ln >> 3, oq = ln & 7;
  float acc[4][2];
  #pragma unroll
  for (int a1 = 0; a1 < 4; a1++) { acc[a1][0] = 0.f; acc[a1][1] = 0.f; }
  int vbeg = wv*160, vend = vbeg + 160 < 600 ? vbeg + 160 : 600;
  for (int v0 = vbeg; v0 < vend; v0 += 32) {
    if (d == 0) {
      #pragma unroll
      for (int q = 0; q < 4; q++) {
        int m = q*64 + ln, rr = m >> 3, c4 = (m & 7)*4;
        int v = v0 + rr;
        float4 av; av.x = av.y = av.z = av.w = 0.f;
        if (v < 600) {
          int wb = w0 + c4;
          if (wb + 3 < 600) av = *(const float4*)(A + v*600 + wb);
          else {
            if (wb+0 < 600) av.x = A[v*600 + wb+0];
            if (wb+1 < 600) av.y = A[v*600 + wb+1];
            if (wb+2 < 600) av.z = A[v*600 + wb+2];
            if (wb+3 < 600) av.w = A[v*600 + wb+3];
          }
        }
        *(float4*)(&As[wv][rr][c4]) = av;
      }
    } else {
      #pragma unroll
      for (int q = 0; q < 4; q++) {
        int m = q*64 + ln, rr = m >> 3, c4 = (m & 7)*4;
        int w = w0 + rr;
        float4 av; av.x = av.y = av.z = av.w = 0.f;
        if (w < 600) {
          if (v0 + c4 + 3 < 600) av = *(const float4*)(A + w*600 + v0 + c4);
          else {
            if (v0+c4+0 < 600) av.x = A[w*600 + v0+c4+0];
            if (v0+c4+1 < 600) av.y = A[w*600 + v0+c4+1];
            if (v0+c4+2 < 600) av.z = A[w*600 + v0+c4+2];
            if (v0+c4+3 < 600) av.w = A[w*600 + v0+c4+3];
          }
        }
        As[wv][c4+0][rr] = av.x; As[wv][c4+1][rr] = av.y;
        As[wv][c4+2][rr] = av.z; As[wv][c4+3][rr] = av.w;
      }
    }
    #pragma unroll
    for (int q = 0; q < 2; q++) {
      int m = q*64 + ln, rr = m >> 2, c4 = (m & 3)*4;
      int v = v0 + rr;
      float4 zv; zv.x = zv.y = zv.z = zv.w = 0.f;
      if (v < 600) {
        float ir = irx[v];
        float4 uv = *(const float4*)(u2x + v*16 + c4);
        zv.x = ir*uv.x; zv.y = ir*uv.y; zv.z = ir*uv.z; zv.w = ir*uv.w;
      }
      *(float4*)(&Zs[wv][rr][c4]) = zv;
    }
    __builtin_amdgcn_s_waitcnt(0);
    for (int vl = 0; vl < 32; vl++) {
      float4 a4 = *(const float4*)(&As[wv][vl][wq*4]);
      float2 z2 = *(const float2*)(&Zs[wv][vl][oq*2]);
      acc[0][0] = fmaf(a4.x, z2.x, acc[0][0]); acc[0][1] = fmaf(a4.x, z2.y, acc[0][1]);
      acc[1][0] = fmaf(a4.y, z2.x, acc[1][0]); acc[1][1] = fmaf(a4.y, z2.y, acc[1][1]);
      acc[2][0] = fmaf(a4.z, z2.x, acc[2][0]); acc[2][1] = fmaf(a4.z, z2.y, acc[2][1]);
      acc[3][0] = fmaf(a4.w, z2.x, acc[3][0]); acc[3][1] = fmaf(a4.w, z2.y, acc[3][1]);
    }
  }
  if (wv > 0) {
    #pragma unroll
    for (int kw = 0; kw < 4; kw++) {
      red[wv-1][ln][kw*2+0] = acc[kw][0];
      red[wv-1][ln][kw*2+1] = acc[kw][1];
    }
  }
  __syncthreads();
  if (wv == 0) {
    float* dst = ws + (d==0 ? OW_U3A : OW_U3B);
    #pragma unroll
    for (int kw = 0; kw < 4; kw++) {
      int w = w0 + wq*4 + kw;
      if (w >= 600) continue;
      float irw = irx[w];
      #pragma unroll
      for (int ko = 0; ko < 2; ko++) {
        int oz = oq*2 + ko;
        float sum = acc[kw][ko] + red[0][ln][kw*2+ko] + red[1][ln][kw*2+ko] + red[2][ln][kw*2+ko];
        sum += irw * u2x[w*16 + oz];
        dst[(ib*600 + w)*16 + oz] = sum;
      }
    }
  }
}

// ---------------- assemble head outputs + fused SE row sums ----------------
__global__ __launch_bounds__(256) void k_outs(float* ws)
{
  __shared__ float sums[2];
  int tid = threadIdx.x;
  int e = blockIdx.x*256 + tid;
  int rA = (blockIdx.x*256)/600;
  if (tid < 2) sums[tid] = 0.f;
  __syncthreads();
  float val = 0.f;
  int row = rA;
  if (e < 153600) {
    int n = e % 600, o = (e/600) % 16, b = (e/9600) % 4, s = e/38400;
    if (s == 0) {
      val = ws[OW_T + (b*600+n)*256 + 240 + o];
    } else {
      int i = s - 1;
      int idx = ((i*4+b)*600 + n)*16 + o;
      float t0 = ws[OW_T + (b*600+n)*256 + i*80 + o];
      val = t0 + 0.95f  * (ws[OW_U1A+idx] + ws[OW_U1B+idx])
               + 0.0475f* (ws[OW_U2A+idx] + ws[OW_U2B+idx])
               + 0.9025f* (ws[OW_U3A+idx] + ws[OW_U3B+idx])
               + ws[OW_CSV + i*16 + o];
    }
    ws[OW_O + ((s*4+b)*16 + o)*600 + n] = val;
    row = e/600;
  }
  // segmented wave reduce (<=2 distinct rows per block)
  float vA = (e < 153600 && row == rA) ? val : 0.f;
  float vB = (e < 153600 && row == rA+1) ? val : 0.f;
  #pragma unroll
  for (int s = 32; s; s >>= 1) { vA += __shfl_down(vA, s, 64); vB += __shfl_down(vB, s, 64); }
  if ((tid & 63) == 0) {
    if (vA != 0.f) atomicAdd(&sums[0], vA);
    if (vB != 0.f) atomicAdd(&sums[1], vB);
  }
  __syncthreads();
  if (tid < 2) {
    int r = rA + tid;
    if (r < 256) atomicAdd(&ws[OW_SVS + r], sums[tid]);
  }
}

// ---------------- SE gate (reads fused sums) ----------------
__global__ void k_se(const float* gfW1, const float* gfW2, float* ws)
{
  __shared__ float sv[4][64], hb[4][4];
  int t = threadIdx.x;
  {
    int row = t;
    int o = row & 15, b = (row >> 4) & 3, s = row >> 6;
    sv[b][s*16 + o] = ws[OW_SVS + row] * (1.f/600.f);
  }
  __syncthreads();
  if (t < 16) {
    int bb = t >> 2, j = t & 3;
    float h = 0.f;
    for (int kk = 0; kk < 64; kk++) h += sv[bb][kk]*gfW1[kk*4+j];
    hb[bb][j] = h > 0.f ? h : 0.f;
  }
  __syncthreads();
  if (t < 16) {
    int bb = t >> 2, ii = t & 3;
    float g = 0.f;
    for (int j = 0; j < 4; j++) g += hb[bb][j]*gfW2[j*4+ii];
    ws[OW_SE + bb*4 + ii] = 1.f/(1.f + expf(-g));
  }
}

// ---------------- gate + end MLP (parallel final stage) ----------------
__global__ __launch_bounds__(128) void k_head(const float* e1W, const float* e1b,
                                              const float* e2W, const float* e2b,
                                              float* ws, float* dout)
{
  int blk = blockIdx.x, b = blk/600, n = blk%600;
  __shared__ float y0[16], y1[128];
  int t = threadIdx.x;
  if (t < 16) {
    float f = 0.f;
    for (int s = 0; s < 4; s++) f += ws[OW_SE + b*4 + s] * ws[OW_O + ((s*4+b)*16 + t)*600 + n];
    f *= 0.25f;
    y0[t] = f > 0.f ? f : 0.f;
  }
  __syncthreads();
  {
    float h = e1b[t];
    for (int o = 0; o < 16; o++) h += e1W[t*16+o]*y0[o];
    y1[t] = h > 0.f ? h : 0.f;
  }
  __syncthreads();
  if (t < 96) {
    int o = t >> 3, part = t & 7;   // 12 outputs x 8 partials
    float v = 0.f;
    #pragma unroll
    for (int e = 0; e < 16; e++) v = fmaf(e2W[o*128 + part*16 + e], y1[part*16 + e], v);
    #pragma unroll
    for (int s = 4; s; s >>= 1) v += __shfl_down(v, s, 8);
    if (part == 0) dout[b*7200 + o*600 + n] = e2b[o] + v;
  }
}

extern "C" void kernel_launch(void* const* d_in, const int* in_sizes, int n_in,
                              void* d_out, int out_size, void* d_ws, size_t ws_size,
                              hipStream_t stream)
{
  const float* x    = (const float*)d_in[0];
  const float* Ws   = (const float*)d_in[1];
  const float* bs   = (const float*)d_in[2];
  const float* scW0 = (const float*)d_in[3];
  const float* scW1 = (const float*)d_in[4];
  const float* scW2 = (const float*)d_in[5];
  const float* scb  = (const float*)d_in[6];
  const float* emb1 = (const float*)d_in[7];
  const float* emb2 = (const float*)d_in[8];
  const float* lin1W= (const float*)d_in[9];
  const float* lin1b= (const float*)d_in[10];
  const float* lin2W= (const float*)d_in[11];
  const float* lin2b= (const float*)d_in[12];
  const float* gW   = (const float*)d_in[13];
  const float* gb   = (const float*)d_in[14];
  const float* svW0 = (const float*)d_in[15];
  const float* svW1 = (const float*)d_in[16];
  const float* svW2 = (const float*)d_in[17];
  const float* svb  = (const float*)d_in[18];
  const float* s0W  = (const float*)d_in[19];
  const float* s0b  = (const float*)d_in[20];
  const float* gfW1 = (const float*)d_in[21];
  const float* gfW2 = (const float*)d_in[22];
  const float* e1W  = (const float*)d_in[23];
  const float* e1b  = (const float*)d_in[24];
  const float* e2W  = (const float*)d_in[25];
  const float* e2b  = (const float*)d_in[26];
  float* out = (float*)d_out;
  float* ws  = (float*)d_ws;
  double* wd = (double*)d_ws;
  float* adj_out = out + 28800;

  k_pre_wc<<<49, 256, 0, stream>>>(Ws, bs, scW0, scW1, scW2, scb,
                                   svW0, svW1, svW2, gb, svb, wd, ws);
  k_pre_p<<<15, 256, 0, stream>>>(gW, wd);
  k_pre_v<<<256, 256, 0, stream>>>(svW0, svW1, svW2, s0W, s0b, wd, ws);
  k_fg<<<450, 256, 0, stream>>>(x, wd, ws);
  k_nodes<<<456, 256, 0, stream>>>(lin1W, lin1b, lin2W, lin2b, emb1, emb2, ws);
  k_adj<<<900, 256, 0, stream>>>(adj_out, ws);
  k_invrb<<<120, 256, 0, stream>>>(adj_out, ws);
  k_prop1<<<456, 256, 0, stream>>>(adj_out, ws);
  k_prop2<<<456, 256, 0, stream>>>(adj_out, ws);
  hipMemsetAsync((void*)(ws + OW_SVS), 0, 256*sizeof(float), stream);
  k_outs<<<600, 256, 0, stream>>>(ws);
  k_se<<<1, 256, 0, stream>>>(gfW1, gfW2, ws);
  k_head<<<2400, 128, 0, stream>>>(e1W, e1b, e2W, e2b, ws, out);
}

// Round 20
// 234.909 us; speedup vs baseline: 1.4584x; 1.0065x over previous
//
#include <hip/hip_runtime.h>
#include <math.h>

// ---------------- problem constants ----------------
// B=4, N=600, S=168, D=40, Cc=32, Cs=16, Ce=128, Od=12
// Adjacency path: bit-exact Eigen/MLIR fast-tanh (clamp 7.99881172180175781f,
// FMA Horner, |x|<0.0004 passthrough) + Eigen seq-FMA dots. PROVEN R7-R19.
// R20: k_adj reverted to R18 single-buffer (57us proven) + column-sum
// epilogue (atomicAdd raw sums); k_invrb = tiny 1/(1+s) transform.

// ---------------- workspace layout ----------------
#define DW_WEFF 0          // [3][32][16] doubles
#define DW_CC   1536       // [3][32]
#define DW_P    1632       // [3][5][32][16] doubles = 7680
#define DW_Q    9312       // [3][5][32] doubles = 480
#define FB      19584      // float offset = 2*9792
#define OW_CSV  (FB+0)
#define OW_CBIG (FB+48)
#define OW_VBIG (FB+304)
#define OW_T    (FB+760112)
#define OW_FEAT (FB+1374512)
#define OW_N1   (FB+1604912)
#define OW_N2   (FB+1892912)
#define OW_IRA  (FB+2180912)
#define OW_IRB  (FB+2188112)
#define OW_U1A  (FB+2195312)
#define OW_U2A  (FB+2310512)
#define OW_U1B  (FB+2425712)
#define OW_U2B  (FB+2540912)
#define OW_U3A  (FB+2656112)
#define OW_U3B  (FB+2771312)
#define OW_O    (FB+2886512)
#define OW_SE   (FB+3040112)   // [16]
#define OW_SVS  (FB+3040128)   // [256] per-(s,b,o) row sums (atomic)
#define OW_CSB  (FB+3040384)   // [12][600] raw adjacency column sums (atomic)

// ---------------- Eigen/MLIR fast tanh f32 (FMA build), bit-faithful ----------------
__device__ __forceinline__ float tanh_eigen(float x)
{
  const float CL = 7.99881172180175781f;
  float xc = fminf(fmaxf(x, -CL), CL);
  float x2 = __fmul_rn(xc, xc);
  float p = fmaf(x2, -2.76076847742355e-16f, 2.00018790482477e-13f);
  p = fmaf(x2, p, -8.60467152213735e-11f);
  p = fmaf(x2, p, 5.12229709037114e-08f);
  p = fmaf(x2, p, 1.48572235717979e-05f);
  p = fmaf(x2, p, 6.37261928875436e-04f);
  p = fmaf(x2, p, 4.89352455891786e-03f);
  p = __fmul_rn(xc, p);
  float q = fmaf(x2, 1.19825839466702e-06f, 1.18534705686654e-04f);
  q = fmaf(x2, q, 2.26843463243900e-03f);
  q = fmaf(x2, q, 4.89352518554385e-03f);
  float r = __fdiv_rn(p, q);
  return fabsf(x) < 0.0004f ? x : r;
}

// ---------------- fused: weff fold (block 48) + const_sv (blocks 0..47) ----------------
__global__ __launch_bounds__(256) void k_pre_wc(const float* Ws, const float* bs,
    const float* scW0, const float* scW1, const float* scW2, const float* scb,
    const float* svW0, const float* svW1, const float* svW2,
    const float* gb, const float* svb, double* wd, float* ws)
{
  if (blockIdx.x < 48) {
    int blk = blockIdx.x;
    int i = blk/16, o = blk%16;
    const float* svW = (i==0)?svW0:((i==1)?svW1:svW2);
    int L = (i==0)?162:((i==1)?79:39);
    int tid = threadIdx.x;
    __shared__ double red[256];
    double s = 0;
    for (int idx = tid; idx < 32*L; idx += 256) {
      int o2 = idx / L, l = idx - o2*L;
      s += (double)svW[(o*32+o2)*L + l] * ((double)gb[(i*2+0)*32+o2] + (double)gb[(i*2+1)*32+o2]);
    }
    red[tid] = s; __syncthreads();
    for (int st = 128; st; st >>= 1) { if (tid < st) red[tid] += red[tid+st]; __syncthreads(); }
    if (tid == 0) ws[OW_CSV + blk] = (float)(red[0] + (double)svb[i*16+o]);
    return;
  }
  __shared__ double w0[32][7], c0[32], w1[32][12], c1[32];
  int t = threadIdx.x;
  for (int e = t; e < 32*7; e += 256) {
    int c = e/7, p = e%7; double s = 0;
    for (int ci = 0; ci < 32; ci++) s += (double)scW0[(c*32+ci)*7+p] * (double)Ws[ci];
    w0[c][p] = s;
  }
  for (int e = t; e < 32; e += 256) {
    double s = 0;
    for (int ci = 0; ci < 32; ci++) { double a = 0; for (int p = 0; p < 7; p++) a += (double)scW0[(e*32+ci)*7+p]; s += a*(double)bs[ci]; }
    c0[e] = s + (double)scb[e];
  }
  __syncthreads();
  for (int e = t; e < 32*12; e += 256) {
    int c = e/12, m = e%12; double s = 0;
    for (int k1 = 0; k1 < 6; k1++) { int k0 = m - k1; if (k0 < 0 || k0 > 6) continue;
      for (int ci = 0; ci < 32; ci++) s += (double)scW1[(c*32+ci)*6+k1] * w0[ci][k0]; }
    w1[c][m] = s;
  }
  for (int e = t; e < 32; e += 256) {
    double s = 0;
    for (int ci = 0; ci < 32; ci++) { double a = 0; for (int k1 = 0; k1 < 6; k1++) a += (double)scW1[(e*32+ci)*6+k1]; s += a*c0[ci]; }
    c1[e] = s + (double)scb[32+e];
  }
  __syncthreads();
  for (int e = t; e < 32*16; e += 256) {
    int c = e/16, p = e%16; double s = 0;
    for (int k2 = 0; k2 < 3; k2++) { int m = p - 2*k2; if (m < 0 || m > 11) continue;
      for (int ci = 0; ci < 32; ci++) s += (double)scW2[(c*32+ci)*3+k2] * w1[ci][m]; }
    wd[DW_WEFF + (2*32+c)*16 + p] = s;
  }
  for (int e = t; e < 32; e += 256) {
    double s = 0;
    for (int ci = 0; ci < 32; ci++) { double a = 0; for (int k2 = 0; k2 < 3; k2++) a += (double)scW2[(e*32+ci)*3+k2]; s += a*c1[ci]; }
    wd[DW_CC + 64 + e] = s + (double)scb[64+e];
  }
  for (int e = t; e < 32*7;  e += 256) wd[DW_WEFF + (e/7)*16  + e%7 ] = w0[e/7][e%7];
  for (int e = t; e < 32*12; e += 256) wd[DW_WEFF + (32 + e/12)*16 + e%12] = w1[e/12][e%12];
  for (int e = t; e < 32; e += 256) { wd[DW_CC+e] = c0[e]; wd[DW_CC+32+e] = c1[e]; }
}

// ---------------- P[i][g][o2][p] + Q[i][g][o2]  (15 blocks, LDS-staged gW) ----------------
__global__ __launch_bounds__(256) void k_pre_p(const float* gW, double* wd)
{
  int blk = blockIdx.x;      // i*5+g
  int i = blk/5, g = blk%5;
  int tid = threadIdx.x;
  __shared__ float gls[2][3072];
  __shared__ double weffs[512];
  __shared__ double ccs[32];
  for (int e = tid; e < 6144; e += 256) gls[e/3072][e % 3072] = gW[i*6144 + e];
  for (int e = tid; e < 512; e += 256) weffs[e] = wd[DW_WEFF + i*512 + e];
  if (tid < 32) ccs[tid] = wd[DW_CC + i*32 + tid];
  __syncthreads();
  const float* g0 = gls[0];
  const float* g1 = gls[1];
  for (int e = tid; e < 512; e += 256) {
    int o2 = e >> 4, p = e & 15;
    double s = 0;
    for (int c = 0; c < 32; c++) {
      float w;
      if (g == 0) w = g0[c*32+o2] + g1[c*32+o2]
                    + 0.05f*(g0[(32+c)*32+o2] + g0[(64+c)*32+o2] + g1[(32+c)*32+o2] + g1[(64+c)*32+o2]);
      else if (g == 1) w = g0[(32+c)*32+o2];
      else if (g == 2) w = g0[(64+c)*32+o2];
      else if (g == 3) w = g1[(32+c)*32+o2];
      else             w = g1[(64+c)*32+o2];
      s += (double)w * weffs[c*16 + p];
    }
    wd[DW_P + ((i*5+g)*32 + o2)*16 + p] = s;
  }
  if (tid < 32) {
    int o2 = tid;
    double s = 0;
    for (int c = 0; c < 32; c++) {
      float w;
      if (g == 0) w = g0[c*32+o2] + g1[c*32+o2]
                    + 0.05f*(g0[(32+c)*32+o2] + g0[(64+c)*32+o2] + g1[(32+c)*32+o2] + g1[(64+c)*32+o2]);
      else if (g == 1) w = g0[(32+c)*32+o2];
      else if (g == 2) w = g0[(64+c)*32+o2];
      else if (g == 3) w = g1[(32+c)*32+o2];
      else             w = g1[(64+c)*32+o2];
      s += (double)w * ccs[c];
    }
    wd[DW_Q + (i*5+g)*32 + o2] = s;
  }
}

// ---------------- t-path/out0 fused weight columns (svW x P) + cbig (svW x Q) ----------------
__global__ __launch_bounds__(256) void k_pre_v(const float* svW0, const float* svW1, const float* svW2,
                                               const float* s0W, const float* s0b, double* wd, float* ws)
{
  int jj = blockIdx.x;             // 0..255
  int tid = threadIdx.x;
  if (jj >= 240) {
    int o = jj - 240;
    if (tid < 168) ws[OW_VBIG + jj*168 + tid] = s0W[o*168 + tid];
    if (tid == 0)  ws[OW_CBIG + jj] = s0b[o];
    return;
  }
  int i = jj/80, g = (jj%80)/16, o = jj%16;
  int st = (i==0)?1:((i==1)?2:4), tp = (i==0)?7:((i==1)?12:16), L = (i==0)?162:((i==1)?79:39);
  const float* svW = (i==0)?svW0:((i==1)?svW1:svW2);
  const float* svo = svW + o*32*L;
  __shared__ float svlds[32*162];
  __shared__ double Pl[32][16];
  __shared__ double Qs[32];
  __shared__ double red[256];
  int NL = 32*L;
  for (int e = tid; e < NL; e += 256) svlds[e] = svo[e];
  for (int e = tid; e < 512; e += 256) {
    int o2 = e >> 4, p = e & 15;
    Pl[o2][p] = wd[DW_P + ((i*5+g)*32 + o2)*16 + p];
  }
  if (tid < 32) Qs[tid] = wd[DW_Q + (i*5+g)*32 + tid];
  __syncthreads();
  double s = 0;
  for (int e = tid; e < NL; e += 256) s += (double)svlds[e] * Qs[e / L];
  red[tid] = s; __syncthreads();
  for (int stp = 128; stp; stp >>= 1) { if (tid < stp) red[tid] += red[tid+stp]; __syncthreads(); }
  if (tid == 0) ws[OW_CBIG + jj] = (float)red[0];
  if (tid < 168) {
    int u = tid;
    int lo_ = u - tp + 1;
    int lmin = lo_ > 0 ? (lo_ + st - 1)/st : 0;
    int lmax = u/st; if (lmax > L-1) lmax = L-1;
    double v = 0.0;
    for (int o2 = 0; o2 < 32; o2++) {
      const float* sv = svlds + o2*L;
      const double* Pp = Pl[o2];
      for (int l = lmin; l <= lmax; l++)
        v += (double)sv[l] * Pp[u - st*l];
    }
    ws[OW_VBIG + jj*168 + u] = (float)v;
  }
}

// ---------------- fused: feat (blocks 0..299) + t-path GEMM (300..449) ----------------
__global__ __launch_bounds__(256) void k_fg(const float* x, double* wd, float* ws)
{
  int t = threadIdx.x;
  if (blockIdx.x >= 300) {
    __shared__ float xs[16][168];
    int r0 = (blockIdx.x - 300)*16;
    for (int e = t; e < 16*168; e += 256) { int r = e/168, u = e%168; xs[r][u] = x[(r0+r)*168 + u]; }
    __syncthreads();
    int jj = t;
    const float* V = ws + OW_VBIG + jj*168;
    double a[16];
    #pragma unroll
    for (int r = 0; r < 16; r++) a[r] = 0;
    for (int u = 0; u < 168; u++) {
      float wv = V[u];
      #pragma unroll
      for (int r = 0; r < 16; r++) a[r] += (double)wv * (double)xs[r][u];
    }
    double cb = (double)ws[OW_CBIG + jj];
    for (int r = 0; r < 16; r++)
      ws[OW_T + (r0+r)*256 + jj] = (float)(a[r] + cb);
    return;
  }
  int blk = blockIdx.x;      // 4*75
  int b = blk / 75, n0 = (blk % 75) * 8;
  __shared__ float xsf[8][168];
  __shared__ double xbar[8][35];
  for (int e = t; e < 8*168; e += 256) xsf[e/168][e%168] = x[(b*600 + n0 + e/168)*168 + e%168];
  __syncthreads();
  for (int e = t; e < 8*35; e += 256) {
    int nn = e/35, slot = e%35;
    int i = slot < 7 ? 0 : (slot < 19 ? 1 : 2);
    int p = slot - (i==0?0:(i==1?7:19));
    int st = (i==0)?1:((i==1)?2:4), L = (i==0)?162:((i==1)?79:39);
    double s = 0;
    for (int l = 0; l < L; l++) s += (double)xsf[nn][st*l+p];
    xbar[nn][slot] = s / (double)L;
  }
  __syncthreads();
  int nn = t >> 5, c = t & 31;
  for (int i = 0; i < 3; i++) {
    int off = (i==0)?0:((i==1)?7:19), tp = (i==0)?7:((i==1)?12:16);
    double f = wd[DW_CC + i*32 + c];
    for (int p = 0; p < tp; p++) f += wd[DW_WEFF + (i*32+c)*16 + p] * xbar[nn][off+p];
    ws[OW_FEAT + ((i*4+b)*600 + n0+nn)*32 + c] = (float)f;
  }
}

// ---------------- n1/n2: LDS-staged weights, 16 nodes per block ----------------
__global__ __launch_bounds__(256) void k_nodes(const float* lin1W, const float* lin1b,
                                               const float* lin2W, const float* lin2b,
                                               const float* emb1, const float* emb2, float* ws)
{
  int blk = blockIdx.x;  // i*152 + b*38 + nt
  int nt = blk % 38, b = (blk/38) % 4, i = blk/152;
  int n0 = nt*16;
  __shared__ float W1[1280], W2[1280], b1[40], b2[40], sf[16][33];
  int t = threadIdx.x;
  for (int e = t; e < 1280; e += 256) { W1[e] = lin1W[i*1280 + e]; W2[e] = lin2W[i*1280 + e]; }
  if (t < 40) { b1[t] = lin1b[i*40 + t]; b2[t] = lin2b[i*40 + t]; }
  for (int e = t; e < 16*32; e += 256) {
    int nn = e >> 5, c = e & 31; int n = n0 + nn;
    sf[nn][c] = (n < 600) ? ws[OW_FEAT + ((i*4+b)*600 + n)*32 + c] : 0.f;
  }
  __syncthreads();
  const float TSF[3] = {3.0f, 2.4f, 1.8f};
  for (int item = t; item < 16*80; item += 256) {
    int nn = item / 80, rr = item % 80;
    int n = n0 + nn; if (n >= 600) continue;
    int which = rr/40, d = rr%40;
    const float* W  = which ? W2 : W1;
    const float* bv = which ? b2 : b1;
    const float* em = which ? emb2 : emb1;
    float pre = 0.f;
    #pragma unroll
    for (int c = 0; c < 32; c++) pre = fmaf(sf[nn][c], W[c*40+d], pre);
    float p2 = __fadd_rn(pre, bv[d]);
    float p3 = __fadd_rn(p2, em[n*40+d]);
    float arg = __fmul_rn(TSF[i], p3);
    ws[(which ? OW_N2 : OW_N1) + ((i*4+b)*600 + n)*40 + d] = tanh_eigen(arg);
  }
}

// ---------------- adjacency staging helper ----------------
__device__ __forceinline__ float4 adj_ld(const float* n1, const float* n2, int e, int w0)
{
  int mat = e >= 320; int idx = e - 320*mat;
  int jj = idx/10, q = idx - 10*jj;
  int w = w0 + jj;
  if (w < 600) return *(const float4*)((mat ? n2 : n1) + w*40 + 4*q);
  float4 z; z.x = z.y = z.z = z.w = 0.f; return z;
}

// ---------------- adjacency: R18 single-buffer + colsum epilogue ----------------
__global__ __launch_bounds__(256) void k_adj(float* adj_out, float* ws)
{
  int blk = blockIdx.x;                 // 3*4*75
  int tile = blk % 75, b = (blk/75) % 4, i = blk/300;
  int row0 = tile*8;
  const float* n1 = ws + OW_N1 + (i*4+b)*24000;
  const float* n2 = ws + OW_N2 + (i*4+b)*24000;
  __shared__ float c1s[32][44], c2s[32][44];
  __shared__ float svals[8][604];       // 604%32==28: conflict-free
  int t = threadIdx.x;
  int rc = t & 7, jc = t >> 3;          // 8 lanes share each column address
  float am1[40], am2[40];
  {
    const float4* m1p = (const float4*)(n1 + (row0 + rc)*40);
    const float4* m2p = (const float4*)(n2 + (row0 + rc)*40);
    #pragma unroll
    for (int q = 0; q < 10; q++) {
      float4 v1 = m1p[q], v2 = m2p[q];
      am1[4*q]=v1.x; am1[4*q+1]=v1.y; am1[4*q+2]=v1.z; am1[4*q+3]=v1.w;
      am2[4*q]=v2.x; am2[4*q+1]=v2.y; am2[4*q+2]=v2.z; am2[4*q+3]=v2.w;
    }
  }
  float4 s0 = adj_ld(n1, n2, t, 0);
  float4 s1 = adj_ld(n1, n2, t + 256, 0);
  float4 s2; if (t < 128) s2 = adj_ld(n1, n2, t + 512, 0);
  for (int k = 0; k < 19; k++) {
    int w0 = 32*k;
    __syncthreads();
    {
      int e = t;       { int mat=e>=320, idx=e-320*mat, jj=idx/10, q=idx-10*jj, w=w0+jj;
                         if (w<600) *(float4*)(&(mat?c2s:c1s)[jj][4*q]) = s0; }
      e = t + 256;     { int mat=e>=320, idx=e-320*mat, jj=idx/10, q=idx-10*jj, w=w0+jj;
                         if (w<600) *(float4*)(&(mat?c2s:c1s)[jj][4*q]) = s1; }
      if (t < 128) { e = t + 512; int mat=e>=320, idx=e-320*mat, jj=idx/10, q=idx-10*jj, w=w0+jj;
                         if (w<600) *(float4*)(&(mat?c2s:c1s)[jj][4*q]) = s2; }
    }
    __syncthreads();
    if (k < 18) {
      int w0n = w0 + 32;
      s0 = adj_ld(n1, n2, t, w0n);
      s1 = adj_ld(n1, n2, t + 256, w0n);
      if (t < 128) s2 = adj_ld(n1, n2, t + 512, w0n);
    }
    if (jc < 32) {
      int w = w0 + jc;
      if (w < 600) {
        const float4* c2p = (const float4*)c2s[jc];
        const float4* c1p = (const float4*)c1s[jc];
        float d1 = 0.f, d2 = 0.f;
        #pragma unroll
        for (int q = 0; q < 10; q++) {          // ascending d, single accumulator: bit-exact
          float4 v = c2p[q];
          d1 = fmaf(am1[4*q], v.x, d1); d1 = fmaf(am1[4*q+1], v.y, d1);
          d1 = fmaf(am1[4*q+2], v.z, d1); d1 = fmaf(am1[4*q+3], v.w, d1);
        }
        #pragma unroll
        for (int q = 0; q < 10; q++) {
          float4 v = c1p[q];
          d2 = fmaf(am2[4*q], v.x, d2); d2 = fmaf(am2[4*q+1], v.y, d2);
          d2 = fmaf(am2[4*q+2], v.z, d2); d2 = fmaf(am2[4*q+3], v.w, d2);
        }
        float af = __fsub_rn(d1, d2);
        float tv = __fmul_rn(3.0f, af);
        float v = tanh_eigen(tv);
        svals[rc][w] = v > 0.f ? v : 0.f;       // relu
      }
    }
  }
  __syncthreads();
  // ---- top-k phase: proven logic, vv from svals ----
  int r = t >> 5, j = t & 31;
  float vv[19];
  #pragma unroll
  for (int k = 0; k < 19; k++) {
    int w = j + 32*k;
    vv[k] = (w < 600) ? svals[r][w] : 0.f;
  }
  float rm = 0.f;
  #pragma unroll
  for (int k = 0; k < 19; k++) rm = fmaxf(rm, vv[k]);
  #pragma unroll
  for (int s = 16; s; s >>= 1) rm = fmaxf(rm, __shfl_xor(rm, s, 32));
  const float VP = tanh_eigen(8.0f);
  unsigned int vpb = __float_as_uint(VP);
  int cntp = 0;
  #pragma unroll
  for (int k = 0; k < 19; k++) { int w = j + 32*k; if (w < 600 && __float_as_uint(vv[k]) >= vpb) cntp++; }
  #pragma unroll
  for (int s = 16; s; s >>= 1) cntp += __shfl_xor(cntp, s, 32);
  unsigned int lo, hi;
  unsigned int mb1 = __float_as_uint(rm) + 1u;
  if (cntp >= 20) { lo = vpb; hi = mb1; }
  else            { lo = 0u;  hi = vpb < mb1 ? vpb : mb1; }
  while (hi - lo > 1u) {
    unsigned int mid = lo + ((hi - lo) >> 1);
    int cnt = 0;
    #pragma unroll
    for (int k = 0; k < 19; k++) {
      int w = j + 32*k;
      if (w < 600 && __float_as_uint(vv[k]) >= mid) cnt++;
    }
    #pragma unroll
    for (int s = 16; s; s >>= 1) cnt += __shfl_xor(cnt, s, 32);
    if (cnt >= 20) lo = mid; else hi = mid;
  }
  unsigned int kb = lo;
  float* arow = adj_out + (i*4+b)*360000 + (row0+r)*600;
  float rsum = 0.f;
  #pragma unroll
  for (int k = 0; k < 19; k++) {
    int w = j + 32*k;
    if (w < 600) {
      float v = (__float_as_uint(vv[k]) >= kb) ? vv[k] : 0.f;
      arow[w] = v;
      svals[r][w] = v;                  // masked write-back for column sums
      rsum += v;
    }
  }
  #pragma unroll
  for (int s = 16; s; s >>= 1) rsum += __shfl_xor(rsum, s, 32);
  if (j == 0) ws[OW_IRA + (i*4+b)*600 + row0 + r] = 1.f/(1.f + rsum);
  __syncthreads();
  // ---- column-sum epilogue: 8-row partials -> atomic raw sums ----
  {
    float* csb = ws + OW_CSB + (i*4+b)*600;
    for (int w = t; w < 600; w += 256) {
      float cs = 0.f;
      #pragma unroll
      for (int rr2 = 0; rr2 < 8; rr2++) cs += svals[rr2][w];
      atomicAdd(&csb[w], cs);
    }
  }
}

// ---------------- inv row sums for transposed direction: 1/(1+csum) ----------------
__global__ void k_invrb(float* ws)
{
  int e = blockIdx.x*256 + threadIdx.x;
  if (e < 7200) ws[OW_IRB + e] = 1.f/(1.f + ws[OW_CSB + e]);
}

// ---------------- prop1: 4w x 4oz per thread, per-wave K-split, b128 LDS ----------------
__global__ __launch_bounds__(256) void k_prop1(const float* adj, float* ws)
{
  int blk = blockIdx.x;            // ib*38 + d*19 + wt
  int wt = blk % 19;
  int d  = (blk / 19) & 1;
  int ib = blk / 38;
  int i = ib >> 2, b = ib & 3;
  int w0 = wt * 32;
  const float* A   = adj + ib*360000;
  const float* irx = ws + (d ? OW_IRB : OW_IRA) + ib*600;
  const float* Tb  = ws + OW_T + (b*600)*256 + i*80 + 16 + d*32;
  __shared__ float As[4][32][36];
  __shared__ float Zs[4][32][36];
  __shared__ float red[3][64][17];
  int tid = threadIdx.x;
  int wv = tid >> 6, ln = tid & 63;
  int wq = ln >> 3, oq = ln & 7;
  float acc[4][4];
  #pragma unroll
  for (int a1 = 0; a1 < 4; a1++)
    #pragma unroll
    for (int a2 = 0; a2 < 4; a2++) acc[a1][a2] = 0.f;
  int vbeg = wv*160, vend = vbeg + 160 < 600 ? vbeg + 160 : 600;
  for (int v0 = vbeg; v0 < vend; v0 += 32) {
    if (d == 0) {
      #pragma unroll
      for (int q = 0; q < 4; q++) {
        int m = q*64 + ln, rr = m >> 3, c4 = (m & 7)*4;
        int v = v0 + rr;
        float4 av; av.x = av.y = av.z = av.w = 0.f;
        if (v < 600) {
          int wb = w0 + c4;
          if (wb + 3 < 600) av = *(const float4*)(A + v*600 + wb);
          else {
            if (wb+0 < 600) av.x = A[v*600 + wb+0];
            if (wb+1 < 600) av.y = A[v*600 + wb+1];
            if (wb+2 < 600) av.z = A[v*600 + wb+2];
            if (wb+3 < 600) av.w = A[v*600 + wb+3];
          }
        }
        *(float4*)(&As[wv][rr][c4]) = av;
      }
    } else {
      #pragma unroll
      for (int q = 0; q < 4; q++) {
        int m = q*64 + ln, rr = m >> 3, c4 = (m & 7)*4;
        int w = w0 + rr;
        float4 av; av.x = av.y = av.z = av.w = 0.f;
        if (w < 600) {
          if (v0 + c4 + 3 < 600) av = *(const float4*)(A + w*600 + v0 + c4);
          else {
            if (v0+c4+0 < 600) av.x = A[w*600 + v0+c4+0];
            if (v0+c4+1 < 600) av.y = A[w*600 + v0+c4+1];
            if (v0+c4+2 < 600) av.z = A[w*600 + v0+c4+2];
            if (v0+c4+3 < 600) av.w = A[w*600 + v0+c4+3];
          }
        }
        As[wv][c4+0][rr] = av.x; As[wv][c4+1][rr] = av.y;
        As[wv][c4+2][rr] = av.z; As[wv][c4+3][rr] = av.w;
      }
    }
    #pragma unroll
    for (int q = 0; q < 4; q++) {
      int m = q*64 + ln, rr = m >> 3, c4 = (m & 7)*4;
      int v = v0 + rr;
      float4 zv; zv.x = zv.y = zv.z = zv.w = 0.f;
      if (v < 600) {
        float ir = irx[v];
        float4 tv = *(const float4*)(Tb + v*256 + c4);
        zv.x = ir*tv.x; zv.y = ir*tv.y; zv.z = ir*tv.z; zv.w = ir*tv.w;
      }
      *(float4*)(&Zs[wv][rr][c4]) = zv;
    }
    __builtin_amdgcn_s_waitcnt(0);
    for (int vl = 0; vl < 32; vl++) {
      float4 a4 = *(const float4*)(&As[wv][vl][wq*4]);
      float4 z4 = *(const float4*)(&Zs[wv][vl][oq*4]);
      acc[0][0] = fmaf(a4.x, z4.x, acc[0][0]); acc[0][1] = fmaf(a4.x, z4.y, acc[0][1]);
      acc[0][2] = fmaf(a4.x, z4.z, acc[0][2]); acc[0][3] = fmaf(a4.x, z4.w, acc[0][3]);
      acc[1][0] = fmaf(a4.y, z4.x, acc[1][0]); acc[1][1] = fmaf(a4.y, z4.y, acc[1][1]);
      acc[1][2] = fmaf(a4.y, z4.z, acc[1][2]); acc[1][3] = fmaf(a4.y, z4.w, acc[1][3]);
      acc[2][0] = fmaf(a4.z, z4.x, acc[2][0]); acc[2][1] = fmaf(a4.z, z4.y, acc[2][1]);
      acc[2][2] = fmaf(a4.z, z4.z, acc[2][2]); acc[2][3] = fmaf(a4.z, z4.w, acc[2][3]);
      acc[3][0] = fmaf(a4.w, z4.x, acc[3][0]); acc[3][1] = fmaf(a4.w, z4.y, acc[3][1]);
      acc[3][2] = fmaf(a4.w, z4.z, acc[3][2]); acc[3][3] = fmaf(a4.w, z4.w, acc[3][3]);
    }
  }
  if (wv > 0) {
    #pragma unroll
    for (int kw = 0; kw < 4; kw++)
      #pragma unroll
      for (int ko = 0; ko < 4; ko++) red[wv-1][ln][kw*4+ko] = acc[kw][ko];
  }
  __syncthreads();
  if (wv == 0) {
    #pragma unroll
    for (int kw = 0; kw < 4; kw++) {
      int w = w0 + wq*4 + kw;
      if (w >= 600) continue;
      float irw = irx[w];
      #pragma unroll
      for (int ko = 0; ko < 4; ko++) {
        int oz = oq*4 + ko;
        float sum = acc[kw][ko] + red[0][ln][kw*4+ko] + red[1][ln][kw*4+ko] + red[2][ln][kw*4+ko];
        sum += irw * Tb[w*256 + oz];
        float* dst = ws + (d==0 ? (oz < 16 ? OW_U1A : OW_U2A) : (oz < 16 ? OW_U1B : OW_U2B));
        dst[(ib*600 + w)*16 + (oz & 15)] = sum;
      }
    }
  }
}

// ---------------- prop2: 4w x 2oz per thread, per-wave K-split ----------------
__global__ __launch_bounds__(256) void k_prop2(const float* adj, float* ws)
{
  int blk = blockIdx.x;            // ib*38 + d*19 + wt
  int wt = blk % 19;
  int d  = (blk / 19) & 1;
  int ib = blk / 38;
  int w0 = wt * 32;
  const float* A   = adj + ib*360000;
  const float* irx = ws + (d ? OW_IRB : OW_IRA) + ib*600;
  const float* u2x = ws + (d ? OW_U2B : OW_U2A) + ib*9600;
  __shared__ float As[4][32][36];
  __shared__ float Zs[4][32][20];
  __shared__ float red[3][64][9];
  int tid = threadIdx.x;
  int wv = tid >> 6, ln = tid & 63;
  int wq = ln >> 3, oq = ln & 7;
  float acc[4][2];
  #pragma unroll
  for (int a1 = 0; a1 < 4; a1++) { acc[a1][0] = 0.f; acc[a1][1] = 0.f; }
  int vbeg = wv*160, vend = vbeg + 160 < 600 ? vbeg + 160 : 600;
  for (int v0 = vbeg; v0 < vend; v0 += 32) {
    if (d == 0) {
      #pragma unroll
      for (int q = 0; q < 4; q++) {
        int m = q*64 + ln, rr = m >> 3, c4 = (m & 7)*4;
        int v = v0 + rr;
        float4 av; av.x = av.y = av.z = av.w = 0.f;
        if (v < 600) {
          int wb = w0 + c4;
          if (wb + 3 < 600) av = *(const float4*)(A + v*600 + wb);
          else {
            if (wb+0 < 600) av.x = A[v*600 + wb+0];
            if (wb+1 < 600) av.y = A[v*600 + wb+1];
            if (wb+2 < 600) av.z = A[v*600 + wb+2];
            if (wb+3 < 600) av.w = A[v*600 + wb+3];
          }
        }
        *(float4*)(&As[wv][rr][c4]) = av;
      }
    } else {
      #pragma unroll
      for (int q = 0; q < 4; q++) {
        int m = q*64 + ln, rr = m >> 3, c4 = (m & 7)*4;
        int w = w0 + rr;
        float4 av; av.x = av.y = av.z = av.w = 0.f;
        if (w < 600) {
          if (v0 + c4 + 3 < 600) av = *(const float4*)(A + w*600 + v0 + c4);
          else {
            if (v0+c4+0 < 600) av.x = A[w*600 + v0+c4+0];
            if (v0+c4+1 < 600) av.y = A[w*600 + v0+c4+1];
            if (v0+c4+2 < 600) av.z = A[w*600 + v0+c4+2];
            if (v0+c4+3 < 600) av.w = A[w*600 + v0+c4+3];
          }
        }
        As[wv][c4+0][rr] = av.x; As[wv][c4+1][rr] = av.y;
        As[wv][c4+2][rr] = av.z; As[wv][c4+3][rr] = av.w;
      }
    }
    #pragma unroll
    for (int q = 0; q < 2; q++) {
      int m = q*64 + ln, rr = m >> 2, c4 = (m & 3)*4;
      int v = v0 + rr;
      float4 zv; zv.x = zv.y = zv.z = zv.w = 0.f;
      if (v < 600) {
        float ir = irx[v];
        float4 uv = *(const float4*)(u2x + v*16 + c4);
        zv.x = ir*uv.x; zv.y = ir*uv.y; zv.z = ir*uv.z; zv.w = ir*uv.w;
      }
      *(float4*)(&Zs[wv][rr][c4]) = zv;
    }
    __builtin_amdgcn_s_waitcnt(0);
    for (int vl = 0; vl < 32; vl++) {
      float4 a4 = *(const float4*)(&As[wv][vl][wq*4]);
      float2 z2 = *(const float2*)(&Zs[wv][vl][oq*2]);
      acc[0][0] = fmaf(a4.x, z2.x, acc[0][0]); acc[0][1] = fmaf(a4.x, z2.y, acc[0][1]);
      acc[1][0] = fmaf(a4.y, z2.x, acc[1][0]); acc[1][1] = fmaf(a4.y, z2.y, acc[1][1]);
      acc[2][0] = fmaf(a4.z, z2.x, acc[2][0]); acc[2][1] = fmaf(a4.z, z2.y, acc[2][1]);
      acc[3][0] = fmaf(a4.w, z2.x, acc[3][0]); acc[3][1] = fmaf(a4.w, z2.y, acc[3][1]);
    }
  }
  if (wv > 0) {
    #pragma unroll
    for (int kw = 0; kw < 4; kw++) {
      red[wv-1][ln][kw*2+0] = acc[kw][0];
      red[wv-1][ln][kw*2+1] = acc[kw][1];
    }
  }
  __syncthreads();
  if (wv == 0) {
    float* dst = ws + (d==0 ? OW_U3A : OW_U3B);
    #pragma unroll
    for (int kw = 0; kw < 4; kw++) {
      int w = w0 + wq*4 + kw;
      if (w >= 600) continue;
      float irw = irx[w];
      #pragma unroll
      for (int ko = 0; ko < 2; ko++) {
        int oz = oq*2 + ko;
        float sum = acc[kw][ko] + red[0][ln][kw*2+ko] + red[1][ln][kw*2+ko] + red[2][ln][kw*2+ko];
        sum += irw * u2x[w*16 + oz];
        dst[(ib*600 + w)*16 + oz] = sum;
      }
    }
  }
}

// ---------------- assemble head outputs + fused SE row sums ----------------
__global__ __launch_bounds__(256) void k_outs(float* ws)
{
  __shared__ float sums[2];
  int tid = threadIdx.x;
  int e = blockIdx.x*256 + tid;
  int rA = (blockIdx.x*256)/600;
  if (tid < 2) sums[tid] = 0.f;
  __syncthreads();
  float val = 0.f;
  int row = rA;
  if (e < 153600) {
    int n = e % 600, o = (e/600) % 16, b = (e/9600) % 4, s = e/38400;
    if (s == 0) {
      val = ws[OW_T + (b*600+n)*256 + 240 + o];
    } else {
      int i = s - 1;
      int idx = ((i*4+b)*600 + n)*16 + o;
      float t0 = ws[OW_T + (b*600+n)*256 + i*80 + o];
      val = t0 + 0.95f  * (ws[OW_U1A+idx] + ws[OW_U1B+idx])
               + 0.0475f* (ws[OW_U2A+idx] + ws[OW_U2B+idx])
               + 0.9025f* (ws[OW_U3A+idx] + ws[OW_U3B+idx])
               + ws[OW_CSV + i*16 + o];
    }
    ws[OW_O + ((s*4+b)*16 + o)*600 + n] = val;
    row = e/600;
  }
  float vA = (e < 153600 && row == rA) ? val : 0.f;
  float vB = (e < 153600 && row == rA+1) ? val : 0.f;
  #pragma unroll
  for (int s = 32; s; s >>= 1) { vA += __shfl_down(vA, s, 64); vB += __shfl_down(vB, s, 64); }
  if ((tid & 63) == 0) {
    if (vA != 0.f) atomicAdd(&sums[0], vA);
    if (vB != 0.f) atomicAdd(&sums[1], vB);
  }
  __syncthreads();
  if (tid < 2) {
    int r = rA + tid;
    if (r < 256) atomicAdd(&ws[OW_SVS + r], sums[tid]);
  }
}

// ---------------- SE gate (reads fused sums) ----------------
__global__ void k_se(const float* gfW1, const float* gfW2, float* ws)
{
  __shared__ float sv[4][64], hb[4][4];
  int t = threadIdx.x;
  {
    int row = t;
    int o = row & 15, b = (row >> 4) & 3, s = row >> 6;
    sv[b][s*16 + o] = ws[OW_SVS + row] * (1.f/600.f);
  }
  __syncthreads();
  if (t < 16) {
    int bb = t >> 2, j = t & 3;
    float h = 0.f;
    for (int kk = 0; kk < 64; kk++) h += sv[bb][kk]*gfW1[kk*4+j];
    hb[bb][j] = h > 0.f ? h : 0.f;
  }
  __syncthreads();
  if (t < 16) {
    int bb = t >> 2, ii = t & 3;
    float g = 0.f;
    for (int j = 0; j < 4; j++) g += hb[bb][j]*gfW2[j*4+ii];
    ws[OW_SE + bb*4 + ii] = 1.f/(1.f + expf(-g));
  }
}

// ---------------- gate + end MLP (parallel final stage) ----------------
__global__ __launch_bounds__(128) void k_head(const float* e1W, const float* e1b,
                                              const float* e2W, const float* e2b,
                                              float* ws, float* dout)
{
  int blk = blockIdx.x, b = blk/600, n = blk%600;
  __shared__ float y0[16], y1[128];
  int t = threadIdx.x;
  if (t < 16) {
    float f = 0.f;
    for (int s = 0; s < 4; s++) f += ws[OW_SE + b*4 + s] * ws[OW_O + ((s*4+b)*16 + t)*600 + n];
    f *= 0.25f;
    y0[t] = f > 0.f ? f : 0.f;
  }
  __syncthreads();
  {
    float h = e1b[t];
    for (int o = 0; o < 16; o++) h += e1W[t*16+o]*y0[o];
    y1[t] = h > 0.f ? h : 0.f;
  }
  __syncthreads();
  if (t < 96) {
    int o = t >> 3, part = t & 7;   // 12 outputs x 8 partials
    float v = 0.f;
    #pragma unroll
    for (int e = 0; e < 16; e++) v = fmaf(e2W[o*128 + part*16 + e], y1[part*16 + e], v);
    #pragma unroll
    for (int s = 4; s; s >>= 1) v += __shfl_down(v, s, 8);
    if (part == 0) dout[b*7200 + o*600 + n] = e2b[o] + v;
  }
}

extern "C" void kernel_launch(void* const* d_in, const int* in_sizes, int n_in,
                              void* d_out, int out_size, void* d_ws, size_t ws_size,
                              hipStream_t stream)
{
  const float* x    = (const float*)d_in[0];
  const float* Ws   = (const float*)d_in[1];
  const float* bs   = (const float*)d_in[2];
  const float* scW0 = (const float*)d_in[3];
  const float* scW1 = (const float*)d_in[4];
  const float* scW2 = (const float*)d_in[5];
  const float* scb  = (const float*)d_in[6];
  const float* emb1 = (const float*)d_in[7];
  const float* emb2 = (const float*)d_in[8];
  const float* lin1W= (const float*)d_in[9];
  const float* lin1b= (const float*)d_in[10];
  const float* lin2W= (const float*)d_in[11];
  const float* lin2b= (const float*)d_in[12];
  const float* gW   = (const float*)d_in[13];
  const float* gb   = (const float*)d_in[14];
  const float* svW0 = (const float*)d_in[15];
  const float* svW1 = (const float*)d_in[16];
  const float* svW2 = (const float*)d_in[17];
  const float* svb  = (const float*)d_in[18];
  const float* s0W  = (const float*)d_in[19];
  const float* s0b  = (const float*)d_in[20];
  const float* gfW1 = (const float*)d_in[21];
  const float* gfW2 = (const float*)d_in[22];
  const float* e1W  = (const float*)d_in[23];
  const float* e1b  = (const float*)d_in[24];
  const float* e2W  = (const float*)d_in[25];
  const float* e2b  = (const float*)d_in[26];
  float* out = (float*)d_out;
  float* ws  = (float*)d_ws;
  double* wd = (double*)d_ws;
  float* adj_out = out + 28800;

  k_pre_wc<<<49, 256, 0, stream>>>(Ws, bs, scW0, scW1, scW2, scb,
                                   svW0, svW1, svW2, gb, svb, wd, ws);
  k_pre_p<<<15, 256, 0, stream>>>(gW, wd);
  k_pre_v<<<256, 256, 0, stream>>>(svW0, svW1, svW2, s0W, s0b, wd, ws);
  hipMemsetAsync((void*)(ws + OW_SVS), 0, (256 + 7200)*sizeof(float), stream);
  k_fg<<<450, 256, 0, stream>>>(x, wd, ws);
  k_nodes<<<456, 256, 0, stream>>>(lin1W, lin1b, lin2W, lin2b, emb1, emb2, ws);
  k_adj<<<900, 256, 0, stream>>>(adj_out, ws);
  k_invrb<<<29, 256, 0, stream>>>(ws);
  k_prop1<<<456, 256, 0, stream>>>(adj_out, ws);
  k_prop2<<<456, 256, 0, stream>>>(adj_out, ws);
  k_outs<<<600, 256, 0, stream>>>(ws);
  k_se<<<1, 256, 0, stream>>>(gfW1, gfW2, ws);
  k_head<<<2400, 128, 0, stream>>>(e1W, e1b, e2W, e2b, ws, out);
}

// Round 21
// 234.837 us; speedup vs baseline: 1.4589x; 1.0003x over previous
//
#include <hip/hip_runtime.h>
#include <math.h>

// ---------------- problem constants ----------------
// B=4, N=600, S=168, D=40, Cc=32, Cs=16, Ce=128, Od=12
// Adjacency path: bit-exact Eigen/MLIR fast-tanh (clamp 7.99881172180175781f,
// FMA Horner, |x|<0.0004 passthrough) + Eigen seq-FMA dots. PROVEN R7-R19.
// R20: k_adj reverted to R18 single-buffer (57us proven) + column-sum
// epilogue (atomicAdd raw sums); k_invrb = tiny 1/(1+s) transform.

// ---------------- workspace layout ----------------
#define DW_WEFF 0          // [3][32][16] doubles
#define DW_CC   1536       // [3][32]
#define DW_P    1632       // [3][5][32][16] doubles = 7680
#define DW_Q    9312       // [3][5][32] doubles = 480
#define FB      19584      // float offset = 2*9792
#define OW_CSV  (FB+0)
#define OW_CBIG (FB+48)
#define OW_VBIG (FB+304)
#define OW_T    (FB+760112)
#define OW_FEAT (FB+1374512)
#define OW_N1   (FB+1604912)
#define OW_N2   (FB+1892912)
#define OW_IRA  (FB+2180912)
#define OW_IRB  (FB+2188112)
#define OW_U1A  (FB+2195312)
#define OW_U2A  (FB+2310512)
#define OW_U1B  (FB+2425712)
#define OW_U2B  (FB+2540912)
#define OW_U3A  (FB+2656112)
#define OW_U3B  (FB+2771312)
#define OW_O    (FB+2886512)
#define OW_SE   (FB+3040112)   // [16]
#define OW_SVS  (FB+3040128)   // [256] per-(s,b,o) row sums (atomic)
#define OW_CSB  (FB+3040384)   // [12][600] raw adjacency column sums (atomic)

// ---------------- Eigen/MLIR fast tanh f32 (FMA build), bit-faithful ----------------
__device__ __forceinline__ float tanh_eigen(float x)
{
  const float CL = 7.99881172180175781f;
  float xc = fminf(fmaxf(x, -CL), CL);
  float x2 = __fmul_rn(xc, xc);
  float p = fmaf(x2, -2.76076847742355e-16f, 2.00018790482477e-13f);
  p = fmaf(x2, p, -8.60467152213735e-11f);
  p = fmaf(x2, p, 5.12229709037114e-08f);
  p = fmaf(x2, p, 1.48572235717979e-05f);
  p = fmaf(x2, p, 6.37261928875436e-04f);
  p = fmaf(x2, p, 4.89352455891786e-03f);
  p = __fmul_rn(xc, p);
  float q = fmaf(x2, 1.19825839466702e-06f, 1.18534705686654e-04f);
  q = fmaf(x2, q, 2.26843463243900e-03f);
  q = fmaf(x2, q, 4.89352518554385e-03f);
  float r = __fdiv_rn(p, q);
  return fabsf(x) < 0.0004f ? x : r;
}

// ---------------- fused: weff fold (block 48) + const_sv (blocks 0..47) ----------------
__global__ __launch_bounds__(256) void k_pre_wc(const float* Ws, const float* bs,
    const float* scW0, const float* scW1, const float* scW2, const float* scb,
    const float* svW0, const float* svW1, const float* svW2,
    const float* gb, const float* svb, double* wd, float* ws)
{
  if (blockIdx.x < 48) {
    int blk = blockIdx.x;
    int i = blk/16, o = blk%16;
    const float* svW = (i==0)?svW0:((i==1)?svW1:svW2);
    int L = (i==0)?162:((i==1)?79:39);
    int tid = threadIdx.x;
    __shared__ double red[256];
    double s = 0;
    for (int idx = tid; idx < 32*L; idx += 256) {
      int o2 = idx / L, l = idx - o2*L;
      s += (double)svW[(o*32+o2)*L + l] * ((double)gb[(i*2+0)*32+o2] + (double)gb[(i*2+1)*32+o2]);
    }
    red[tid] = s; __syncthreads();
    for (int st = 128; st; st >>= 1) { if (tid < st) red[tid] += red[tid+st]; __syncthreads(); }
    if (tid == 0) ws[OW_CSV + blk] = (float)(red[0] + (double)svb[i*16+o]);
    return;
  }
  __shared__ double w0[32][7], c0[32], w1[32][12], c1[32];
  int t = threadIdx.x;
  for (int e = t; e < 32*7; e += 256) {
    int c = e/7, p = e%7; double s = 0;
    for (int ci = 0; ci < 32; ci++) s += (double)scW0[(c*32+ci)*7+p] * (double)Ws[ci];
    w0[c][p] = s;
  }
  for (int e = t; e < 32; e += 256) {
    double s = 0;
    for (int ci = 0; ci < 32; ci++) { double a = 0; for (int p = 0; p < 7; p++) a += (double)scW0[(e*32+ci)*7+p]; s += a*(double)bs[ci]; }
    c0[e] = s + (double)scb[e];
  }
  __syncthreads();
  for (int e = t; e < 32*12; e += 256) {
    int c = e/12, m = e%12; double s = 0;
    for (int k1 = 0; k1 < 6; k1++) { int k0 = m - k1; if (k0 < 0 || k0 > 6) continue;
      for (int ci = 0; ci < 32; ci++) s += (double)scW1[(c*32+ci)*6+k1] * w0[ci][k0]; }
    w1[c][m] = s;
  }
  for (int e = t; e < 32; e += 256) {
    double s = 0;
    for (int ci = 0; ci < 32; ci++) { double a = 0; for (int k1 = 0; k1 < 6; k1++) a += (double)scW1[(e*32+ci)*6+k1]; s += a*c0[ci]; }
    c1[e] = s + (double)scb[32+e];
  }
  __syncthreads();
  for (int e = t; e < 32*16; e += 256) {
    int c = e/16, p = e%16; double s = 0;
    for (int k2 = 0; k2 < 3; k2++) { int m = p - 2*k2; if (m < 0 || m > 11) continue;
      for (int ci = 0; ci < 32; ci++) s += (double)scW2[(c*32+ci)*3+k2] * w1[ci][m]; }
    wd[DW_WEFF + (2*32+c)*16 + p] = s;
  }
  for (int e = t; e < 32; e += 256) {
    double s = 0;
    for (int ci = 0; ci < 32; ci++) { double a = 0; for (int k2 = 0; k2 < 3; k2++) a += (double)scW2[(e*32+ci)*3+k2]; s += a*c1[ci]; }
    wd[DW_CC + 64 + e] = s + (double)scb[64+e];
  }
  for (int e = t; e < 32*7;  e += 256) wd[DW_WEFF + (e/7)*16  + e%7 ] = w0[e/7][e%7];
  for (int e = t; e < 32*12; e += 256) wd[DW_WEFF + (32 + e/12)*16 + e%12] = w1[e/12][e%12];
  for (int e = t; e < 32; e += 256) { wd[DW_CC+e] = c0[e]; wd[DW_CC+32+e] = c1[e]; }
}

// ---------------- P[i][g][o2][p] + Q[i][g][o2]  (15 blocks, LDS-staged gW) ----------------
__global__ __launch_bounds__(256) void k_pre_p(const float* gW, double* wd)
{
  int blk = blockIdx.x;      // i*5+g
  int i = blk/5, g = blk%5;
  int tid = threadIdx.x;
  __shared__ float gls[2][3072];
  __shared__ double weffs[512];
  __shared__ double ccs[32];
  for (int e = tid; e < 6144; e += 256) gls[e/3072][e % 3072] = gW[i*6144 + e];
  for (int e = tid; e < 512; e += 256) weffs[e] = wd[DW_WEFF + i*512 + e];
  if (tid < 32) ccs[tid] = wd[DW_CC + i*32 + tid];
  __syncthreads();
  const float* g0 = gls[0];
  const float* g1 = gls[1];
  for (int e = tid; e < 512; e += 256) {
    int o2 = e >> 4, p = e & 15;
    double s = 0;
    for (int c = 0; c < 32; c++) {
      float w;
      if (g == 0) w = g0[c*32+o2] + g1[c*32+o2]
                    + 0.05f*(g0[(32+c)*32+o2] + g0[(64+c)*32+o2] + g1[(32+c)*32+o2] + g1[(64+c)*32+o2]);
      else if (g == 1) w = g0[(32+c)*32+o2];
      else if (g == 2) w = g0[(64+c)*32+o2];
      else if (g == 3) w = g1[(32+c)*32+o2];
      else             w = g1[(64+c)*32+o2];
      s += (double)w * weffs[c*16 + p];
    }
    wd[DW_P + ((i*5+g)*32 + o2)*16 + p] = s;
  }
  if (tid < 32) {
    int o2 = tid;
    double s = 0;
    for (int c = 0; c < 32; c++) {
      float w;
      if (g == 0) w = g0[c*32+o2] + g1[c*32+o2]
                    + 0.05f*(g0[(32+c)*32+o2] + g0[(64+c)*32+o2] + g1[(32+c)*32+o2] + g1[(64+c)*32+o2]);
      else if (g == 1) w = g0[(32+c)*32+o2];
      else if (g == 2) w = g0[(64+c)*32+o2];
      else if (g == 3) w = g1[(32+c)*32+o2];
      else             w = g1[(64+c)*32+o2];
      s += (double)w * ccs[c];
    }
    wd[DW_Q + (i*5+g)*32 + o2] = s;
  }
}

// ---------------- t-path/out0 fused weight columns (svW x P) + cbig (svW x Q) ----------------
__global__ __launch_bounds__(256) void k_pre_v(const float* svW0, const float* svW1, const float* svW2,
                                               const float* s0W, const float* s0b, double* wd, float* ws)
{
  int jj = blockIdx.x;             // 0..255
  int tid = threadIdx.x;
  if (jj >= 240) {
    int o = jj - 240;
    if (tid < 168) ws[OW_VBIG + jj*168 + tid] = s0W[o*168 + tid];
    if (tid == 0)  ws[OW_CBIG + jj] = s0b[o];
    return;
  }
  int i = jj/80, g = (jj%80)/16, o = jj%16;
  int st = (i==0)?1:((i==1)?2:4), tp = (i==0)?7:((i==1)?12:16), L = (i==0)?162:((i==1)?79:39);
  const float* svW = (i==0)?svW0:((i==1)?svW1:svW2);
  const float* svo = svW + o*32*L;
  __shared__ float svlds[32*162];
  __shared__ double Pl[32][16];
  __shared__ double Qs[32];
  __shared__ double red[256];
  int NL = 32*L;
  for (int e = tid; e < NL; e += 256) svlds[e] = svo[e];
  for (int e = tid; e < 512; e += 256) {
    int o2 = e >> 4, p = e & 15;
    Pl[o2][p] = wd[DW_P + ((i*5+g)*32 + o2)*16 + p];
  }
  if (tid < 32) Qs[tid] = wd[DW_Q + (i*5+g)*32 + tid];
  __syncthreads();
  double s = 0;
  for (int e = tid; e < NL; e += 256) s += (double)svlds[e] * Qs[e / L];
  red[tid] = s; __syncthreads();
  for (int stp = 128; stp; stp >>= 1) { if (tid < stp) red[tid] += red[tid+stp]; __syncthreads(); }
  if (tid == 0) ws[OW_CBIG + jj] = (float)red[0];
  if (tid < 168) {
    int u = tid;
    int lo_ = u - tp + 1;
    int lmin = lo_ > 0 ? (lo_ + st - 1)/st : 0;
    int lmax = u/st; if (lmax > L-1) lmax = L-1;
    double v = 0.0;
    for (int o2 = 0; o2 < 32; o2++) {
      const float* sv = svlds + o2*L;
      const double* Pp = Pl[o2];
      for (int l = lmin; l <= lmax; l++)
        v += (double)sv[l] * Pp[u - st*l];
    }
    ws[OW_VBIG + jj*168 + u] = (float)v;
  }
}

// ---------------- fused: feat (blocks 0..299) + t-path GEMM (300..449) ----------------
__global__ __launch_bounds__(256) void k_fg(const float* x, double* wd, float* ws)
{
  int t = threadIdx.x;
  if (blockIdx.x >= 300) {
    __shared__ float xs[16][168];
    int r0 = (blockIdx.x - 300)*16;
    for (int e = t; e < 16*168; e += 256) { int r = e/168, u = e%168; xs[r][u] = x[(r0+r)*168 + u]; }
    __syncthreads();
    int jj = t;
    const float* V = ws + OW_VBIG + jj*168;
    double a[16];
    #pragma unroll
    for (int r = 0; r < 16; r++) a[r] = 0;
    for (int u = 0; u < 168; u++) {
      float wv = V[u];
      #pragma unroll
      for (int r = 0; r < 16; r++) a[r] += (double)wv * (double)xs[r][u];
    }
    double cb = (double)ws[OW_CBIG + jj];
    for (int r = 0; r < 16; r++)
      ws[OW_T + (r0+r)*256 + jj] = (float)(a[r] + cb);
    return;
  }
  int blk = blockIdx.x;      // 4*75
  int b = blk / 75, n0 = (blk % 75) * 8;
  __shared__ float xsf[8][168];
  __shared__ double xbar[8][35];
  for (int e = t; e < 8*168; e += 256) xsf[e/168][e%168] = x[(b*600 + n0 + e/168)*168 + e%168];
  __syncthreads();
  for (int e = t; e < 8*35; e += 256) {
    int nn = e/35, slot = e%35;
    int i = slot < 7 ? 0 : (slot < 19 ? 1 : 2);
    int p = slot - (i==0?0:(i==1?7:19));
    int st = (i==0)?1:((i==1)?2:4), L = (i==0)?162:((i==1)?79:39);
    double s = 0;
    for (int l = 0; l < L; l++) s += (double)xsf[nn][st*l+p];
    xbar[nn][slot] = s / (double)L;
  }
  __syncthreads();
  int nn = t >> 5, c = t & 31;
  for (int i = 0; i < 3; i++) {
    int off = (i==0)?0:((i==1)?7:19), tp = (i==0)?7:((i==1)?12:16);
    double f = wd[DW_CC + i*32 + c];
    for (int p = 0; p < tp; p++) f += wd[DW_WEFF + (i*32+c)*16 + p] * xbar[nn][off+p];
    ws[OW_FEAT + ((i*4+b)*600 + n0+nn)*32 + c] = (float)f;
  }
}

// ---------------- n1/n2: LDS-staged weights, 16 nodes per block ----------------
__global__ __launch_bounds__(256) void k_nodes(const float* lin1W, const float* lin1b,
                                               const float* lin2W, const float* lin2b,
                                               const float* emb1, const float* emb2, float* ws)
{
  int blk = blockIdx.x;  // i*152 + b*38 + nt
  int nt = blk % 38, b = (blk/38) % 4, i = blk/152;
  int n0 = nt*16;
  __shared__ float W1[1280], W2[1280], b1[40], b2[40], sf[16][33];
  int t = threadIdx.x;
  for (int e = t; e < 1280; e += 256) { W1[e] = lin1W[i*1280 + e]; W2[e] = lin2W[i*1280 + e]; }
  if (t < 40) { b1[t] = lin1b[i*40 + t]; b2[t] = lin2b[i*40 + t]; }
  for (int e = t; e < 16*32; e += 256) {
    int nn = e >> 5, c = e & 31; int n = n0 + nn;
    sf[nn][c] = (n < 600) ? ws[OW_FEAT + ((i*4+b)*600 + n)*32 + c] : 0.f;
  }
  __syncthreads();
  const float TSF[3] = {3.0f, 2.4f, 1.8f};
  for (int item = t; item < 16*80; item += 256) {
    int nn = item / 80, rr = item % 80;
    int n = n0 + nn; if (n >= 600) continue;
    int which = rr/40, d = rr%40;
    const float* W  = which ? W2 : W1;
    const float* bv = which ? b2 : b1;
    const float* em = which ? emb2 : emb1;
    float pre = 0.f;
    #pragma unroll
    for (int c = 0; c < 32; c++) pre = fmaf(sf[nn][c], W[c*40+d], pre);
    float p2 = __fadd_rn(pre, bv[d]);
    float p3 = __fadd_rn(p2, em[n*40+d]);
    float arg = __fmul_rn(TSF[i], p3);
    ws[(which ? OW_N2 : OW_N1) + ((i*4+b)*600 + n)*40 + d] = tanh_eigen(arg);
  }
}

// ---------------- adjacency staging helper ----------------
__device__ __forceinline__ float4 adj_ld(const float* n1, const float* n2, int e, int w0)
{
  int mat = e >= 320; int idx = e - 320*mat;
  int jj = idx/10, q = idx - 10*jj;
  int w = w0 + jj;
  if (w < 600) return *(const float4*)((mat ? n2 : n1) + w*40 + 4*q);
  float4 z; z.x = z.y = z.z = z.w = 0.f; return z;
}

// ---------------- adjacency: R18 single-buffer + colsum epilogue ----------------
__global__ __launch_bounds__(256) void k_adj(float* adj_out, float* ws)
{
  int blk = blockIdx.x;                 // 3*4*75
  int tile = blk % 75, b = (blk/75) % 4, i = blk/300;
  int row0 = tile*8;
  const float* n1 = ws + OW_N1 + (i*4+b)*24000;
  const float* n2 = ws + OW_N2 + (i*4+b)*24000;
  __shared__ float c1s[32][44], c2s[32][44];
  __shared__ float svals[8][604];       // 604%32==28: conflict-free
  int t = threadIdx.x;
  int rc = t & 7, jc = t >> 3;          // 8 lanes share each column address
  float am1[40], am2[40];
  {
    const float4* m1p = (const float4*)(n1 + (row0 + rc)*40);
    const float4* m2p = (const float4*)(n2 + (row0 + rc)*40);
    #pragma unroll
    for (int q = 0; q < 10; q++) {
      float4 v1 = m1p[q], v2 = m2p[q];
      am1[4*q]=v1.x; am1[4*q+1]=v1.y; am1[4*q+2]=v1.z; am1[4*q+3]=v1.w;
      am2[4*q]=v2.x; am2[4*q+1]=v2.y; am2[4*q+2]=v2.z; am2[4*q+3]=v2.w;
    }
  }
  float4 s0 = adj_ld(n1, n2, t, 0);
  float4 s1 = adj_ld(n1, n2, t + 256, 0);
  float4 s2; if (t < 128) s2 = adj_ld(n1, n2, t + 512, 0);
  for (int k = 0; k < 19; k++) {
    int w0 = 32*k;
    __syncthreads();
    {
      int e = t;       { int mat=e>=320, idx=e-320*mat, jj=idx/10, q=idx-10*jj, w=w0+jj;
                         if (w<600) *(float4*)(&(mat?c2s:c1s)[jj][4*q]) = s0; }
      e = t + 256;     { int mat=e>=320, idx=e-320*mat, jj=idx/10, q=idx-10*jj, w=w0+jj;
                         if (w<600) *(float4*)(&(mat?c2s:c1s)[jj][4*q]) = s1; }
      if (t < 128) { e = t + 512; int mat=e>=320, idx=e-320*mat, jj=idx/10, q=idx-10*jj, w=w0+jj;
                         if (w<600) *(float4*)(&(mat?c2s:c1s)[jj][4*q]) = s2; }
    }
    __syncthreads();
    if (k < 18) {
      int w0n = w0 + 32;
      s0 = adj_ld(n1, n2, t, w0n);
      s1 = adj_ld(n1, n2, t + 256, w0n);
      if (t < 128) s2 = adj_ld(n1, n2, t + 512, w0n);
    }
    if (jc < 32) {
      int w = w0 + jc;
      if (w < 600) {
        const float4* c2p = (const float4*)c2s[jc];
        const float4* c1p = (const float4*)c1s[jc];
        float d1 = 0.f, d2 = 0.f;
        #pragma unroll
        for (int q = 0; q < 10; q++) {          // ascending d, single accumulator: bit-exact
          float4 v = c2p[q];
          d1 = fmaf(am1[4*q], v.x, d1); d1 = fmaf(am1[4*q+1], v.y, d1);
          d1 = fmaf(am1[4*q+2], v.z, d1); d1 = fmaf(am1[4*q+3], v.w, d1);
        }
        #pragma unroll
        for (int q = 0; q < 10; q++) {
          float4 v = c1p[q];
          d2 = fmaf(am2[4*q], v.x, d2); d2 = fmaf(am2[4*q+1], v.y, d2);
          d2 = fmaf(am2[4*q+2], v.z, d2); d2 = fmaf(am2[4*q+3], v.w, d2);
        }
        float af = __fsub_rn(d1, d2);
        float tv = __fmul_rn(3.0f, af);
        float v = tanh_eigen(tv);
        svals[rc][w] = v > 0.f ? v : 0.f;       // relu
      }
    }
  }
  __syncthreads();
  // ---- top-k phase: proven logic, vv from svals ----
  int r = t >> 5, j = t & 31;
  float vv[19];
  #pragma unroll
  for (int k = 0; k < 19; k++) {
    int w = j + 32*k;
    vv[k] = (w < 600) ? svals[r][w] : 0.f;
  }
  float rm = 0.f;
  #pragma unroll
  for (int k = 0; k < 19; k++) rm = fmaxf(rm, vv[k]);
  #pragma unroll
  for (int s = 16; s; s >>= 1) rm = fmaxf(rm, __shfl_xor(rm, s, 32));
  const float VP = tanh_eigen(8.0f);
  unsigned int vpb = __float_as_uint(VP);
  int cntp = 0;
  #pragma unroll
  for (int k = 0; k < 19; k++) { int w = j + 32*k; if (w < 600 && __float_as_uint(vv[k]) >= vpb) cntp++; }
  #pragma unroll
  for (int s = 16; s; s >>= 1) cntp += __shfl_xor(cntp, s, 32);
  unsigned int lo, hi;
  unsigned int mb1 = __float_as_uint(rm) + 1u;
  if (cntp >= 20) { lo = vpb; hi = mb1; }
  else            { lo = 0u;  hi = vpb < mb1 ? vpb : mb1; }
  while (hi - lo > 1u) {
    unsigned int mid = lo + ((hi - lo) >> 1);
    int cnt = 0;
    #pragma unroll
    for (int k = 0; k < 19; k++) {
      int w = j + 32*k;
      if (w < 600 && __float_as_uint(vv[k]) >= mid) cnt++;
    }
    #pragma unroll
    for (int s = 16; s; s >>= 1) cnt += __shfl_xor(cnt, s, 32);
    if (cnt >= 20) lo = mid; else hi = mid;
  }
  unsigned int kb = lo;
  float* arow = adj_out + (i*4+b)*360000 + (row0+r)*600;
  float rsum = 0.f;
  #pragma unroll
  for (int k = 0; k < 19; k++) {
    int w = j + 32*k;
    if (w < 600) {
      float v = (__float_as_uint(vv[k]) >= kb) ? vv[k] : 0.f;
      arow[w] = v;
      svals[r][w] = v;                  // masked write-back for column sums
      rsum += v;
    }
  }
  #pragma unroll
  for (int s = 16; s; s >>= 1) rsum += __shfl_xor(rsum, s, 32);
  if (j == 0) ws[OW_IRA + (i*4+b)*600 + row0 + r] = 1.f/(1.f + rsum);
  __syncthreads();
  // ---- column-sum epilogue: 8-row partials -> atomic raw sums ----
  {
    float* csb = ws + OW_CSB + (i*4+b)*600;
    for (int w = t; w < 600; w += 256) {
      float cs = 0.f;
      #pragma unroll
      for (int rr2 = 0; rr2 < 8; rr2++) cs += svals[rr2][w];
      atomicAdd(&csb[w], cs);
    }
  }
}

// ---------------- inv row sums for transposed direction: 1/(1+csum) ----------------
__global__ void k_invrb(float* ws)
{
  int e = blockIdx.x*256 + threadIdx.x;
  if (e < 7200) ws[OW_IRB + e] = 1.f/(1.f + ws[OW_CSB + e]);
}

// ---------------- prop1: 4w x 4oz per thread, per-wave K-split, b128 LDS ----------------
__global__ __launch_bounds__(256) void k_prop1(const float* adj, float* ws)
{
  int blk = blockIdx.x;            // ib*38 + d*19 + wt
  int wt = blk % 19;
  int d  = (blk / 19) & 1;
  int ib = blk / 38;
  int i = ib >> 2, b = ib & 3;
  int w0 = wt * 32;
  const float* A   = adj + ib*360000;
  const float* irx = ws + (d ? OW_IRB : OW_IRA) + ib*600;
  const float* Tb  = ws + OW_T + (b*600)*256 + i*80 + 16 + d*32;
  __shared__ float As[4][32][36];
  __shared__ float Zs[4][32][36];
  __shared__ float red[3][64][17];
  int tid = threadIdx.x;
  int wv = tid >> 6, ln = tid & 63;
  int wq = ln >> 3, oq = ln & 7;
  float acc[4][4];
  #pragma unroll
  for (int a1 = 0; a1 < 4; a1++)
    #pragma unroll
    for (int a2 = 0; a2 < 4; a2++) acc[a1][a2] = 0.f;
  int vbeg = wv*160, vend = vbeg + 160 < 600 ? vbeg + 160 : 600;
  for (int v0 = vbeg; v0 < vend; v0 += 32) {
    if (d == 0) {
      #pragma unroll
      for (int q = 0; q < 4; q++) {
        int m = q*64 + ln, rr = m >> 3, c4 = (m & 7)*4;
        int v = v0 + rr;
        float4 av; av.x = av.y = av.z = av.w = 0.f;
        if (v < 600) {
          int wb = w0 + c4;
          if (wb + 3 < 600) av = *(const float4*)(A + v*600 + wb);
          else {
            if (wb+0 < 600) av.x = A[v*600 + wb+0];
            if (wb+1 < 600) av.y = A[v*600 + wb+1];
            if (wb+2 < 600) av.z = A[v*600 + wb+2];
            if (wb+3 < 600) av.w = A[v*600 + wb+3];
          }
        }
        *(float4*)(&As[wv][rr][c4]) = av;
      }
    } else {
      #pragma unroll
      for (int q = 0; q < 4; q++) {
        int m = q*64 + ln, rr = m >> 3, c4 = (m & 7)*4;
        int w = w0 + rr;
        float4 av; av.x = av.y = av.z = av.w = 0.f;
        if (w < 600) {
          if (v0 + c4 + 3 < 600) av = *(const float4*)(A + w*600 + v0 + c4);
          else {
            if (v0+c4+0 < 600) av.x = A[w*600 + v0+c4+0];
            if (v0+c4+1 < 600) av.y = A[w*600 + v0+c4+1];
            if (v0+c4+2 < 600) av.z = A[w*600 + v0+c4+2];
            if (v0+c4+3 < 600) av.w = A[w*600 + v0+c4+3];
          }
        }
        As[wv][c4+0][rr] = av.x; As[wv][c4+1][rr] = av.y;
        As[wv][c4+2][rr] = av.z; As[wv][c4+3][rr] = av.w;
      }
    }
    #pragma unroll
    for (int q = 0; q < 4; q++) {
      int m = q*64 + ln, rr = m >> 3, c4 = (m & 7)*4;
      int v = v0 + rr;
      float4 zv; zv.x = zv.y = zv.z = zv.w = 0.f;
      if (v < 600) {
        float ir = irx[v];
        float4 tv = *(const float4*)(Tb + v*256 + c4);
        zv.x = ir*tv.x; zv.y = ir*tv.y; zv.z = ir*tv.z; zv.w = ir*tv.w;
      }
      *(float4*)(&Zs[wv][rr][c4]) = zv;
    }
    __builtin_amdgcn_s_waitcnt(0);
    for (int vl = 0; vl < 32; vl++) {
      float4 a4 = *(const float4*)(&As[wv][vl][wq*4]);
      float4 z4 = *(const float4*)(&Zs[wv][vl][oq*4]);
      acc[0][0] = fmaf(a4.x, z4.x, acc[0][0]); acc[0][1] = fmaf(a4.x, z4.y, acc[0][1]);
      acc[0][2] = fmaf(a4.x, z4.z, acc[0][2]); acc[0][3] = fmaf(a4.x, z4.w, acc[0][3]);
      acc[1][0] = fmaf(a4.y, z4.x, acc[1][0]); acc[1][1] = fmaf(a4.y, z4.y, acc[1][1]);
      acc[1][2] = fmaf(a4.y, z4.z, acc[1][2]); acc[1][3] = fmaf(a4.y, z4.w, acc[1][3]);
      acc[2][0] = fmaf(a4.z, z4.x, acc[2][0]); acc[2][1] = fmaf(a4.z, z4.y, acc[2][1]);
      acc[2][2] = fmaf(a4.z, z4.z, acc[2][2]); acc[2][3] = fmaf(a4.z, z4.w, acc[2][3]);
      acc[3][0] = fmaf(a4.w, z4.x, acc[3][0]); acc[3][1] = fmaf(a4.w, z4.y, acc[3][1]);
      acc[3][2] = fmaf(a4.w, z4.z, acc[3][2]); acc[3][3] = fmaf(a4.w, z4.w, acc[3][3]);
    }
  }
  if (wv > 0) {
    #pragma unroll
    for (int kw = 0; kw < 4; kw++)
      #pragma unroll
      for (int ko = 0; ko < 4; ko++) red[wv-1][ln][kw*4+ko] = acc[kw][ko];
  }
  __syncthreads();
  if (wv == 0) {
    #pragma unroll
    for (int kw = 0; kw < 4; kw++) {
      int w = w0 + wq*4 + kw;
      if (w >= 600) continue;
      float irw = irx[w];
      #pragma unroll
      for (int ko = 0; ko < 4; ko++) {
        int oz = oq*4 + ko;
        float sum = acc[kw][ko] + red[0][ln][kw*4+ko] + red[1][ln][kw*4+ko] + red[2][ln][kw*4+ko];
        sum += irw * Tb[w*256 + oz];
        float* dst = ws + (d==0 ? (oz < 16 ? OW_U1A : OW_U2A) : (oz < 16 ? OW_U1B : OW_U2B));
        dst[(ib*600 + w)*16 + (oz & 15)] = sum;
      }
    }
  }
}

// ---------------- prop2: 4w x 2oz per thread, per-wave K-split ----------------
__global__ __launch_bounds__(256) void k_prop2(const float* adj, float* ws)
{
  int blk = blockIdx.x;            // ib*38 + d*19 + wt
  int wt = blk % 19;
  int d  = (blk / 19) & 1;
  int ib = blk / 38;
  int w0 = wt * 32;
  const float* A   = adj + ib*360000;
  const float* irx = ws + (d ? OW_IRB : OW_IRA) + ib*600;
  const float* u2x = ws + (d ? OW_U2B : OW_U2A) + ib*9600;
  __shared__ float As[4][32][36];
  __shared__ float Zs[4][32][20];
  __shared__ float red[3][64][9];
  int tid = threadIdx.x;
  int wv = tid >> 6, ln = tid & 63;
  int wq = ln >> 3, oq = ln & 7;
  float acc[4][2];
  #pragma unroll
  for (int a1 = 0; a1 < 4; a1++) { acc[a1][0] = 0.f; acc[a1][1] = 0.f; }
  int vbeg = wv*160, vend = vbeg + 160 < 600 ? vbeg + 160 : 600;
  for (int v0 = vbeg; v0 < vend; v0 += 32) {
    if (d == 0) {
      #pragma unroll
      for (int q = 0; q < 4; q++) {
        int m = q*64 + ln, rr = m >> 3, c4 = (m & 7)*4;
        int v = v0 + rr;
        float4 av; av.x = av.y = av.z = av.w = 0.f;
        if (v < 600) {
          int wb = w0 + c4;
          if (wb + 3 < 600) av = *(const float4*)(A + v*600 + wb);
          else {
            if (wb+0 < 600) av.x = A[v*600 + wb+0];
            if (wb+1 < 600) av.y = A[v*600 + wb+1];
            if (wb+2 < 600) av.z = A[v*600 + wb+2];
            if (wb+3 < 600) av.w = A[v*600 + wb+3];
          }
        }
        *(float4*)(&As[wv][rr][c4]) = av;
      }
    } else {
      #pragma unroll
      for (int q = 0; q < 4; q++) {
        int m = q*64 + ln, rr = m >> 3, c4 = (m & 7)*4;
        int w = w0 + rr;
        float4 av; av.x = av.y = av.z = av.w = 0.f;
        if (w < 600) {
          if (v0 + c4 + 3 < 600) av = *(const float4*)(A + w*600 + v0 + c4);
          else {
            if (v0+c4+0 < 600) av.x = A[w*600 + v0+c4+0];
            if (v0+c4+1 < 600) av.y = A[w*600 + v0+c4+1];
            if (v0+c4+2 < 600) av.z = A[w*600 + v0+c4+2];
            if (v0+c4+3 < 600) av.w = A[w*600 + v0+c4+3];
          }
        }
        As[wv][c4+0][rr] = av.x; As[wv][c4+1][rr] = av.y;
        As[wv][c4+2][rr] = av.z; As[wv][c4+3][rr] = av.w;
      }
    }
    #pragma unroll
    for (int q = 0; q < 2; q++) {
      int m = q*64 + ln, rr = m >> 2, c4 = (m & 3)*4;
      int v = v0 + rr;
      float4 zv; zv.x = zv.y = zv.z = zv.w = 0.f;
      if (v < 600) {
        float ir = irx[v];
        float4 uv = *(const float4*)(u2x + v*16 + c4);
        zv.x = ir*uv.x; zv.y = ir*uv.y; zv.z = ir*uv.z; zv.w = ir*uv.w;
      }
      *(float4*)(&Zs[wv][rr][c4]) = zv;
    }
    __builtin_amdgcn_s_waitcnt(0);
    for (int vl = 0; vl < 32; vl++) {
      float4 a4 = *(const float4*)(&As[wv][vl][wq*4]);
      float2 z2 = *(const float2*)(&Zs[wv][vl][oq*2]);
      acc[0][0] = fmaf(a4.x, z2.x, acc[0][0]); acc[0][1] = fmaf(a4.x, z2.y, acc[0][1]);
      acc[1][0] = fmaf(a4.y, z2.x, acc[1][0]); acc[1][1] = fmaf(a4.y, z2.y, acc[1][1]);
      acc[2][0] = fmaf(a4.z, z2.x, acc[2][0]); acc[2][1] = fmaf(a4.z, z2.y, acc[2][1]);
      acc[3][0] = fmaf(a4.w, z2.x, acc[3][0]); acc[3][1] = fmaf(a4.w, z2.y, acc[3][1]);
    }
  }
  if (wv > 0) {
    #pragma unroll
    for (int kw = 0; kw < 4; kw++) {
      red[wv-1][ln][kw*2+0] = acc[kw][0];
      red[wv-1][ln][kw*2+1] = acc[kw][1];
    }
  }
  __syncthreads();
  if (wv == 0) {
    float* dst = ws + (d==0 ? OW_U3A : OW_U3B);
    #pragma unroll
    for (int kw = 0; kw < 4; kw++) {
      int w = w0 + wq*4 + kw;
      if (w >= 600) continue;
      float irw = irx[w];
      #pragma unroll
      for (int ko = 0; ko < 2; ko++) {
        int oz = oq*2 + ko;
        float sum = acc[kw][ko] + red[0][ln][kw*2+ko] + red[1][ln][kw*2+ko] + red[2][ln][kw*2+ko];
        sum += irw * u2x[w*16 + oz];
        dst[(ib*600 + w)*16 + oz] = sum;
      }
    }
  }
}

// ---------------- assemble head outputs + fused SE row sums ----------------
__global__ __launch_bounds__(256) void k_outs(float* ws)
{
  __shared__ float sums[2];
  int tid = threadIdx.x;
  int e = blockIdx.x*256 + tid;
  int rA = (blockIdx.x*256)/600;
  if (tid < 2) sums[tid] = 0.f;
  __syncthreads();
  float val = 0.f;
  int row = rA;
  if (e < 153600) {
    int n = e % 600, o = (e/600) % 16, b = (e/9600) % 4, s = e/38400;
    if (s == 0) {
      val = ws[OW_T + (b*600+n)*256 + 240 + o];
    } else {
      int i = s - 1;
      int idx = ((i*4+b)*600 + n)*16 + o;
      float t0 = ws[OW_T + (b*600+n)*256 + i*80 + o];
      val = t0 + 0.95f  * (ws[OW_U1A+idx] + ws[OW_U1B+idx])
               + 0.0475f* (ws[OW_U2A+idx] + ws[OW_U2B+idx])
               + 0.9025f* (ws[OW_U3A+idx] + ws[OW_U3B+idx])
               + ws[OW_CSV + i*16 + o];
    }
    ws[OW_O + ((s*4+b)*16 + o)*600 + n] = val;
    row = e/600;
  }
  float vA = (e < 153600 && row == rA) ? val : 0.f;
  float vB = (e < 153600 && row == rA+1) ? val : 0.f;
  #pragma unroll
  for (int s = 32; s; s >>= 1) { vA += __shfl_down(vA, s, 64); vB += __shfl_down(vB, s, 64); }
  if ((tid & 63) == 0) {
    if (vA != 0.f) atomicAdd(&sums[0], vA);
    if (vB != 0.f) atomicAdd(&sums[1], vB);
  }
  __syncthreads();
  if (tid < 2) {
    int r = rA + tid;
    if (r < 256) atomicAdd(&ws[OW_SVS + r], sums[tid]);
  }
}

// ---------------- SE gate (reads fused sums) ----------------
__global__ void k_se(const float* gfW1, const float* gfW2, float* ws)
{
  __shared__ float sv[4][64], hb[4][4];
  int t = threadIdx.x;
  {
    int row = t;
    int o = row & 15, b = (row >> 4) & 3, s = row >> 6;
    sv[b][s*16 + o] = ws[OW_SVS + row] * (1.f/600.f);
  }
  __syncthreads();
  if (t < 16) {
    int bb = t >> 2, j = t & 3;
    float h = 0.f;
    for (int kk = 0; kk < 64; kk++) h += sv[bb][kk]*gfW1[kk*4+j];
    hb[bb][j] = h > 0.f ? h : 0.f;
  }
  __syncthreads();
  if (t < 16) {
    int bb = t >> 2, ii = t & 3;
    float g = 0.f;
    for (int j = 0; j < 4; j++) g += hb[bb][j]*gfW2[j*4+ii];
    ws[OW_SE + bb*4 + ii] = 1.f/(1.f + expf(-g));
  }
}

// ---------------- gate + end MLP (parallel final stage) ----------------
__global__ __launch_bounds__(128) void k_head(const float* e1W, const float* e1b,
                                              const float* e2W, const float* e2b,
                                              float* ws, float* dout)
{
  int blk = blockIdx.x, b = blk/600, n = blk%600;
  __shared__ float y0[16], y1[128];
  int t = threadIdx.x;
  if (t < 16) {
    float f = 0.f;
    for (int s = 0; s < 4; s++) f += ws[OW_SE + b*4 + s] * ws[OW_O + ((s*4+b)*16 + t)*600 + n];
    f *= 0.25f;
    y0[t] = f > 0.f ? f : 0.f;
  }
  __syncthreads();
  {
    float h = e1b[t];
    for (int o = 0; o < 16; o++) h += e1W[t*16+o]*y0[o];
    y1[t] = h > 0.f ? h : 0.f;
  }
  __syncthreads();
  if (t < 96) {
    int o = t >> 3, part = t & 7;   // 12 outputs x 8 partials
    float v = 0.f;
    #pragma unroll
    for (int e = 0; e < 16; e++) v = fmaf(e2W[o*128 + part*16 + e], y1[part*16 + e], v);
    #pragma unroll
    for (int s = 4; s; s >>= 1) v += __shfl_down(v, s, 8);
    if (part == 0) dout[b*7200 + o*600 + n] = e2b[o] + v;
  }
}

extern "C" void kernel_launch(void* const* d_in, const int* in_sizes, int n_in,
                              void* d_out, int out_size, void* d_ws, size_t ws_size,
                              hipStream_t stream)
{
  const float* x    = (const float*)d_in[0];
  const float* Ws   = (const float*)d_in[1];
  const float* bs   = (const float*)d_in[2];
  const float* scW0 = (const float*)d_in[3];
  const float* scW1 = (const float*)d_in[4];
  const float* scW2 = (const float*)d_in[5];
  const float* scb  = (const float*)d_in[6];
  const float* emb1 = (const float*)d_in[7];
  const float* emb2 = (const float*)d_in[8];
  const float* lin1W= (const float*)d_in[9];
  const float* lin1b= (const float*)d_in[10];
  const float* lin2W= (const float*)d_in[11];
  const float* lin2b= (const float*)d_in[12];
  const float* gW   = (const float*)d_in[13];
  const float* gb   = (const float*)d_in[14];
  const float* svW0 = (const float*)d_in[15];
  const float* svW1 = (const float*)d_in[16];
  const float* svW2 = (const float*)d_in[17];
  const float* svb  = (const float*)d_in[18];
  const float* s0W  = (const float*)d_in[19];
  const float* s0b  = (const float*)d_in[20];
  const float* gfW1 = (const float*)d_in[21];
  const float* gfW2 = (const float*)d_in[22];
  const float* e1W  = (const float*)d_in[23];
  const float* e1b  = (const float*)d_in[24];
  const float* e2W  = (const float*)d_in[25];
  const float* e2b  = (const float*)d_in[26];
  float* out = (float*)d_out;
  float* ws  = (float*)d_ws;
  double* wd = (double*)d_ws;
  float* adj_out = out + 28800;

  k_pre_wc<<<49, 256, 0, stream>>>(Ws, bs, scW0, scW1, scW2, scb,
                                   svW0, svW1, svW2, gb, svb, wd, ws);
  k_pre_p<<<15, 256, 0, stream>>>(gW, wd);
  k_pre_v<<<256, 256, 0, stream>>>(svW0, svW1, svW2, s0W, s0b, wd, ws);
  hipMemsetAsync((void*)(ws + OW_SVS), 0, (256 + 7200)*sizeof(float), stream);
  k_fg<<<450, 256, 0, stream>>>(x, wd, ws);
  k_nodes<<<456, 256, 0, stream>>>(lin1W, lin1b, lin2W, lin2b, emb1, emb2, ws);
  k_adj<<<900, 256, 0, stream>>>(adj_out, ws);
  k_invrb<<<29, 256, 0, stream>>>(ws);
  k_prop1<<<456, 256, 0, stream>>>(adj_out, ws);
  k_prop2<<<456, 256, 0, stream>>>(adj_out, ws);
  k_outs<<<600, 256, 0, stream>>>(ws);
  k_se<<<1, 256, 0, stream>>>(gfW1, gfW2, ws);
  k_head<<<2400, 128, 0, stream>>>(e1W, e1b, e2W, e2b, ws, out);
}

// Round 22
// 227.936 us; speedup vs baseline: 1.5031x; 1.0303x over previous
//
#include <hip/hip_runtime.h>
#include <math.h>

// ---------------- problem constants ----------------
// B=4, N=600, S=168, D=40, Cc=32, Cs=16, Ce=128, Od=12
// Adjacency path: bit-exact Eigen/MLIR fast-tanh (clamp 7.99881172180175781f,
// FMA Horner, |x|<0.0004 passthrough) + Eigen seq-FMA dots. PROVEN R7-R21.
// R22: k_adj 16 rows/block (grid 456) - halves redundant L2 staging traffic
// (was 75x re-read of 192KB panel per (i,b)); 16-way column broadcast.

// ---------------- workspace layout ----------------
#define DW_WEFF 0          // [3][32][16] doubles
#define DW_CC   1536       // [3][32]
#define DW_P    1632       // [3][5][32][16] doubles = 7680
#define DW_Q    9312       // [3][5][32] doubles = 480
#define FB      19584      // float offset = 2*9792
#define OW_CSV  (FB+0)
#define OW_CBIG (FB+48)
#define OW_VBIG (FB+304)
#define OW_T    (FB+760112)
#define OW_FEAT (FB+1374512)
#define OW_N1   (FB+1604912)
#define OW_N2   (FB+1892912)
#define OW_IRA  (FB+2180912)
#define OW_IRB  (FB+2188112)
#define OW_U1A  (FB+2195312)
#define OW_U2A  (FB+2310512)
#define OW_U1B  (FB+2425712)
#define OW_U2B  (FB+2540912)
#define OW_U3A  (FB+2656112)
#define OW_U3B  (FB+2771312)
#define OW_O    (FB+2886512)
#define OW_SE   (FB+3040112)   // [16]
#define OW_SVS  (FB+3040128)   // [256] per-(s,b,o) row sums (atomic)
#define OW_CSB  (FB+3040384)   // [12][600] raw adjacency column sums (atomic)

// ---------------- Eigen/MLIR fast tanh f32 (FMA build), bit-faithful ----------------
__device__ __forceinline__ float tanh_eigen(float x)
{
  const float CL = 7.99881172180175781f;
  float xc = fminf(fmaxf(x, -CL), CL);
  float x2 = __fmul_rn(xc, xc);
  float p = fmaf(x2, -2.76076847742355e-16f, 2.00018790482477e-13f);
  p = fmaf(x2, p, -8.60467152213735e-11f);
  p = fmaf(x2, p, 5.12229709037114e-08f);
  p = fmaf(x2, p, 1.48572235717979e-05f);
  p = fmaf(x2, p, 6.37261928875436e-04f);
  p = fmaf(x2, p, 4.89352455891786e-03f);
  p = __fmul_rn(xc, p);
  float q = fmaf(x2, 1.19825839466702e-06f, 1.18534705686654e-04f);
  q = fmaf(x2, q, 2.26843463243900e-03f);
  q = fmaf(x2, q, 4.89352518554385e-03f);
  float r = __fdiv_rn(p, q);
  return fabsf(x) < 0.0004f ? x : r;
}

// ---------------- fused: weff fold (block 48) + const_sv (blocks 0..47) ----------------
__global__ __launch_bounds__(256) void k_pre_wc(const float* Ws, const float* bs,
    const float* scW0, const float* scW1, const float* scW2, const float* scb,
    const float* svW0, const float* svW1, const float* svW2,
    const float* gb, const float* svb, double* wd, float* ws)
{
  if (blockIdx.x < 48) {
    int blk = blockIdx.x;
    int i = blk/16, o = blk%16;
    const float* svW = (i==0)?svW0:((i==1)?svW1:svW2);
    int L = (i==0)?162:((i==1)?79:39);
    int tid = threadIdx.x;
    __shared__ double red[256];
    double s = 0;
    for (int idx = tid; idx < 32*L; idx += 256) {
      int o2 = idx / L, l = idx - o2*L;
      s += (double)svW[(o*32+o2)*L + l] * ((double)gb[(i*2+0)*32+o2] + (double)gb[(i*2+1)*32+o2]);
    }
    red[tid] = s; __syncthreads();
    for (int st = 128; st; st >>= 1) { if (tid < st) red[tid] += red[tid+st]; __syncthreads(); }
    if (tid == 0) ws[OW_CSV + blk] = (float)(red[0] + (double)svb[i*16+o]);
    return;
  }
  __shared__ double w0[32][7], c0[32], w1[32][12], c1[32];
  int t = threadIdx.x;
  for (int e = t; e < 32*7; e += 256) {
    int c = e/7, p = e%7; double s = 0;
    for (int ci = 0; ci < 32; ci++) s += (double)scW0[(c*32+ci)*7+p] * (double)Ws[ci];
    w0[c][p] = s;
  }
  for (int e = t; e < 32; e += 256) {
    double s = 0;
    for (int ci = 0; ci < 32; ci++) { double a = 0; for (int p = 0; p < 7; p++) a += (double)scW0[(e*32+ci)*7+p]; s += a*(double)bs[ci]; }
    c0[e] = s + (double)scb[e];
  }
  __syncthreads();
  for (int e = t; e < 32*12; e += 256) {
    int c = e/12, m = e%12; double s = 0;
    for (int k1 = 0; k1 < 6; k1++) { int k0 = m - k1; if (k0 < 0 || k0 > 6) continue;
      for (int ci = 0; ci < 32; ci++) s += (double)scW1[(c*32+ci)*6+k1] * w0[ci][k0]; }
    w1[c][m] = s;
  }
  for (int e = t; e < 32; e += 256) {
    double s = 0;
    for (int ci = 0; ci < 32; ci++) { double a = 0; for (int k1 = 0; k1 < 6; k1++) a += (double)scW1[(e*32+ci)*6+k1]; s += a*c0[ci]; }
    c1[e] = s + (double)scb[32+e];
  }
  __syncthreads();
  for (int e = t; e < 32*16; e += 256) {
    int c = e/16, p = e%16; double s = 0;
    for (int k2 = 0; k2 < 3; k2++) { int m = p - 2*k2; if (m < 0 || m > 11) continue;
      for (int ci = 0; ci < 32; ci++) s += (double)scW2[(c*32+ci)*3+k2] * w1[ci][m]; }
    wd[DW_WEFF + (2*32+c)*16 + p] = s;
  }
  for (int e = t; e < 32; e += 256) {
    double s = 0;
    for (int ci = 0; ci < 32; ci++) { double a = 0; for (int k2 = 0; k2 < 3; k2++) a += (double)scW2[(e*32+ci)*3+k2]; s += a*c1[ci]; }
    wd[DW_CC + 64 + e] = s + (double)scb[64+e];
  }
  for (int e = t; e < 32*7;  e += 256) wd[DW_WEFF + (e/7)*16  + e%7 ] = w0[e/7][e%7];
  for (int e = t; e < 32*12; e += 256) wd[DW_WEFF + (32 + e/12)*16 + e%12] = w1[e/12][e%12];
  for (int e = t; e < 32; e += 256) { wd[DW_CC+e] = c0[e]; wd[DW_CC+32+e] = c1[e]; }
}

// ---------------- P[i][g][o2][p] + Q[i][g][o2]  (15 blocks, LDS-staged gW) ----------------
__global__ __launch_bounds__(256) void k_pre_p(const float* gW, double* wd)
{
  int blk = blockIdx.x;      // i*5+g
  int i = blk/5, g = blk%5;
  int tid = threadIdx.x;
  __shared__ float gls[2][3072];
  __shared__ double weffs[512];
  __shared__ double ccs[32];
  for (int e = tid; e < 6144; e += 256) gls[e/3072][e % 3072] = gW[i*6144 + e];
  for (int e = tid; e < 512; e += 256) weffs[e] = wd[DW_WEFF + i*512 + e];
  if (tid < 32) ccs[tid] = wd[DW_CC + i*32 + tid];
  __syncthreads();
  const float* g0 = gls[0];
  const float* g1 = gls[1];
  for (int e = tid; e < 512; e += 256) {
    int o2 = e >> 4, p = e & 15;
    double s = 0;
    for (int c = 0; c < 32; c++) {
      float w;
      if (g == 0) w = g0[c*32+o2] + g1[c*32+o2]
                    + 0.05f*(g0[(32+c)*32+o2] + g0[(64+c)*32+o2] + g1[(32+c)*32+o2] + g1[(64+c)*32+o2]);
      else if (g == 1) w = g0[(32+c)*32+o2];
      else if (g == 2) w = g0[(64+c)*32+o2];
      else if (g == 3) w = g1[(32+c)*32+o2];
      else             w = g1[(64+c)*32+o2];
      s += (double)w * weffs[c*16 + p];
    }
    wd[DW_P + ((i*5+g)*32 + o2)*16 + p] = s;
  }
  if (tid < 32) {
    int o2 = tid;
    double s = 0;
    for (int c = 0; c < 32; c++) {
      float w;
      if (g == 0) w = g0[c*32+o2] + g1[c*32+o2]
                    + 0.05f*(g0[(32+c)*32+o2] + g0[(64+c)*32+o2] + g1[(32+c)*32+o2] + g1[(64+c)*32+o2]);
      else if (g == 1) w = g0[(32+c)*32+o2];
      else if (g == 2) w = g0[(64+c)*32+o2];
      else if (g == 3) w = g1[(32+c)*32+o2];
      else             w = g1[(64+c)*32+o2];
      s += (double)w * ccs[c];
    }
    wd[DW_Q + (i*5+g)*32 + o2] = s;
  }
}

// ---------------- t-path/out0 fused weight columns (svW x P) + cbig (svW x Q) ----------------
__global__ __launch_bounds__(256) void k_pre_v(const float* svW0, const float* svW1, const float* svW2,
                                               const float* s0W, const float* s0b, double* wd, float* ws)
{
  int jj = blockIdx.x;             // 0..255
  int tid = threadIdx.x;
  if (jj >= 240) {
    int o = jj - 240;
    if (tid < 168) ws[OW_VBIG + jj*168 + tid] = s0W[o*168 + tid];
    if (tid == 0)  ws[OW_CBIG + jj] = s0b[o];
    return;
  }
  int i = jj/80, g = (jj%80)/16, o = jj%16;
  int st = (i==0)?1:((i==1)?2:4), tp = (i==0)?7:((i==1)?12:16), L = (i==0)?162:((i==1)?79:39);
  const float* svW = (i==0)?svW0:((i==1)?svW1:svW2);
  const float* svo = svW + o*32*L;
  __shared__ float svlds[32*162];
  __shared__ double Pl[32][16];
  __shared__ double Qs[32];
  __shared__ double red[256];
  int NL = 32*L;
  for (int e = tid; e < NL; e += 256) svlds[e] = svo[e];
  for (int e = tid; e < 512; e += 256) {
    int o2 = e >> 4, p = e & 15;
    Pl[o2][p] = wd[DW_P + ((i*5+g)*32 + o2)*16 + p];
  }
  if (tid < 32) Qs[tid] = wd[DW_Q + (i*5+g)*32 + tid];
  __syncthreads();
  double s = 0;
  for (int e = tid; e < NL; e += 256) s += (double)svlds[e] * Qs[e / L];
  red[tid] = s; __syncthreads();
  for (int stp = 128; stp; stp >>= 1) { if (tid < stp) red[tid] += red[tid+stp]; __syncthreads(); }
  if (tid == 0) ws[OW_CBIG + jj] = (float)red[0];
  if (tid < 168) {
    int u = tid;
    int lo_ = u - tp + 1;
    int lmin = lo_ > 0 ? (lo_ + st - 1)/st : 0;
    int lmax = u/st; if (lmax > L-1) lmax = L-1;
    double v = 0.0;
    for (int o2 = 0; o2 < 32; o2++) {
      const float* sv = svlds + o2*L;
      const double* Pp = Pl[o2];
      for (int l = lmin; l <= lmax; l++)
        v += (double)sv[l] * Pp[u - st*l];
    }
    ws[OW_VBIG + jj*168 + u] = (float)v;
  }
}

// ---------------- fused: feat (blocks 0..299) + t-path GEMM (300..449) ----------------
__global__ __launch_bounds__(256) void k_fg(const float* x, double* wd, float* ws)
{
  int t = threadIdx.x;
  if (blockIdx.x >= 300) {
    __shared__ float xs[16][168];
    int r0 = (blockIdx.x - 300)*16;
    for (int e = t; e < 16*168; e += 256) { int r = e/168, u = e%168; xs[r][u] = x[(r0+r)*168 + u]; }
    __syncthreads();
    int jj = t;
    const float* V = ws + OW_VBIG + jj*168;
    double a[16];
    #pragma unroll
    for (int r = 0; r < 16; r++) a[r] = 0;
    for (int u = 0; u < 168; u++) {
      float wv = V[u];
      #pragma unroll
      for (int r = 0; r < 16; r++) a[r] += (double)wv * (double)xs[r][u];
    }
    double cb = (double)ws[OW_CBIG + jj];
    for (int r = 0; r < 16; r++)
      ws[OW_T + (r0+r)*256 + jj] = (float)(a[r] + cb);
    return;
  }
  int blk = blockIdx.x;      // 4*75
  int b = blk / 75, n0 = (blk % 75) * 8;
  __shared__ float xsf[8][168];
  __shared__ double xbar[8][35];
  for (int e = t; e < 8*168; e += 256) xsf[e/168][e%168] = x[(b*600 + n0 + e/168)*168 + e%168];
  __syncthreads();
  for (int e = t; e < 8*35; e += 256) {
    int nn = e/35, slot = e%35;
    int i = slot < 7 ? 0 : (slot < 19 ? 1 : 2);
    int p = slot - (i==0?0:(i==1?7:19));
    int st = (i==0)?1:((i==1)?2:4), L = (i==0)?162:((i==1)?79:39);
    double s = 0;
    for (int l = 0; l < L; l++) s += (double)xsf[nn][st*l+p];
    xbar[nn][slot] = s / (double)L;
  }
  __syncthreads();
  int nn = t >> 5, c = t & 31;
  for (int i = 0; i < 3; i++) {
    int off = (i==0)?0:((i==1)?7:19), tp = (i==0)?7:((i==1)?12:16);
    double f = wd[DW_CC + i*32 + c];
    for (int p = 0; p < tp; p++) f += wd[DW_WEFF + (i*32+c)*16 + p] * xbar[nn][off+p];
    ws[OW_FEAT + ((i*4+b)*600 + n0+nn)*32 + c] = (float)f;
  }
}

// ---------------- n1/n2: LDS-staged weights, 16 nodes per block ----------------
__global__ __launch_bounds__(256) void k_nodes(const float* lin1W, const float* lin1b,
                                               const float* lin2W, const float* lin2b,
                                               const float* emb1, const float* emb2, float* ws)
{
  int blk = blockIdx.x;  // i*152 + b*38 + nt
  int nt = blk % 38, b = (blk/38) % 4, i = blk/152;
  int n0 = nt*16;
  __shared__ float W1[1280], W2[1280], b1[40], b2[40], sf[16][33];
  int t = threadIdx.x;
  for (int e = t; e < 1280; e += 256) { W1[e] = lin1W[i*1280 + e]; W2[e] = lin2W[i*1280 + e]; }
  if (t < 40) { b1[t] = lin1b[i*40 + t]; b2[t] = lin2b[i*40 + t]; }
  for (int e = t; e < 16*32; e += 256) {
    int nn = e >> 5, c = e & 31; int n = n0 + nn;
    sf[nn][c] = (n < 600) ? ws[OW_FEAT + ((i*4+b)*600 + n)*32 + c] : 0.f;
  }
  __syncthreads();
  const float TSF[3] = {3.0f, 2.4f, 1.8f};
  for (int item = t; item < 16*80; item += 256) {
    int nn = item / 80, rr = item % 80;
    int n = n0 + nn; if (n >= 600) continue;
    int which = rr/40, d = rr%40;
    const float* W  = which ? W2 : W1;
    const float* bv = which ? b2 : b1;
    const float* em = which ? emb2 : emb1;
    float pre = 0.f;
    #pragma unroll
    for (int c = 0; c < 32; c++) pre = fmaf(sf[nn][c], W[c*40+d], pre);
    float p2 = __fadd_rn(pre, bv[d]);
    float p3 = __fadd_rn(p2, em[n*40+d]);
    float arg = __fmul_rn(TSF[i], p3);
    ws[(which ? OW_N2 : OW_N1) + ((i*4+b)*600 + n)*40 + d] = tanh_eigen(arg);
  }
}

// ---------------- adjacency staging helper ----------------
__device__ __forceinline__ float4 adj_ld(const float* n1, const float* n2, int e, int w0)
{
  int mat = e >= 320; int idx = e - 320*mat;
  int jj = idx/10, q = idx - 10*jj;
  int w = w0 + jj;
  if (w < 600) return *(const float4*)((mat ? n2 : n1) + w*40 + 4*q);
  float4 z; z.x = z.y = z.z = z.w = 0.f; return z;
}

// ---------------- adjacency: 16 rows/block, 16-way broadcast, colsum epilogue ----------------
__global__ __launch_bounds__(256) void k_adj(float* adj_out, float* ws)
{
  int blk = blockIdx.x;                 // ib*38 + tile  (12*38 = 456)
  int tile = blk % 38, ib = blk / 38;   // ib = i*4+b
  int row0 = tile*16;
  const float* n1 = ws + OW_N1 + ib*24000;
  const float* n2 = ws + OW_N2 + ib*24000;
  __shared__ float c1s[32][44], c2s[32][44];
  __shared__ float svals[16][604];      // 604%32==28: conflict-free
  int t = threadIdx.x;
  int rc = t & 15, jc = t >> 4;         // 16 lanes share each column address
  int myrow = row0 + rc;
  bool rvalid = myrow < 600;
  float am1[40], am2[40];
  {
    int rl = rvalid ? myrow : 599;
    const float4* m1p = (const float4*)(n1 + rl*40);
    const float4* m2p = (const float4*)(n2 + rl*40);
    #pragma unroll
    for (int q = 0; q < 10; q++) {
      float4 v1 = m1p[q], v2 = m2p[q];
      am1[4*q]=v1.x; am1[4*q+1]=v1.y; am1[4*q+2]=v1.z; am1[4*q+3]=v1.w;
      am2[4*q]=v2.x; am2[4*q+1]=v2.y; am2[4*q+2]=v2.z; am2[4*q+3]=v2.w;
    }
  }
  float4 s0 = adj_ld(n1, n2, t, 0);
  float4 s1 = adj_ld(n1, n2, t + 256, 0);
  float4 s2; if (t < 128) s2 = adj_ld(n1, n2, t + 512, 0);
  for (int k = 0; k < 19; k++) {
    int w0 = 32*k;
    __syncthreads();
    {
      int e = t;       { int mat=e>=320, idx=e-320*mat, jj=idx/10, q=idx-10*jj, w=w0+jj;
                         if (w<600) *(float4*)(&(mat?c2s:c1s)[jj][4*q]) = s0; }
      e = t + 256;     { int mat=e>=320, idx=e-320*mat, jj=idx/10, q=idx-10*jj, w=w0+jj;
                         if (w<600) *(float4*)(&(mat?c2s:c1s)[jj][4*q]) = s1; }
      if (t < 128) { e = t + 512; int mat=e>=320, idx=e-320*mat, jj=idx/10, q=idx-10*jj, w=w0+jj;
                         if (w<600) *(float4*)(&(mat?c2s:c1s)[jj][4*q]) = s2; }
    }
    __syncthreads();
    if (k < 18) {
      int w0n = w0 + 32;
      s0 = adj_ld(n1, n2, t, w0n);
      s1 = adj_ld(n1, n2, t + 256, w0n);
      if (t < 128) s2 = adj_ld(n1, n2, t + 512, w0n);
    }
    #pragma unroll
    for (int cc = 0; cc < 2; cc++) {
      int col = jc + 16*cc;
      int w = w0 + col;
      if (rvalid && w < 600) {
        const float4* c2p = (const float4*)c2s[col];
        const float4* c1p = (const float4*)c1s[col];
        float d1 = 0.f, d2 = 0.f;
        #pragma unroll
        for (int q = 0; q < 10; q++) {          // ascending d, single accumulator: bit-exact
          float4 v = c2p[q];
          d1 = fmaf(am1[4*q], v.x, d1); d1 = fmaf(am1[4*q+1], v.y, d1);
          d1 = fmaf(am1[4*q+2], v.z, d1); d1 = fmaf(am1[4*q+3], v.w, d1);
        }
        #pragma unroll
        for (int q = 0; q < 10; q++) {
          float4 v = c1p[q];
          d2 = fmaf(am2[4*q], v.x, d2); d2 = fmaf(am2[4*q+1], v.y, d2);
          d2 = fmaf(am2[4*q+2], v.z, d2); d2 = fmaf(am2[4*q+3], v.w, d2);
        }
        float af = __fsub_rn(d1, d2);
        float tv = __fmul_rn(3.0f, af);
        float v = tanh_eigen(tv);
        svals[rc][w] = v > 0.f ? v : 0.f;       // relu
      }
    }
  }
  __syncthreads();
  // ---- top-k: proven per-row logic, two passes of 8 rows ----
  const float VP = tanh_eigen(8.0f);
  unsigned int vpb = __float_as_uint(VP);
  int j = t & 31;
  for (int p = 0; p < 2; p++) {
    int r = p*8 + (t >> 5);
    int row = row0 + r;
    if (row < 600) {
      float vv[19];
      #pragma unroll
      for (int k = 0; k < 19; k++) {
        int w = j + 32*k;
        vv[k] = (w < 600) ? svals[r][w] : 0.f;
      }
      float rm = 0.f;
      #pragma unroll
      for (int k = 0; k < 19; k++) rm = fmaxf(rm, vv[k]);
      #pragma unroll
      for (int s = 16; s; s >>= 1) rm = fmaxf(rm, __shfl_xor(rm, s, 32));
      int cntp = 0;
      #pragma unroll
      for (int k = 0; k < 19; k++) { int w = j + 32*k; if (w < 600 && __float_as_uint(vv[k]) >= vpb) cntp++; }
      #pragma unroll
      for (int s = 16; s; s >>= 1) cntp += __shfl_xor(cntp, s, 32);
      unsigned int lo, hi;
      unsigned int mb1 = __float_as_uint(rm) + 1u;
      if (cntp >= 20) { lo = vpb; hi = mb1; }
      else            { lo = 0u;  hi = vpb < mb1 ? vpb : mb1; }
      while (hi - lo > 1u) {
        unsigned int mid = lo + ((hi - lo) >> 1);
        int cnt = 0;
        #pragma unroll
        for (int k = 0; k < 19; k++) {
          int w = j + 32*k;
          if (w < 600 && __float_as_uint(vv[k]) >= mid) cnt++;
        }
        #pragma unroll
        for (int s = 16; s; s >>= 1) cnt += __shfl_xor(cnt, s, 32);
        if (cnt >= 20) lo = mid; else hi = mid;
      }
      unsigned int kb = lo;
      float* arow = adj_out + ib*360000 + row*600;
      float rsum = 0.f;
      #pragma unroll
      for (int k = 0; k < 19; k++) {
        int w = j + 32*k;
        if (w < 600) {
          float v = (__float_as_uint(vv[k]) >= kb) ? vv[k] : 0.f;
          arow[w] = v;
          svals[r][w] = v;              // masked write-back for column sums
          rsum += v;
        }
      }
      #pragma unroll
      for (int s = 16; s; s >>= 1) rsum += __shfl_xor(rsum, s, 32);
      if (j == 0) ws[OW_IRA + ib*600 + row] = 1.f/(1.f + rsum);
    }
  }
  __syncthreads();
  // ---- column-sum epilogue: valid-row partials -> atomic raw sums ----
  {
    int nv = 600 - row0; if (nv > 16) nv = 16;
    float* csb = ws + OW_CSB + ib*600;
    for (int w = t; w < 600; w += 256) {
      float cs = 0.f;
      for (int rr2 = 0; rr2 < nv; rr2++) cs += svals[rr2][w];
      atomicAdd(&csb[w], cs);
    }
  }
}

// ---------------- inv row sums for transposed direction: 1/(1+csum) ----------------
__global__ void k_invrb(float* ws)
{
  int e = blockIdx.x*256 + threadIdx.x;
  if (e < 7200) ws[OW_IRB + e] = 1.f/(1.f + ws[OW_CSB + e]);
}

// ---------------- prop1: 4w x 4oz per thread, per-wave K-split, b128 LDS ----------------
__global__ __launch_bounds__(256) void k_prop1(const float* adj, float* ws)
{
  int blk = blockIdx.x;            // ib*38 + d*19 + wt
  int wt = blk % 19;
  int d  = (blk / 19) & 1;
  int ib = blk / 38;
  int i = ib >> 2, b = ib & 3;
  int w0 = wt * 32;
  const float* A   = adj + ib*360000;
  const float* irx = ws + (d ? OW_IRB : OW_IRA) + ib*600;
  const float* Tb  = ws + OW_T + (b*600)*256 + i*80 + 16 + d*32;
  __shared__ float As[4][32][36];
  __shared__ float Zs[4][32][36];
  __shared__ float red[3][64][17];
  int tid = threadIdx.x;
  int wv = tid >> 6, ln = tid & 63;
  int wq = ln >> 3, oq = ln & 7;
  float acc[4][4];
  #pragma unroll
  for (int a1 = 0; a1 < 4; a1++)
    #pragma unroll
    for (int a2 = 0; a2 < 4; a2++) acc[a1][a2] = 0.f;
  int vbeg = wv*160, vend = vbeg + 160 < 600 ? vbeg + 160 : 600;
  for (int v0 = vbeg; v0 < vend; v0 += 32) {
    if (d == 0) {
      #pragma unroll
      for (int q = 0; q < 4; q++) {
        int m = q*64 + ln, rr = m >> 3, c4 = (m & 7)*4;
        int v = v0 + rr;
        float4 av; av.x = av.y = av.z = av.w = 0.f;
        if (v < 600) {
          int wb = w0 + c4;
          if (wb + 3 < 600) av = *(const float4*)(A + v*600 + wb);
          else {
            if (wb+0 < 600) av.x = A[v*600 + wb+0];
            if (wb+1 < 600) av.y = A[v*600 + wb+1];
            if (wb+2 < 600) av.z = A[v*600 + wb+2];
            if (wb+3 < 600) av.w = A[v*600 + wb+3];
          }
        }
        *(float4*)(&As[wv][rr][c4]) = av;
      }
    } else {
      #pragma unroll
      for (int q = 0; q < 4; q++) {
        int m = q*64 + ln, rr = m >> 3, c4 = (m & 7)*4;
        int w = w0 + rr;
        float4 av; av.x = av.y = av.z = av.w = 0.f;
        if (w < 600) {
          if (v0 + c4 + 3 < 600) av = *(const float4*)(A + w*600 + v0 + c4);
          else {
            if (v0+c4+0 < 600) av.x = A[w*600 + v0+c4+0];
            if (v0+c4+1 < 600) av.y = A[w*600 + v0+c4+1];
            if (v0+c4+2 < 600) av.z = A[w*600 + v0+c4+2];
            if (v0+c4+3 < 600) av.w = A[w*600 + v0+c4+3];
          }
        }
        As[wv][c4+0][rr] = av.x; As[wv][c4+1][rr] = av.y;
        As[wv][c4+2][rr] = av.z; As[wv][c4+3][rr] = av.w;
      }
    }
    #pragma unroll
    for (int q = 0; q < 4; q++) {
      int m = q*64 + ln, rr = m >> 3, c4 = (m & 7)*4;
      int v = v0 + rr;
      float4 zv; zv.x = zv.y = zv.z = zv.w = 0.f;
      if (v < 600) {
        float ir = irx[v];
        float4 tv = *(const float4*)(Tb + v*256 + c4);
        zv.x = ir*tv.x; zv.y = ir*tv.y; zv.z = ir*tv.z; zv.w = ir*tv.w;
      }
      *(float4*)(&Zs[wv][rr][c4]) = zv;
    }
    __builtin_amdgcn_s_waitcnt(0);
    for (int vl = 0; vl < 32; vl++) {
      float4 a4 = *(const float4*)(&As[wv][vl][wq*4]);
      float4 z4 = *(const float4*)(&Zs[wv][vl][oq*4]);
      acc[0][0] = fmaf(a4.x, z4.x, acc[0][0]); acc[0][1] = fmaf(a4.x, z4.y, acc[0][1]);
      acc[0][2] = fmaf(a4.x, z4.z, acc[0][2]); acc[0][3] = fmaf(a4.x, z4.w, acc[0][3]);
      acc[1][0] = fmaf(a4.y, z4.x, acc[1][0]); acc[1][1] = fmaf(a4.y, z4.y, acc[1][1]);
      acc[1][2] = fmaf(a4.y, z4.z, acc[1][2]); acc[1][3] = fmaf(a4.y, z4.w, acc[1][3]);
      acc[2][0] = fmaf(a4.z, z4.x, acc[2][0]); acc[2][1] = fmaf(a4.z, z4.y, acc[2][1]);
      acc[2][2] = fmaf(a4.z, z4.z, acc[2][2]); acc[2][3] = fmaf(a4.z, z4.w, acc[2][3]);
      acc[3][0] = fmaf(a4.w, z4.x, acc[3][0]); acc[3][1] = fmaf(a4.w, z4.y, acc[3][1]);
      acc[3][2] = fmaf(a4.w, z4.z, acc[3][2]); acc[3][3] = fmaf(a4.w, z4.w, acc[3][3]);
    }
  }
  if (wv > 0) {
    #pragma unroll
    for (int kw = 0; kw < 4; kw++)
      #pragma unroll
      for (int ko = 0; ko < 4; ko++) red[wv-1][ln][kw*4+ko] = acc[kw][ko];
  }
  __syncthreads();
  if (wv == 0) {
    #pragma unroll
    for (int kw = 0; kw < 4; kw++) {
      int w = w0 + wq*4 + kw;
      if (w >= 600) continue;
      float irw = irx[w];
      #pragma unroll
      for (int ko = 0; ko < 4; ko++) {
        int oz = oq*4 + ko;
        float sum = acc[kw][ko] + red[0][ln][kw*4+ko] + red[1][ln][kw*4+ko] + red[2][ln][kw*4+ko];
        sum += irw * Tb[w*256 + oz];
        float* dst = ws + (d==0 ? (oz < 16 ? OW_U1A : OW_U2A) : (oz < 16 ? OW_U1B : OW_U2B));
        dst[(ib*600 + w)*16 + (oz & 15)] = sum;
      }
    }
  }
}

// ---------------- prop2: 4w x 2oz per thread, per-wave K-split ----------------
__global__ __launch_bounds__(256) void k_prop2(const float* adj, float* ws)
{
  int blk = blockIdx.x;            // ib*38 + d*19 + wt
  int wt = blk % 19;
  int d  = (blk / 19) & 1;
  int ib = blk / 38;
  int w0 = wt * 32;
  const float* A   = adj + ib*360000;
  const float* irx = ws + (d ? OW_IRB : OW_IRA) + ib*600;
  const float* u2x = ws + (d ? OW_U2B : OW_U2A) + ib*9600;
  __shared__ float As[4][32][36];
  __shared__ float Zs[4][32][20];
  __shared__ float red[3][64][9];
  int tid = threadIdx.x;
  int wv = tid >> 6, ln = tid & 63;
  int wq = ln >> 3, oq = ln & 7;
  float acc[4][2];
  #pragma unroll
  for (int a1 = 0; a1 < 4; a1++) { acc[a1][0] = 0.f; acc[a1][1] = 0.f; }
  int vbeg = wv*160, vend = vbeg + 160 < 600 ? vbeg + 160 : 600;
  for (int v0 = vbeg; v0 < vend; v0 += 32) {
    if (d == 0) {
      #pragma unroll
      for (int q = 0; q < 4; q++) {
        int m = q*64 + ln, rr = m >> 3, c4 = (m & 7)*4;
        int v = v0 + rr;
        float4 av; av.x = av.y = av.z = av.w = 0.f;
        if (v < 600) {
          int wb = w0 + c4;
          if (wb + 3 < 600) av = *(const float4*)(A + v*600 + wb);
          else {
            if (wb+0 < 600) av.x = A[v*600 + wb+0];
            if (wb+1 < 600) av.y = A[v*600 + wb+1];
            if (wb+2 < 600) av.z = A[v*600 + wb+2];
            if (wb+3 < 600) av.w = A[v*600 + wb+3];
          }
        }
        *(float4*)(&As[wv][rr][c4]) = av;
      }
    } else {
      #pragma unroll
      for (int q = 0; q < 4; q++) {
        int m = q*64 + ln, rr = m >> 3, c4 = (m & 7)*4;
        int w = w0 + rr;
        float4 av; av.x = av.y = av.z = av.w = 0.f;
        if (w < 600) {
          if (v0 + c4 + 3 < 600) av = *(const float4*)(A + w*600 + v0 + c4);
          else {
            if (v0+c4+0 < 600) av.x = A[w*600 + v0+c4+0];
            if (v0+c4+1 < 600) av.y = A[w*600 + v0+c4+1];
            if (v0+c4+2 < 600) av.z = A[w*600 + v0+c4+2];
            if (v0+c4+3 < 600) av.w = A[w*600 + v0+c4+3];
          }
        }
        As[wv][c4+0][rr] = av.x; As[wv][c4+1][rr] = av.y;
        As[wv][c4+2][rr] = av.z; As[wv][c4+3][rr] = av.w;
      }
    }
    #pragma unroll
    for (int q = 0; q < 2; q++) {
      int m = q*64 + ln, rr = m >> 2, c4 = (m & 3)*4;
      int v = v0 + rr;
      float4 zv; zv.x = zv.y = zv.z = zv.w = 0.f;
      if (v < 600) {
        float ir = irx[v];
        float4 uv = *(const float4*)(u2x + v*16 + c4);
        zv.x = ir*uv.x; zv.y = ir*uv.y; zv.z = ir*uv.z; zv.w = ir*uv.w;
      }
      *(float4*)(&Zs[wv][rr][c4]) = zv;
    }
    __builtin_amdgcn_s_waitcnt(0);
    for (int vl = 0; vl < 32; vl++) {
      float4 a4 = *(const float4*)(&As[wv][vl][wq*4]);
      float2 z2 = *(const float2*)(&Zs[wv][vl][oq*2]);
      acc[0][0] = fmaf(a4.x, z2.x, acc[0][0]); acc[0][1] = fmaf(a4.x, z2.y, acc[0][1]);
      acc[1][0] = fmaf(a4.y, z2.x, acc[1][0]); acc[1][1] = fmaf(a4.y, z2.y, acc[1][1]);
      acc[2][0] = fmaf(a4.z, z2.x, acc[2][0]); acc[2][1] = fmaf(a4.z, z2.y, acc[2][1]);
      acc[3][0] = fmaf(a4.w, z2.x, acc[3][0]); acc[3][1] = fmaf(a4.w, z2.y, acc[3][1]);
    }
  }
  if (wv > 0) {
    #pragma unroll
    for (int kw = 0; kw < 4; kw++) {
      red[wv-1][ln][kw*2+0] = acc[kw][0];
      red[wv-1][ln][kw*2+1] = acc[kw][1];
    }
  }
  __syncthreads();
  if (wv == 0) {
    float* dst = ws + (d==0 ? OW_U3A : OW_U3B);
    #pragma unroll
    for (int kw = 0; kw < 4; kw++) {
      int w = w0 + wq*4 + kw;
      if (w >= 600) continue;
      float irw = irx[w];
      #pragma unroll
      for (int ko = 0; ko < 2; ko++) {
        int oz = oq*2 + ko;
        float sum = acc[kw][ko] + red[0][ln][kw*2+ko] + red[1][ln][kw*2+ko] + red[2][ln][kw*2+ko];
        sum += irw * u2x[w*16 + oz];
        dst[(ib*600 + w)*16 + oz] = sum;
      }
    }
  }
}

// ---------------- assemble head outputs + fused SE row sums ----------------
__global__ __launch_bounds__(256) void k_outs(float* ws)
{
  __shared__ float sums[2];
  int tid = threadIdx.x;
  int e = blockIdx.x*256 + tid;
  int rA = (blockIdx.x*256)/600;
  if (tid < 2) sums[tid] = 0.f;
  __syncthreads();
  float val = 0.f;
  int row = rA;
  if (e < 153600) {
    int n = e % 600, o = (e/600) % 16, b = (e/9600) % 4, s = e/38400;
    if (s == 0) {
      val = ws[OW_T + (b*600+n)*256 + 240 + o];
    } else {
      int i = s - 1;
      int idx = ((i*4+b)*600 + n)*16 + o;
      float t0 = ws[OW_T + (b*600+n)*256 + i*80 + o];
      val = t0 + 0.95f  * (ws[OW_U1A+idx] + ws[OW_U1B+idx])
               + 0.0475f* (ws[OW_U2A+idx] + ws[OW_U2B+idx])
               + 0.9025f* (ws[OW_U3A+idx] + ws[OW_U3B+idx])
               + ws[OW_CSV + i*16 + o];
    }
    ws[OW_O + ((s*4+b)*16 + o)*600 + n] = val;
    row = e/600;
  }
  float vA = (e < 153600 && row == rA) ? val : 0.f;
  float vB = (e < 153600 && row == rA+1) ? val : 0.f;
  #pragma unroll
  for (int s = 32; s; s >>= 1) { vA += __shfl_down(vA, s, 64); vB += __shfl_down(vB, s, 64); }
  if ((tid & 63) == 0) {
    if (vA != 0.f) atomicAdd(&sums[0], vA);
    if (vB != 0.f) atomicAdd(&sums[1], vB);
  }
  __syncthreads();
  if (tid < 2) {
    int r = rA + tid;
    if (r < 256) atomicAdd(&ws[OW_SVS + r], sums[tid]);
  }
}

// ---------------- SE gate (reads fused sums) ----------------
__global__ void k_se(const float* gfW1, const float* gfW2, float* ws)
{
  __shared__ float sv[4][64], hb[4][4];
  int t = threadIdx.x;
  {
    int row = t;
    int o = row & 15, b = (row >> 4) & 3, s = row >> 6;
    sv[b][s*16 + o] = ws[OW_SVS + row] * (1.f/600.f);
  }
  __syncthreads();
  if (t < 16) {
    int bb = t >> 2, j = t & 3;
    float h = 0.f;
    for (int kk = 0; kk < 64; kk++) h += sv[bb][kk]*gfW1[kk*4+j];
    hb[bb][j] = h > 0.f ? h : 0.f;
  }
  __syncthreads();
  if (t < 16) {
    int bb = t >> 2, ii = t & 3;
    float g = 0.f;
    for (int j = 0; j < 4; j++) g += hb[bb][j]*gfW2[j*4+ii];
    ws[OW_SE + bb*4 + ii] = 1.f/(1.f + expf(-g));
  }
}

// ---------------- gate + end MLP (parallel final stage) ----------------
__global__ __launch_bounds__(128) void k_head(const float* e1W, const float* e1b,
                                              const float* e2W, const float* e2b,
                                              float* ws, float* dout)
{
  int blk = blockIdx.x, b = blk/600, n = blk%600;
  __shared__ float y0[16], y1[128];
  int t = threadIdx.x;
  if (t < 16) {
    float f = 0.f;
    for (int s = 0; s < 4; s++) f += ws[OW_SE + b*4 + s] * ws[OW_O + ((s*4+b)*16 + t)*600 + n];
    f *= 0.25f;
    y0[t] = f > 0.f ? f : 0.f;
  }
  __syncthreads();
  {
    float h = e1b[t];
    for (int o = 0; o < 16; o++) h += e1W[t*16+o]*y0[o];
    y1[t] = h > 0.f ? h : 0.f;
  }
  __syncthreads();
  if (t < 96) {
    int o = t >> 3, part = t & 7;   // 12 outputs x 8 partials
    float v = 0.f;
    #pragma unroll
    for (int e = 0; e < 16; e++) v = fmaf(e2W[o*128 + part*16 + e], y1[part*16 + e], v);
    #pragma unroll
    for (int s = 4; s; s >>= 1) v += __shfl_down(v, s, 8);
    if (part == 0) dout[b*7200 + o*600 + n] = e2b[o] + v;
  }
}

extern "C" void kernel_launch(void* const* d_in, const int* in_sizes, int n_in,
                              void* d_out, int out_size, void* d_ws, size_t ws_size,
                              hipStream_t stream)
{
  const float* x    = (const float*)d_in[0];
  const float* Ws   = (const float*)d_in[1];
  const float* bs   = (const float*)d_in[2];
  const float* scW0 = (const float*)d_in[3];
  const float* scW1 = (const float*)d_in[4];
  const float* scW2 = (const float*)d_in[5];
  const float* scb  = (const float*)d_in[6];
  const float* emb1 = (const float*)d_in[7];
  const float* emb2 = (const float*)d_in[8];
  const float* lin1W= (const float*)d_in[9];
  const float* lin1b= (const float*)d_in[10];
  const float* lin2W= (const float*)d_in[11];
  const float* lin2b= (const float*)d_in[12];
  const float* gW   = (const float*)d_in[13];
  const float* gb   = (const float*)d_in[14];
  const float* svW0 = (const float*)d_in[15];
  const float* svW1 = (const float*)d_in[16];
  const float* svW2 = (const float*)d_in[17];
  const float* svb  = (const float*)d_in[18];
  const float* s0W  = (const float*)d_in[19];
  const float* s0b  = (const float*)d_in[20];
  const float* gfW1 = (const float*)d_in[21];
  const float* gfW2 = (const float*)d_in[22];
  const float* e1W  = (const float*)d_in[23];
  const float* e1b  = (const float*)d_in[24];
  const float* e2W  = (const float*)d_in[25];
  const float* e2b  = (const float*)d_in[26];
  float* out = (float*)d_out;
  float* ws  = (float*)d_ws;
  double* wd = (double*)d_ws;
  float* adj_out = out + 28800;

  k_pre_wc<<<49, 256, 0, stream>>>(Ws, bs, scW0, scW1, scW2, scb,
                                   svW0, svW1, svW2, gb, svb, wd, ws);
  k_pre_p<<<15, 256, 0, stream>>>(gW, wd);
  k_pre_v<<<256, 256, 0, stream>>>(svW0, svW1, svW2, s0W, s0b, wd, ws);
  hipMemsetAsync((void*)(ws + OW_SVS), 0, (256 + 7200)*sizeof(float), stream);
  k_fg<<<450, 256, 0, stream>>>(x, wd, ws);
  k_nodes<<<456, 256, 0, stream>>>(lin1W, lin1b, lin2W, lin2b, emb1, emb2, ws);
  k_adj<<<456, 256, 0, stream>>>(adj_out, ws);
  k_invrb<<<29, 256, 0, stream>>>(ws);
  k_prop1<<<456, 256, 0, stream>>>(adj_out, ws);
  k_prop2<<<456, 256, 0, stream>>>(adj_out, ws);
  k_outs<<<600, 256, 0, stream>>>(ws);
  k_se<<<1, 256, 0, stream>>>(gfW1, gfW2, ws);
  k_head<<<2400, 128, 0, stream>>>(e1W, e1b, e2W, e2b, ws, out);
}

// Round 23
// 214.810 us; speedup vs baseline: 1.5949x; 1.0611x over previous
//
#include <hip/hip_runtime.h>
#include <math.h>

// ---------------- problem constants ----------------
// B=4, N=600, S=168, D=40, Cc=32, Cs=16, Ce=128, Od=12
// Adjacency path: bit-exact Eigen/MLIR fast-tanh (clamp 7.99881172180175781f,
// FMA Horner, |x|<0.0004 passthrough) + Eigen seq-FMA dots. PROVEN R7-R22.
// R23: k_pre_wc fold block LDS-staged (scW panels coalesced into LDS; serial
// global-load chains removed); bias reductions parallelized BIT-EXACTLY
// (same a-then-s grouping). All fold outputs bit-identical to R22.

// ---------------- workspace layout ----------------
#define DW_WEFF 0          // [3][32][16] doubles
#define DW_CC   1536       // [3][32]
#define DW_P    1632       // [3][5][32][16] doubles = 7680
#define DW_Q    9312       // [3][5][32] doubles = 480
#define FB      19584      // float offset = 2*9792
#define OW_CSV  (FB+0)
#define OW_CBIG (FB+48)
#define OW_VBIG (FB+304)
#define OW_T    (FB+760112)
#define OW_FEAT (FB+1374512)
#define OW_N1   (FB+1604912)
#define OW_N2   (FB+1892912)
#define OW_IRA  (FB+2180912)
#define OW_IRB  (FB+2188112)
#define OW_U1A  (FB+2195312)
#define OW_U2A  (FB+2310512)
#define OW_U1B  (FB+2425712)
#define OW_U2B  (FB+2540912)
#define OW_U3A  (FB+2656112)
#define OW_U3B  (FB+2771312)
#define OW_O    (FB+2886512)
#define OW_SE   (FB+3040112)   // [16]
#define OW_SVS  (FB+3040128)   // [256] per-(s,b,o) row sums (atomic)
#define OW_CSB  (FB+3040384)   // [12][600] raw adjacency column sums (atomic)

// ---------------- Eigen/MLIR fast tanh f32 (FMA build), bit-faithful ----------------
__device__ __forceinline__ float tanh_eigen(float x)
{
  const float CL = 7.99881172180175781f;
  float xc = fminf(fmaxf(x, -CL), CL);
  float x2 = __fmul_rn(xc, xc);
  float p = fmaf(x2, -2.76076847742355e-16f, 2.00018790482477e-13f);
  p = fmaf(x2, p, -8.60467152213735e-11f);
  p = fmaf(x2, p, 5.12229709037114e-08f);
  p = fmaf(x2, p, 1.48572235717979e-05f);
  p = fmaf(x2, p, 6.37261928875436e-04f);
  p = fmaf(x2, p, 4.89352455891786e-03f);
  p = __fmul_rn(xc, p);
  float q = fmaf(x2, 1.19825839466702e-06f, 1.18534705686654e-04f);
  q = fmaf(x2, q, 2.26843463243900e-03f);
  q = fmaf(x2, q, 4.89352518554385e-03f);
  float r = __fdiv_rn(p, q);
  return fabsf(x) < 0.0004f ? x : r;
}

// ---------------- fused: weff fold (block 48, LDS-staged) + const_sv (blocks 0..47) ----------------
__global__ __launch_bounds__(256) void k_pre_wc(const float* Ws, const float* bs,
    const float* scW0, const float* scW1, const float* scW2, const float* scb,
    const float* svW0, const float* svW1, const float* svW2,
    const float* gb, const float* svb, double* wd, float* ws)
{
  if (blockIdx.x < 48) {
    int blk = blockIdx.x;
    int i = blk/16, o = blk%16;
    const float* svW = (i==0)?svW0:((i==1)?svW1:svW2);
    int L = (i==0)?162:((i==1)?79:39);
    int tid = threadIdx.x;
    __shared__ double red[256];
    double s = 0;
    for (int idx = tid; idx < 32*L; idx += 256) {
      int o2 = idx / L, l = idx - o2*L;
      s += (double)svW[(o*32+o2)*L + l] * ((double)gb[(i*2+0)*32+o2] + (double)gb[(i*2+1)*32+o2]);
    }
    red[tid] = s; __syncthreads();
    for (int st = 128; st; st >>= 1) { if (tid < st) red[tid] += red[tid+st]; __syncthreads(); }
    if (tid == 0) ws[OW_CSV + blk] = (float)(red[0] + (double)svb[i*16+o]);
    return;
  }
  // ---- fold block: LDS-staged ----
  __shared__ float scs[7168];
  __shared__ float wsb[32], bsb[32], scbb[96];
  __shared__ double w0[32][7], c0[32], w1[32][12], c1[32];
  __shared__ double pa[32][32];
  int t = threadIdx.x;
  // stage scW0 (7168) + consts
  for (int e = t; e < 7168; e += 256) scs[e] = scW0[e];
  if (t < 32) { wsb[t] = Ws[t]; bsb[t] = bs[t]; }
  if (t >= 32 && t < 128) scbb[t-32] = scb[t-32];
  __syncthreads();
  // w0[c][p] (identical order)
  for (int e = t; e < 224; e += 256) {
    int c = e/7, p = e%7; double s = 0;
    for (int ci = 0; ci < 32; ci++) s += (double)scs[(c*32+ci)*7+p] * (double)wsb[ci];
    w0[c][p] = s;
  }
  // pa[e][ci] = sum_p scW0 (identical to original inner 'a')
  for (int e = t; e < 1024; e += 256) {
    int ee = e >> 5, ci = e & 31;
    double a = 0;
    for (int p = 0; p < 7; p++) a += (double)scs[(ee*32+ci)*7+p];
    pa[ee][ci] = a;
  }
  __syncthreads();
  // c0 (identical outer order) ; concurrently stage scW1 (6144)
  if (t < 32) {
    double s = 0;
    for (int ci = 0; ci < 32; ci++) s += pa[t][ci] * (double)bsb[ci];
    c0[t] = s + (double)scbb[t];
  }
  __syncthreads();
  for (int e = t; e < 6144; e += 256) scs[e] = scW1[e];
  __syncthreads();
  // w1[c][m] (identical order)
  for (int e = t; e < 384; e += 256) {
    int c = e/12, m = e%12; double s = 0;
    for (int k1 = 0; k1 < 6; k1++) { int k0 = m - k1; if (k0 < 0 || k0 > 6) continue;
      for (int ci = 0; ci < 32; ci++) s += (double)scs[(c*32+ci)*6+k1] * w0[ci][k0]; }
    w1[c][m] = s;
  }
  for (int e = t; e < 1024; e += 256) {
    int ee = e >> 5, ci = e & 31;
    double a = 0;
    for (int k1 = 0; k1 < 6; k1++) a += (double)scs[(ee*32+ci)*6+k1];
    pa[ee][ci] = a;
  }
  __syncthreads();
  if (t < 32) {
    double s = 0;
    for (int ci = 0; ci < 32; ci++) s += pa[t][ci] * c1[ci];   // placeholder avoided below
  }
  // NOTE: compute c1 correctly (uses c0)
  if (t < 32) {
    double s = 0;
    for (int ci = 0; ci < 32; ci++) s += pa[t][ci] * c0[ci];
    c1[t] = s + (double)scbb[32+t];
  }
  __syncthreads();
  for (int e = t; e < 3072; e += 256) scs[e] = scW2[e];
  __syncthreads();
  // weff2 (identical order)
  for (int e = t; e < 512; e += 256) {
    int c = e/16, p = e%16; double s = 0;
    for (int k2 = 0; k2 < 3; k2++) { int m = p - 2*k2; if (m < 0 || m > 11) continue;
      for (int ci = 0; ci < 32; ci++) s += (double)scs[(c*32+ci)*3+k2] * w1[ci][m]; }
    wd[DW_WEFF + (2*32+c)*16 + p] = s;
  }
  for (int e = t; e < 1024; e += 256) {
    int ee = e >> 5, ci = e & 31;
    double a = 0;
    for (int k2 = 0; k2 < 3; k2++) a += (double)scs[(ee*32+ci)*3+k2];
    pa[ee][ci] = a;
  }
  __syncthreads();
  if (t < 32) {
    double s = 0;
    for (int ci = 0; ci < 32; ci++) s += pa[t][ci] * c1[ci];
    wd[DW_CC + 64 + t] = s + (double)scbb[64+t];
  }
  // write w0/w1/c0/c1
  for (int e = t; e < 224; e += 256) wd[DW_WEFF + (e/7)*16 + e%7] = w0[e/7][e%7];
  for (int e = t; e < 384; e += 256) wd[DW_WEFF + (32 + e/12)*16 + e%12] = w1[e/12][e%12];
  if (t < 32) { wd[DW_CC+t] = c0[t]; wd[DW_CC+32+t] = c1[t]; }
}

// ---------------- P[i][g][o2][p] + Q[i][g][o2]  (15 blocks, LDS-staged gW) ----------------
__global__ __launch_bounds__(256) void k_pre_p(const float* gW, double* wd)
{
  int blk = blockIdx.x;      // i*5+g
  int i = blk/5, g = blk%5;
  int tid = threadIdx.x;
  __shared__ float gls[2][3072];
  __shared__ double weffs[512];
  __shared__ double ccs[32];
  for (int e = tid; e < 6144; e += 256) gls[e/3072][e % 3072] = gW[i*6144 + e];
  for (int e = tid; e < 512; e += 256) weffs[e] = wd[DW_WEFF + i*512 + e];
  if (tid < 32) ccs[tid] = wd[DW_CC + i*32 + tid];
  __syncthreads();
  const float* g0 = gls[0];
  const float* g1 = gls[1];
  for (int e = tid; e < 512; e += 256) {
    int o2 = e >> 4, p = e & 15;
    double s = 0;
    for (int c = 0; c < 32; c++) {
      float w;
      if (g == 0) w = g0[c*32+o2] + g1[c*32+o2]
                    + 0.05f*(g0[(32+c)*32+o2] + g0[(64+c)*32+o2] + g1[(32+c)*32+o2] + g1[(64+c)*32+o2]);
      else if (g == 1) w = g0[(32+c)*32+o2];
      else if (g == 2) w = g0[(64+c)*32+o2];
      else if (g == 3) w = g1[(32+c)*32+o2];
      else             w = g1[(64+c)*32+o2];
      s += (double)w * weffs[c*16 + p];
    }
    wd[DW_P + ((i*5+g)*32 + o2)*16 + p] = s;
  }
  if (tid < 32) {
    int o2 = tid;
    double s = 0;
    for (int c = 0; c < 32; c++) {
      float w;
      if (g == 0) w = g0[c*32+o2] + g1[c*32+o2]
                    + 0.05f*(g0[(32+c)*32+o2] + g0[(64+c)*32+o2] + g1[(32+c)*32+o2] + g1[(64+c)*32+o2]);
      else if (g == 1) w = g0[(32+c)*32+o2];
      else if (g == 2) w = g0[(64+c)*32+o2];
      else if (g == 3) w = g1[(32+c)*32+o2];
      else             w = g1[(64+c)*32+o2];
      s += (double)w * ccs[c];
    }
    wd[DW_Q + (i*5+g)*32 + o2] = s;
  }
}

// ---------------- t-path/out0 fused weight columns (svW x P) + cbig (svW x Q) ----------------
__global__ __launch_bounds__(256) void k_pre_v(const float* svW0, const float* svW1, const float* svW2,
                                               const float* s0W, const float* s0b, double* wd, float* ws)
{
  int jj = blockIdx.x;             // 0..255
  int tid = threadIdx.x;
  if (jj >= 240) {
    int o = jj - 240;
    if (tid < 168) ws[OW_VBIG + jj*168 + tid] = s0W[o*168 + tid];
    if (tid == 0)  ws[OW_CBIG + jj] = s0b[o];
    return;
  }
  int i = jj/80, g = (jj%80)/16, o = jj%16;
  int st = (i==0)?1:((i==1)?2:4), tp = (i==0)?7:((i==1)?12:16), L = (i==0)?162:((i==1)?79:39);
  const float* svW = (i==0)?svW0:((i==1)?svW1:svW2);
  const float* svo = svW + o*32*L;
  __shared__ float svlds[32*162];
  __shared__ double Pl[32][16];
  __shared__ double Qs[32];
  __shared__ double red[256];
  int NL = 32*L;
  for (int e = tid; e < NL; e += 256) svlds[e] = svo[e];
  for (int e = tid; e < 512; e += 256) {
    int o2 = e >> 4, p = e & 15;
    Pl[o2][p] = wd[DW_P + ((i*5+g)*32 + o2)*16 + p];
  }
  if (tid < 32) Qs[tid] = wd[DW_Q + (i*5+g)*32 + tid];
  __syncthreads();
  double s = 0;
  for (int e = tid; e < NL; e += 256) s += (double)svlds[e] * Qs[e / L];
  red[tid] = s; __syncthreads();
  for (int stp = 128; stp; stp >>= 1) { if (tid < stp) red[tid] += red[tid+stp]; __syncthreads(); }
  if (tid == 0) ws[OW_CBIG + jj] = (float)red[0];
  if (tid < 168) {
    int u = tid;
    int lo_ = u - tp + 1;
    int lmin = lo_ > 0 ? (lo_ + st - 1)/st : 0;
    int lmax = u/st; if (lmax > L-1) lmax = L-1;
    double v = 0.0;
    for (int o2 = 0; o2 < 32; o2++) {
      const float* sv = svlds + o2*L;
      const double* Pp = Pl[o2];
      for (int l = lmin; l <= lmax; l++)
        v += (double)sv[l] * Pp[u - st*l];
    }
    ws[OW_VBIG + jj*168 + u] = (float)v;
  }
}

// ---------------- fused: feat (blocks 0..299) + t-path GEMM (300..449) ----------------
__global__ __launch_bounds__(256) void k_fg(const float* x, double* wd, float* ws)
{
  int t = threadIdx.x;
  if (blockIdx.x >= 300) {
    __shared__ float xs[16][168];
    int r0 = (blockIdx.x - 300)*16;
    for (int e = t; e < 16*168; e += 256) { int r = e/168, u = e%168; xs[r][u] = x[(r0+r)*168 + u]; }
    __syncthreads();
    int jj = t;
    const float* V = ws + OW_VBIG + jj*168;
    double a[16];
    #pragma unroll
    for (int r = 0; r < 16; r++) a[r] = 0;
    for (int u = 0; u < 168; u++) {
      float wv = V[u];
      #pragma unroll
      for (int r = 0; r < 16; r++) a[r] += (double)wv * (double)xs[r][u];
    }
    double cb = (double)ws[OW_CBIG + jj];
    for (int r = 0; r < 16; r++)
      ws[OW_T + (r0+r)*256 + jj] = (float)(a[r] + cb);
    return;
  }
  int blk = blockIdx.x;      // 4*75
  int b = blk / 75, n0 = (blk % 75) * 8;
  __shared__ float xsf[8][168];
  __shared__ double xbar[8][35];
  for (int e = t; e < 8*168; e += 256) xsf[e/168][e%168] = x[(b*600 + n0 + e/168)*168 + e%168];
  __syncthreads();
  for (int e = t; e < 8*35; e += 256) {
    int nn = e/35, slot = e%35;
    int i = slot < 7 ? 0 : (slot < 19 ? 1 : 2);
    int p = slot - (i==0?0:(i==1?7:19));
    int st = (i==0)?1:((i==1)?2:4), L = (i==0)?162:((i==1)?79:39);
    double s = 0;
    for (int l = 0; l < L; l++) s += (double)xsf[nn][st*l+p];
    xbar[nn][slot] = s / (double)L;
  }
  __syncthreads();
  int nn = t >> 5, c = t & 31;
  for (int i = 0; i < 3; i++) {
    int off = (i==0)?0:((i==1)?7:19), tp = (i==0)?7:((i==1)?12:16);
    double f = wd[DW_CC + i*32 + c];
    for (int p = 0; p < tp; p++) f += wd[DW_WEFF + (i*32+c)*16 + p] * xbar[nn][off+p];
    ws[OW_FEAT + ((i*4+b)*600 + n0+nn)*32 + c] = (float)f;
  }
}

// ---------------- n1/n2: LDS-staged weights, 16 nodes per block ----------------
__global__ __launch_bounds__(256) void k_nodes(const float* lin1W, const float* lin1b,
                                               const float* lin2W, const float* lin2b,
                                               const float* emb1, const float* emb2, float* ws)
{
  int blk = blockIdx.x;  // i*152 + b*38 + nt
  int nt = blk % 38, b = (blk/38) % 4, i = blk/152;
  int n0 = nt*16;
  __shared__ float W1[1280], W2[1280], b1[40], b2[40], sf[16][33];
  int t = threadIdx.x;
  for (int e = t; e < 1280; e += 256) { W1[e] = lin1W[i*1280 + e]; W2[e] = lin2W[i*1280 + e]; }
  if (t < 40) { b1[t] = lin1b[i*40 + t]; b2[t] = lin2b[i*40 + t]; }
  for (int e = t; e < 16*32; e += 256) {
    int nn = e >> 5, c = e & 31; int n = n0 + nn;
    sf[nn][c] = (n < 600) ? ws[OW_FEAT + ((i*4+b)*600 + n)*32 + c] : 0.f;
  }
  __syncthreads();
  const float TSF[3] = {3.0f, 2.4f, 1.8f};
  for (int item = t; item < 16*80; item += 256) {
    int nn = item / 80, rr = item % 80;
    int n = n0 + nn; if (n >= 600) continue;
    int which = rr/40, d = rr%40;
    const float* W  = which ? W2 : W1;
    const float* bv = which ? b2 : b1;
    const float* em = which ? emb2 : emb1;
    float pre = 0.f;
    #pragma unroll
    for (int c = 0; c < 32; c++) pre = fmaf(sf[nn][c], W[c*40+d], pre);
    float p2 = __fadd_rn(pre, bv[d]);
    float p3 = __fadd_rn(p2, em[n*40+d]);
    float arg = __fmul_rn(TSF[i], p3);
    ws[(which ? OW_N2 : OW_N1) + ((i*4+b)*600 + n)*40 + d] = tanh_eigen(arg);
  }
}

// ---------------- adjacency staging helper ----------------
__device__ __forceinline__ float4 adj_ld(const float* n1, const float* n2, int e, int w0)
{
  int mat = e >= 320; int idx = e - 320*mat;
  int jj = idx/10, q = idx - 10*jj;
  int w = w0 + jj;
  if (w < 600) return *(const float4*)((mat ? n2 : n1) + w*40 + 4*q);
  float4 z; z.x = z.y = z.z = z.w = 0.f; return z;
}

// ---------------- adjacency: 16 rows/block, 16-way broadcast, colsum epilogue ----------------
__global__ __launch_bounds__(256) void k_adj(float* adj_out, float* ws)
{
  int blk = blockIdx.x;                 // ib*38 + tile  (12*38 = 456)
  int tile = blk % 38, ib = blk / 38;   // ib = i*4+b
  int row0 = tile*16;
  const float* n1 = ws + OW_N1 + ib*24000;
  const float* n2 = ws + OW_N2 + ib*24000;
  __shared__ float c1s[32][44], c2s[32][44];
  __shared__ float svals[16][604];      // 604%32==28: conflict-free
  int t = threadIdx.x;
  int rc = t & 15, jc = t >> 4;         // 16 lanes share each column address
  int myrow = row0 + rc;
  bool rvalid = myrow < 600;
  float am1[40], am2[40];
  {
    int rl = rvalid ? myrow : 599;
    const float4* m1p = (const float4*)(n1 + rl*40);
    const float4* m2p = (const float4*)(n2 + rl*40);
    #pragma unroll
    for (int q = 0; q < 10; q++) {
      float4 v1 = m1p[q], v2 = m2p[q];
      am1[4*q]=v1.x; am1[4*q+1]=v1.y; am1[4*q+2]=v1.z; am1[4*q+3]=v1.w;
      am2[4*q]=v2.x; am2[4*q+1]=v2.y; am2[4*q+2]=v2.z; am2[4*q+3]=v2.w;
    }
  }
  float4 s0 = adj_ld(n1, n2, t, 0);
  float4 s1 = adj_ld(n1, n2, t + 256, 0);
  float4 s2; if (t < 128) s2 = adj_ld(n1, n2, t + 512, 0);
  for (int k = 0; k < 19; k++) {
    int w0 = 32*k;
    __syncthreads();
    {
      int e = t;       { int mat=e>=320, idx=e-320*mat, jj=idx/10, q=idx-10*jj, w=w0+jj;
                         if (w<600) *(float4*)(&(mat?c2s:c1s)[jj][4*q]) = s0; }
      e = t + 256;     { int mat=e>=320, idx=e-320*mat, jj=idx/10, q=idx-10*jj, w=w0+jj;
                         if (w<600) *(float4*)(&(mat?c2s:c1s)[jj][4*q]) = s1; }
      if (t < 128) { e = t + 512; int mat=e>=320, idx=e-320*mat, jj=idx/10, q=idx-10*jj, w=w0+jj;
                         if (w<600) *(float4*)(&(mat?c2s:c1s)[jj][4*q]) = s2; }
    }
    __syncthreads();
    if (k < 18) {
      int w0n = w0 + 32;
      s0 = adj_ld(n1, n2, t, w0n);
      s1 = adj_ld(n1, n2, t + 256, w0n);
      if (t < 128) s2 = adj_ld(n1, n2, t + 512, w0n);
    }
    #pragma unroll
    for (int cc = 0; cc < 2; cc++) {
      int col = jc + 16*cc;
      int w = w0 + col;
      if (rvalid && w < 600) {
        const float4* c2p = (const float4*)c2s[col];
        const float4* c1p = (const float4*)c1s[col];
        float d1 = 0.f, d2 = 0.f;
        #pragma unroll
        for (int q = 0; q < 10; q++) {          // ascending d, single accumulator: bit-exact
          float4 v = c2p[q];
          d1 = fmaf(am1[4*q], v.x, d1); d1 = fmaf(am1[4*q+1], v.y, d1);
          d1 = fmaf(am1[4*q+2], v.z, d1); d1 = fmaf(am1[4*q+3], v.w, d1);
        }
        #pragma unroll
        for (int q = 0; q < 10; q++) {
          float4 v = c1p[q];
          d2 = fmaf(am2[4*q], v.x, d2); d2 = fmaf(am2[4*q+1], v.y, d2);
          d2 = fmaf(am2[4*q+2], v.z, d2); d2 = fmaf(am2[4*q+3], v.w, d2);
        }
        float af = __fsub_rn(d1, d2);
        float tv = __fmul_rn(3.0f, af);
        float v = tanh_eigen(tv);
        svals[rc][w] = v > 0.f ? v : 0.f;       // relu
      }
    }
  }
  __syncthreads();
  // ---- top-k: proven per-row logic, two passes of 8 rows ----
  const float VP = tanh_eigen(8.0f);
  unsigned int vpb = __float_as_uint(VP);
  int j = t & 31;
  for (int p = 0; p < 2; p++) {
    int r = p*8 + (t >> 5);
    int row = row0 + r;
    if (row < 600) {
      float vv[19];
      #pragma unroll
      for (int k = 0; k < 19; k++) {
        int w = j + 32*k;
        vv[k] = (w < 600) ? svals[r][w] : 0.f;
      }
      float rm = 0.f;
      #pragma unroll
      for (int k = 0; k < 19; k++) rm = fmaxf(rm, vv[k]);
      #pragma unroll
      for (int s = 16; s; s >>= 1) rm = fmaxf(rm, __shfl_xor(rm, s, 32));
      int cntp = 0;
      #pragma unroll
      for (int k = 0; k < 19; k++) { int w = j + 32*k; if (w < 600 && __float_as_uint(vv[k]) >= vpb) cntp++; }
      #pragma unroll
      for (int s = 16; s; s >>= 1) cntp += __shfl_xor(cntp, s, 32);
      unsigned int lo, hi;
      unsigned int mb1 = __float_as_uint(rm) + 1u;
      if (cntp >= 20) { lo = vpb; hi = mb1; }
      else            { lo = 0u;  hi = vpb < mb1 ? vpb : mb1; }
      while (hi - lo > 1u) {
        unsigned int mid = lo + ((hi - lo) >> 1);
        int cnt = 0;
        #pragma unroll
        for (int k = 0; k < 19; k++) {
          int w = j + 32*k;
          if (w < 600 && __float_as_uint(vv[k]) >= mid) cnt++;
        }
        #pragma unroll
        for (int s = 16; s; s >>= 1) cnt += __shfl_xor(cnt, s, 32);
        if (cnt >= 20) lo = mid; else hi = mid;
      }
      unsigned int kb = lo;
      float* arow = adj_out + ib*360000 + row*600;
      float rsum = 0.f;
      #pragma unroll
      for (int k = 0; k < 19; k++) {
        int w = j + 32*k;
        if (w < 600) {
          float v = (__float_as_uint(vv[k]) >= kb) ? vv[k] : 0.f;
          arow[w] = v;
          svals[r][w] = v;              // masked write-back for column sums
          rsum += v;
        }
      }
      #pragma unroll
      for (int s = 16; s; s >>= 1) rsum += __shfl_xor(rsum, s, 32);
      if (j == 0) ws[OW_IRA + ib*600 + row] = 1.f/(1.f + rsum);
    }
  }
  __syncthreads();
  // ---- column-sum epilogue: valid-row partials -> atomic raw sums ----
  {
    int nv = 600 - row0; if (nv > 16) nv = 16;
    float* csb = ws + OW_CSB + ib*600;
    for (int w = t; w < 600; w += 256) {
      float cs = 0.f;
      for (int rr2 = 0; rr2 < nv; rr2++) cs += svals[rr2][w];
      atomicAdd(&csb[w], cs);
    }
  }
}

// ---------------- inv row sums for transposed direction: 1/(1+csum) ----------------
__global__ void k_invrb(float* ws)
{
  int e = blockIdx.x*256 + threadIdx.x;
  if (e < 7200) ws[OW_IRB + e] = 1.f/(1.f + ws[OW_CSB + e]);
}

// ---------------- prop1: 4w x 4oz per thread, per-wave K-split, b128 LDS ----------------
__global__ __launch_bounds__(256) void k_prop1(const float* adj, float* ws)
{
  int blk = blockIdx.x;            // ib*38 + d*19 + wt
  int wt = blk % 19;
  int d  = (blk / 19) & 1;
  int ib = blk / 38;
  int i = ib >> 2, b = ib & 3;
  int w0 = wt * 32;
  const float* A   = adj + ib*360000;
  const float* irx = ws + (d ? OW_IRB : OW_IRA) + ib*600;
  const float* Tb  = ws + OW_T + (b*600)*256 + i*80 + 16 + d*32;
  __shared__ float As[4][32][36];
  __shared__ float Zs[4][32][36];
  __shared__ float red[3][64][17];
  int tid = threadIdx.x;
  int wv = tid >> 6, ln = tid & 63;
  int wq = ln >> 3, oq = ln & 7;
  float acc[4][4];
  #pragma unroll
  for (int a1 = 0; a1 < 4; a1++)
    #pragma unroll
    for (int a2 = 0; a2 < 4; a2++) acc[a1][a2] = 0.f;
  int vbeg = wv*160, vend = vbeg + 160 < 600 ? vbeg + 160 : 600;
  for (int v0 = vbeg; v0 < vend; v0 += 32) {
    if (d == 0) {
      #pragma unroll
      for (int q = 0; q < 4; q++) {
        int m = q*64 + ln, rr = m >> 3, c4 = (m & 7)*4;
        int v = v0 + rr;
        float4 av; av.x = av.y = av.z = av.w = 0.f;
        if (v < 600) {
          int wb = w0 + c4;
          if (wb + 3 < 600) av = *(const float4*)(A + v*600 + wb);
          else {
            if (wb+0 < 600) av.x = A[v*600 + wb+0];
            if (wb+1 < 600) av.y = A[v*600 + wb+1];
            if (wb+2 < 600) av.z = A[v*600 + wb+2];
            if (wb+3 < 600) av.w = A[v*600 + wb+3];
          }
        }
        *(float4*)(&As[wv][rr][c4]) = av;
      }
    } else {
      #pragma unroll
      for (int q = 0; q < 4; q++) {
        int m = q*64 + ln, rr = m >> 3, c4 = (m & 7)*4;
        int w = w0 + rr;
        float4 av; av.x = av.y = av.z = av.w = 0.f;
        if (w < 600) {
          if (v0 + c4 + 3 < 600) av = *(const float4*)(A + w*600 + v0 + c4);
          else {
            if (v0+c4+0 < 600) av.x = A[w*600 + v0+c4+0];
            if (v0+c4+1 < 600) av.y = A[w*600 + v0+c4+1];
            if (v0+c4+2 < 600) av.z = A[w*600 + v0+c4+2];
            if (v0+c4+3 < 600) av.w = A[w*600 + v0+c4+3];
          }
        }
        As[wv][c4+0][rr] = av.x; As[wv][c4+1][rr] = av.y;
        As[wv][c4+2][rr] = av.z; As[wv][c4+3][rr] = av.w;
      }
    }
    #pragma unroll
    for (int q = 0; q < 4; q++) {
      int m = q*64 + ln, rr = m >> 3, c4 = (m & 7)*4;
      int v = v0 + rr;
      float4 zv; zv.x = zv.y = zv.z = zv.w = 0.f;
      if (v < 600) {
        float ir = irx[v];
        float4 tv = *(const float4*)(Tb + v*256 + c4);
        zv.x = ir*tv.x; zv.y = ir*tv.y; zv.z = ir*tv.z; zv.w = ir*tv.w;
      }
      *(float4*)(&Zs[wv][rr][c4]) = zv;
    }
    __builtin_amdgcn_s_waitcnt(0);
    for (int vl = 0; vl < 32; vl++) {
      float4 a4 = *(const float4*)(&As[wv][vl][wq*4]);
      float4 z4 = *(const float4*)(&Zs[wv][vl][oq*4]);
      acc[0][0] = fmaf(a4.x, z4.x, acc[0][0]); acc[0][1] = fmaf(a4.x, z4.y, acc[0][1]);
      acc[0][2] = fmaf(a4.x, z4.z, acc[0][2]); acc[0][3] = fmaf(a4.x, z4.w, acc[0][3]);
      acc[1][0] = fmaf(a4.y, z4.x, acc[1][0]); acc[1][1] = fmaf(a4.y, z4.y, acc[1][1]);
      acc[1][2] = fmaf(a4.y, z4.z, acc[1][2]); acc[1][3] = fmaf(a4.y, z4.w, acc[1][3]);
      acc[2][0] = fmaf(a4.z, z4.x, acc[2][0]); acc[2][1] = fmaf(a4.z, z4.y, acc[2][1]);
      acc[2][2] = fmaf(a4.z, z4.z, acc[2][2]); acc[2][3] = fmaf(a4.z, z4.w, acc[2][3]);
      acc[3][0] = fmaf(a4.w, z4.x, acc[3][0]); acc[3][1] = fmaf(a4.w, z4.y, acc[3][1]);
      acc[3][2] = fmaf(a4.w, z4.z, acc[3][2]); acc[3][3] = fmaf(a4.w, z4.w, acc[3][3]);
    }
  }
  if (wv > 0) {
    #pragma unroll
    for (int kw = 0; kw < 4; kw++)
      #pragma unroll
      for (int ko = 0; ko < 4; ko++) red[wv-1][ln][kw*4+ko] = acc[kw][ko];
  }
  __syncthreads();
  if (wv == 0) {
    #pragma unroll
    for (int kw = 0; kw < 4; kw++) {
      int w = w0 + wq*4 + kw;
      if (w >= 600) continue;
      float irw = irx[w];
      #pragma unroll
      for (int ko = 0; ko < 4; ko++) {
        int oz = oq*4 + ko;
        float sum = acc[kw][ko] + red[0][ln][kw*4+ko] + red[1][ln][kw*4+ko] + red[2][ln][kw*4+ko];
        sum += irw * Tb[w*256 + oz];
        float* dst = ws + (d==0 ? (oz < 16 ? OW_U1A : OW_U2A) : (oz < 16 ? OW_U1B : OW_U2B));
        dst[(ib*600 + w)*16 + (oz & 15)] = sum;
      }
    }
  }
}

// ---------------- prop2: 4w x 2oz per thread, per-wave K-split ----------------
__global__ __launch_bounds__(256) void k_prop2(const float* adj, float* ws)
{
  int blk = blockIdx.x;            // ib*38 + d*19 + wt
  int wt = blk % 19;
  int d  = (blk / 19) & 1;
  int ib = blk / 38;
  int w0 = wt * 32;
  const float* A   = adj + ib*360000;
  const float* irx = ws + (d ? OW_IRB : OW_IRA) + ib*600;
  const float* u2x = ws + (d ? OW_U2B : OW_U2A) + ib*9600;
  __shared__ float As[4][32][36];
  __shared__ float Zs[4][32][20];
  __shared__ float red[3][64][9];
  int tid = threadIdx.x;
  int wv = tid >> 6, ln = tid & 63;
  int wq = ln >> 3, oq = ln & 7;
  float acc[4][2];
  #pragma unroll
  for (int a1 = 0; a1 < 4; a1++) { acc[a1][0] = 0.f; acc[a1][1] = 0.f; }
  int vbeg = wv*160, vend = vbeg + 160 < 600 ? vbeg + 160 : 600;
  for (int v0 = vbeg; v0 < vend; v0 += 32) {
    if (d == 0) {
      #pragma unroll
      for (int q = 0; q < 4; q++) {
        int m = q*64 + ln, rr = m >> 3, c4 = (m & 7)*4;
        int v = v0 + rr;
        float4 av; av.x = av.y = av.z = av.w = 0.f;
        if (v < 600) {
          int wb = w0 + c4;
          if (wb + 3 < 600) av = *(const float4*)(A + v*600 + wb);
          else {
            if (wb+0 < 600) av.x = A[v*600 + wb+0];
            if (wb+1 < 600) av.y = A[v*600 + wb+1];
            if (wb+2 < 600) av.z = A[v*600 + wb+2];
            if (wb+3 < 600) av.w = A[v*600 + wb+3];
          }
        }
        *(float4*)(&As[wv][rr][c4]) = av;
      }
    } else {
      #pragma unroll
      for (int q = 0; q < 4; q++) {
        int m = q*64 + ln, rr = m >> 3, c4 = (m & 7)*4;
        int w = w0 + rr;
        float4 av; av.x = av.y = av.z = av.w = 0.f;
        if (w < 600) {
          if (v0 + c4 + 3 < 600) av = *(const float4*)(A + w*600 + v0 + c4);
          else {
            if (v0+c4+0 < 600) av.x = A[w*600 + v0+c4+0];
            if (v0+c4+1 < 600) av.y = A[w*600 + v0+c4+1];
            if (v0+c4+2 < 600) av.z = A[w*600 + v0+c4+2];
            if (v0+c4+3 < 600) av.w = A[w*600 + v0+c4+3];
          }
        }
        As[wv][c4+0][rr] = av.x; As[wv][c4+1][rr] = av.y;
        As[wv][c4+2][rr] = av.z; As[wv][c4+3][rr] = av.w;
      }
    }
    #pragma unroll
    for (int q = 0; q < 2; q++) {
      int m = q*64 + ln, rr = m >> 2, c4 = (m & 3)*4;
      int v = v0 + rr;
      float4 zv; zv.x = zv.y = zv.z = zv.w = 0.f;
      if (v < 600) {
        float ir = irx[v];
        float4 uv = *(const float4*)(u2x + v*16 + c4);
        zv.x = ir*uv.x; zv.y = ir*uv.y; zv.z = ir*uv.z; zv.w = ir*uv.w;
      }
      *(float4*)(&Zs[wv][rr][c4]) = zv;
    }
    __builtin_amdgcn_s_waitcnt(0);
    for (int vl = 0; vl < 32; vl++) {
      float4 a4 = *(const float4*)(&As[wv][vl][wq*4]);
      float2 z2 = *(const float2*)(&Zs[wv][vl][oq*2]);
      acc[0][0] = fmaf(a4.x, z2.x, acc[0][0]); acc[0][1] = fmaf(a4.x, z2.y, acc[0][1]);
      acc[1][0] = fmaf(a4.y, z2.x, acc[1][0]); acc[1][1] = fmaf(a4.y, z2.y, acc[1][1]);
      acc[2][0] = fmaf(a4.z, z2.x, acc[2][0]); acc[2][1] = fmaf(a4.z, z2.y, acc[2][1]);
      acc[3][0] = fmaf(a4.w, z2.x, acc[3][0]); acc[3][1] = fmaf(a4.w, z2.y, acc[3][1]);
    }
  }
  if (wv > 0) {
    #pragma unroll
    for (int kw = 0; kw < 4; kw++) {
      red[wv-1][ln][kw*2+0] = acc[kw][0];
      red[wv-1][ln][kw*2+1] = acc[kw][1];
    }
  }
  __syncthreads();
  if (wv == 0) {
    float* dst = ws + (d==0 ? OW_U3A : OW_U3B);
    #pragma unroll
    for (int kw = 0; kw < 4; kw++) {
      int w = w0 + wq*4 + kw;
      if (w >= 600) continue;
      float irw = irx[w];
      #pragma unroll
      for (int ko = 0; ko < 2; ko++) {
        int oz = oq*2 + ko;
        float sum = acc[kw][ko] + red[0][ln][kw*2+ko] + red[1][ln][kw*2+ko] + red[2][ln][kw*2+ko];
        sum += irw * u2x[w*16 + oz];
        dst[(ib*600 + w)*16 + oz] = sum;
      }
    }
  }
}

// ---------------- assemble head outputs + fused SE row sums ----------------
__global__ __launch_bounds__(256) void k_outs(float* ws)
{
  __shared__ float sums[2];
  int tid = threadIdx.x;
  int e = blockIdx.x*256 + tid;
  int rA = (blockIdx.x*256)/600;
  if (tid < 2) sums[tid] = 0.f;
  __syncthreads();
  float val = 0.f;
  int row = rA;
  if (e < 153600) {
    int n = e % 600, o = (e/600) % 16, b = (e/9600) % 4, s = e/38400;
    if (s == 0) {
      val = ws[OW_T + (b*600+n)*256 + 240 + o];
    } else {
      int i = s - 1;
      int idx = ((i*4+b)*600 + n)*16 + o;
      float t0 = ws[OW_T + (b*600+n)*256 + i*80 + o];
      val = t0 + 0.95f  * (ws[OW_U1A+idx] + ws[OW_U1B+idx])
               + 0.0475f* (ws[OW_U2A+idx] + ws[OW_U2B+idx])
               + 0.9025f* (ws[OW_U3A+idx] + ws[OW_U3B+idx])
               + ws[OW_CSV + i*16 + o];
    }
    ws[OW_O + ((s*4+b)*16 + o)*600 + n] = val;
    row = e/600;
  }
  float vA = (e < 153600 && row == rA) ? val : 0.f;
  float vB = (e < 153600 && row == rA+1) ? val : 0.f;
  #pragma unroll
  for (int s = 32; s; s >>= 1) { vA += __shfl_down(vA, s, 64); vB += __shfl_down(vB, s, 64); }
  if ((tid & 63) == 0) {
    if (vA != 0.f) atomicAdd(&sums[0], vA);
    if (vB != 0.f) atomicAdd(&sums[1], vB);
  }
  __syncthreads();
  if (tid < 2) {
    int r = rA + tid;
    if (r < 256) atomicAdd(&ws[OW_SVS + r], sums[tid]);
  }
}

// ---------------- SE gate (reads fused sums) ----------------
__global__ void k_se(const float* gfW1, const float* gfW2, float* ws)
{
  __shared__ float sv[4][64], hb[4][4];
  int t = threadIdx.x;
  {
    int row = t;
    int o = row & 15, b = (row >> 4) & 3, s = row >> 6;
    sv[b][s*16 + o] = ws[OW_SVS + row] * (1.f/600.f);
  }
  __syncthreads();
  if (t < 16) {
    int bb = t >> 2, j = t & 3;
    float h = 0.f;
    for (int kk = 0; kk < 64; kk++) h += sv[bb][kk]*gfW1[kk*4+j];
    hb[bb][j] = h > 0.f ? h : 0.f;
  }
  __syncthreads();
  if (t < 16) {
    int bb = t >> 2, ii = t & 3;
    float g = 0.f;
    for (int j = 0; j < 4; j++) g += hb[bb][j]*gfW2[j*4+ii];
    ws[OW_SE + bb*4 + ii] = 1.f/(1.f + expf(-g));
  }
}

// ---------------- gate + end MLP (parallel final stage) ----------------
__global__ __launch_bounds__(128) void k_head(const float* e1W, const float* e1b,
                                              const float* e2W, const float* e2b,
                                              float* ws, float* dout)
{
  int blk = blockIdx.x, b = blk/600, n = blk%600;
  __shared__ float y0[16], y1[128];
  int t = threadIdx.x;
  if (t < 16) {
    float f = 0.f;
    for (int s = 0; s < 4; s++) f += ws[OW_SE + b*4 + s] * ws[OW_O + ((s*4+b)*16 + t)*600 + n];
    f *= 0.25f;
    y0[t] = f > 0.f ? f : 0.f;
  }
  __syncthreads();
  {
    float h = e1b[t];
    for (int o = 0; o < 16; o++) h += e1W[t*16+o]*y0[o];
    y1[t] = h > 0.f ? h : 0.f;
  }
  __syncthreads();
  if (t < 96) {
    int o = t >> 3, part = t & 7;   // 12 outputs x 8 partials
    float v = 0.f;
    #pragma unroll
    for (int e = 0; e < 16; e++) v = fmaf(e2W[o*128 + part*16 + e], y1[part*16 + e], v);
    #pragma unroll
    for (int s = 4; s; s >>= 1) v += __shfl_down(v, s, 8);
    if (part == 0) dout[b*7200 + o*600 + n] = e2b[o] + v;
  }
}

extern "C" void kernel_launch(void* const* d_in, const int* in_sizes, int n_in,
                              void* d_out, int out_size, void* d_ws, size_t ws_size,
                              hipStream_t stream)
{
  const float* x    = (const float*)d_in[0];
  const float* Ws   = (const float*)d_in[1];
  const float* bs   = (const float*)d_in[2];
  const float* scW0 = (const float*)d_in[3];
  const float* scW1 = (const float*)d_in[4];
  const float* scW2 = (const float*)d_in[5];
  const float* scb  = (const float*)d_in[6];
  const float* emb1 = (const float*)d_in[7];
  const float* emb2 = (const float*)d_in[8];
  const float* lin1W= (const float*)d_in[9];
  const float* lin1b= (const float*)d_in[10];
  const float* lin2W= (const float*)d_in[11];
  const float* lin2b= (const float*)d_in[12];
  const float* gW   = (const float*)d_in[13];
  const float* gb   = (const float*)d_in[14];
  const float* svW0 = (const float*)d_in[15];
  const float* svW1 = (const float*)d_in[16];
  const float* svW2 = (const float*)d_in[17];
  const float* svb  = (const float*)d_in[18];
  const float* s0W  = (const float*)d_in[19];
  const float* s0b  = (const float*)d_in[20];
  const float* gfW1 = (const float*)d_in[21];
  const float* gfW2 = (const float*)d_in[22];
  const float* e1W  = (const float*)d_in[23];
  const float* e1b  = (const float*)d_in[24];
  const float* e2W  = (const float*)d_in[25];
  const float* e2b  = (const float*)d_in[26];
  float* out = (float*)d_out;
  float* ws  = (float*)d_ws;
  double* wd = (double*)d_ws;
  float* adj_out = out + 28800;

  k_pre_wc<<<49, 256, 0, stream>>>(Ws, bs, scW0, scW1, scW2, scb,
                                   svW0, svW1, svW2, gb, svb, wd, ws);
  k_pre_p<<<15, 256, 0, stream>>>(gW, wd);
  k_pre_v<<<256, 256, 0, stream>>>(svW0, svW1, svW2, s0W, s0b, wd, ws);
  hipMemsetAsync((void*)(ws + OW_SVS), 0, (256 + 7200)*sizeof(float), stream);
  k_fg<<<450, 256, 0, stream>>>(x, wd, ws);
  k_nodes<<<456, 256, 0, stream>>>(lin1W, lin1b, lin2W, lin2b, emb1, emb2, ws);
  k_adj<<<456, 256, 0, stream>>>(adj_out, ws);
  k_invrb<<<29, 256, 0, stream>>>(ws);
  k_prop1<<<456, 256, 0, stream>>>(adj_out, ws);
  k_prop2<<<456, 256, 0, stream>>>(adj_out, ws);
  k_outs<<<600, 256, 0, stream>>>(ws);
  k_se<<<1, 256, 0, stream>>>(gfW1, gfW2, ws);
  k_head<<<2400, 128, 0, stream>>>(e1W, e1b, e2W, e2b, ws, out);
}